// Round 13
// baseline (466.333 us; speedup 1.0000x reference)
//
#include <hip/hip_runtime.h>
#include <hip/hip_bf16.h>

typedef __hip_bfloat16 bf16;
typedef __attribute__((ext_vector_type(8))) short short8;
typedef __attribute__((ext_vector_type(4))) float f32x4;
typedef __attribute__((ext_vector_type(4))) unsigned short u16x4;

#define Hh 160
#define Wd 160
#define HWp (Hh*Wd)       // 25600
#define Bn 2
#define Cc 64
#define NPIX (Bn*HWp)     // 51200
#define SCL 0.07905694150420949f   // 1/sqrt(160)
#define TWO_PI_160 0.039269908169872414f  // 2*pi/160

static __device__ __forceinline__ float b2f(bf16 x) { return __bfloat162float(x); }
static __device__ __forceinline__ bf16 f2b(float f) { return __float2bfloat16(f); }
static __device__ __forceinline__ unsigned short f2bu(float f) {
  union { bf16 h; unsigned short u; } z; z.h = __float2bfloat16(f); return z.u;
}
static __device__ __forceinline__ float ubf(unsigned short u) {
  union { unsigned int i; float f; } z; z.i = ((unsigned int)u) << 16; return z.f;
}

// ---------------- LayerNorm over channel dim, single-pass ----------------
__global__ void k_ln(const float* __restrict__ in, const float* __restrict__ w,
                     const float* __restrict__ bb, bf16* __restrict__ out) {
  __shared__ float2 sm[4][64];
  int t = threadIdx.x;
  int pxl = t & 63, cq = t >> 6;
  int pix = blockIdx.x * 64 + pxl;          // 800 blocks cover NPIX
  int b = pix / HWp, p = pix - b * HWp;
  const float* src = in + ((size_t)b * Cc + cq * 16) * HWp + p;
  float v[16];
  float s = 0.f, s2 = 0.f;
  #pragma unroll
  for (int i = 0; i < 16; i++) {
    v[i] = src[(size_t)i * HWp];
    s += v[i]; s2 += v[i] * v[i];
  }
  sm[cq][pxl] = make_float2(s, s2);
  __syncthreads();
  float S = 0.f, S2 = 0.f;
  #pragma unroll
  for (int k = 0; k < 4; k++) { float2 z = sm[k][pxl]; S += z.x; S2 += z.y; }
  float mu = S * (1.f / 64.f);
  float var = S2 * (1.f / 64.f) - mu * mu;
  float rs = rsqrtf(fmaxf(var, 0.f) + 1e-6f);
  bf16* dst = out + ((size_t)b * Cc + cq * 16) * HWp + p;
  #pragma unroll
  for (int i = 0; i < 16; i++) {
    int c = cq * 16 + i;
    dst[(size_t)i * HWp] = f2b((v[i] - mu) * rs * w[c] + bb[c]);
  }
}

// ---------------- mean over HW per (b,c) plane (bf16 in) ----------------
__global__ void k_meanhw(const bf16* __restrict__ in, float* __restrict__ out) {
  int bc = blockIdx.x;
  const bf16* src = in + (size_t)bc * HWp;
  int t = threadIdx.x;
  float s = 0.f;
  for (int i = t; i < HWp; i += 256) s += b2f(src[i]);
  __shared__ float sm[256];
  sm[t] = s; __syncthreads();
  for (int off = 128; off; off >>= 1) { if (t < off) sm[t] += sm[t + off]; __syncthreads(); }
  if (t == 0) out[bc] = sm[0] * (1.f / HWp);
}

// ---------------- fused dual mean: bc<128 from in0, else in1 ----------------
__global__ void k_meanhw2(const bf16* __restrict__ in0, const bf16* __restrict__ in1,
                          float* __restrict__ out) {
  int bc = blockIdx.x;   // 0..255
  const bf16* src = (bc < 128) ? (in0 + (size_t)bc * HWp) : (in1 + (size_t)(bc - 128) * HWp);
  int t = threadIdx.x;
  float s = 0.f;
  for (int i = t; i < HWp; i += 256) s += b2f(src[i]);
  __shared__ float sm[256];
  sm[t] = s; __syncthreads();
  for (int off = 128; off; off >>= 1) { if (t < off) sm[t] += sm[t + off]; __syncthreads(); }
  if (t == 0) out[bc] = sm[0] * (1.f / HWp);
}

// ---------------- small matvec ----------------
__global__ void k_small_mv(const float* __restrict__ xin, const float* __restrict__ w,
                           const float* __restrict__ bias, float* __restrict__ out, int addone) {
  int t = threadIdx.x;              // 128 threads
  int b = t >> 6, o = t & 63;
  float acc = bias[o];
  for (int k = 0; k < 64; k++) acc += w[o * 64 + k] * xin[b * 64 + k];
  out[t] = addone ? (1.f + acc) : acc;
}

// ---------------- fused dual small matvec ----------------
__global__ void k_small_mv2(const float* __restrict__ xin, const float* __restrict__ w,
                            const float* __restrict__ bias, float* __restrict__ out) {
  int t = threadIdx.x;              // 256 threads
  int half = t >> 7, r = t & 127;
  int b = r >> 6, o = r & 63;
  const float* x = xin + half * 128 + b * 64;
  float acc = bias[o];
  for (int k = 0; k < 64; k++) acc += w[o * 64 + k] * x[k];
  out[half * 128 + r] = 1.f + acc;
}

// ---------------- c2a vectorized: grouped 3x3, 64->32, groups=32, 4 px/thread ----------------
__global__ void k_c2a4(const bf16* __restrict__ in, const float* __restrict__ w,
                       const float* __restrict__ bias, bf16* __restrict__ out) {
  int t = threadIdx.x;
  int o = blockIdx.y, b = blockIdx.z;       // o 0..31
  int pq = blockIdx.x * 256 + t;            // grid.x = 25
  int h = pq / 40, x4 = (pq - h * 40) * 4;
  float bs = bias[o];
  float acc[4] = {bs, bs, bs, bs};
  #pragma unroll
  for (int ci = 0; ci < 2; ci++) {
    const unsigned short* src = (const unsigned short*)in + ((size_t)b * Cc + o * 2 + ci) * HWp;
    float wv[9];
    #pragma unroll
    for (int i = 0; i < 9; i++) wv[i] = w[(o * 2 + ci) * 9 + i];
    #pragma unroll
    for (int ki = 0; ki < 3; ki++) {
      int hh = h + ki - 1;
      if ((unsigned)hh >= Hh) continue;
      const unsigned short* row = src + hh * Wd + x4;
      float v[6];
      u16x4 m = *(const u16x4*)row;
      v[1] = ubf(m[0]); v[2] = ubf(m[1]); v[3] = ubf(m[2]); v[4] = ubf(m[3]);
      v[0] = (x4 > 0) ? ubf(row[-1]) : 0.f;
      v[5] = (x4 + 4 < Wd) ? ubf(row[4]) : 0.f;
      #pragma unroll
      for (int j = 0; j < 4; j++)
        #pragma unroll
        for (int kj = 0; kj < 3; kj++)
          acc[j] = fmaf(wv[ki * 3 + kj], v[j + kj], acc[j]);
    }
  }
  u16x4 pk;
  #pragma unroll
  for (int j = 0; j < 4; j++) pk[j] = f2bu(acc[j]);
  *(u16x4*)((unsigned short*)out + ((size_t)b * 32 + o) * HWp + h * Wd + x4) = pk;
}

// ---------------- fused weight prep ----------------
__global__ void k_prep_all(const float* __restrict__ kbw, const float* __restrict__ kbb,
                           short* __restrict__ kbwF,
                           const float* __restrict__ fc1w, const float* __restrict__ fc2w,
                           short* __restrict__ wAf1, short* __restrict__ wAf2,
                           short* __restrict__ cosF, short* __restrict__ sinF,
                           const float* __restrict__ c11aw, const float* __restrict__ c1w,
                           const float* __restrict__ c3w, const float* __restrict__ c2cw,
                           const float* __restrict__ c211w, const float* __restrict__ attg,
                           short* __restrict__ wA_c11a, short* __restrict__ wA_c1,
                           short* __restrict__ wA_c3, short* __restrict__ wA_att) {
  int i = blockIdx.x * 256 + threadIdx.x;   // 172032 total (672 blocks)
  if (i < 81920) {
    int g = i / 5120, r = i - g * 5120;
    float v = 0.f;
    if (r < 4096) {
      int j = r & 7, lane = (r >> 3) & 63, mt = r >> 9;
      int m = mt * 16 + (lane & 15);
      int s = m >> 2, o = m & 3;
      int k = (lane >> 4) * 8 + j;
      v = kbw[s * 2304 + g * 144 + o * 36 + k];
    } else {
      int r2 = r - 4096;
      int j = r2 & 7, n = (r2 >> 3) & 15, mt = r2 >> 7;
      int m = mt * 16 + n;
      int s = m >> 2, o = m & 3;
      int k = 32 + j;
      if (k < 36) v = kbw[s * 2304 + g * 144 + o * 36 + k];
      else if (k == 36) v = kbb[s * 64 + g * 4 + o];
    }
    kbwF[i] = (short)f2bu(v);
  } else if (i < 131072) {
    int i1 = i - 81920;
    if (i1 < 32768) {
      int j = i1 & 7, lane = (i1 >> 3) & 63, fk = i1 >> 9;
      int kc = fk & 3, mt = fk >> 2;
      int o = mt * 16 + (lane & 15);
      int k = kc * 32 + (lane >> 4) * 8 + j;
      wAf1[i1] = (short)f2bu(fc1w[o * 128 + k]);
    } else {
      int i2 = i1 - 32768;
      int j = i2 & 7, lane = (i2 >> 3) & 63, fk = i2 >> 9;
      int kc = fk & 3, mt = fk >> 2;
      int o = mt * 16 + (lane & 15);
      int k = kc * 32 + (lane >> 4) * 8 + j;
      wAf2[i2] = (short)f2bu(fc2w[o * 128 + k]);
    }
  } else if (i < 156672) {
    int i2 = i - 131072;
    int j = i2 & 7, lane = (i2 >> 3) & 63, fk = i2 >> 9;   // fk = ct*5+kc
    int kc = fk % 5, ct = fk / 5;
    int c = ct * 16 + (lane & 15);
    int bb2 = kc * 32 + (lane >> 4) * 8 + j;
    int m = (bb2 * c) % 160;
    float sv, cv;
    __sincosf((float)m * TWO_PI_160, &sv, &cv);
    cosF[i2] = (short)f2bu(cv);
    sinF[i2] = (short)f2bu(sv);
  } else {
    int i3 = i - 156672;
    if (i3 < 12288) {
      int wi = i3 / 4096, r = i3 - wi * 4096;
      int j = r & 7, lane = (r >> 3) & 63, fk = r >> 9;
      int kc = fk & 1, mt = fk >> 1;
      int o = mt * 16 + (lane & 15);
      int k = kc * 32 + (lane >> 4) * 8 + j;
      const float* w = (wi == 0) ? c11aw : (wi == 1) ? c1w : c3w;
      short* dst = (wi == 0) ? wA_c11a : (wi == 1) ? wA_c1 : wA_c3;
      dst[r] = (short)f2bu(w[o * 64 + k]);
    } else {
      int r = i3 - 12288;
      int j = r & 7, lane = (r >> 3) & 63, fk = r >> 9;
      int kc = fk % 3, mt = fk / 3;
      int s = mt * 16 + (lane & 15);
      int k = kc * 32 + (lane >> 4) * 8 + j;
      float v;
      if (k < 16) v = c2cw[s * 16 + k] * attg[s];
      else if (k < 32) v = 0.f;
      else v = c211w[s * 64 + (k - 32)];
      wA_att[r] = (short)f2bu(v);
    }
  }
}

// ---------------- dual 1x1 conv 64->64 via MFMA (t1 and t2 share input fragments) ----------------
__global__ __launch_bounds__(256) void k_conv1x1_dual(
    const bf16* __restrict__ in, const short* __restrict__ wA1,
    const float* __restrict__ b1, const short* __restrict__ wA2,
    const float* __restrict__ b2, bf16* __restrict__ out1, bf16* __restrict__ out2) {
  int b = blockIdx.z;
  int lane = threadIdx.x & 63, w = threadIdx.x >> 6;
  int px = blockIdx.x * 64 + w * 16 + (lane & 15);
  int q = lane >> 4;
  const unsigned short* src = (const unsigned short*)in + (size_t)b * Cc * HWp;
  const short8* wf1 = (const short8*)wA1;
  const short8* wf2 = (const short8*)wA2;
  f32x4 acc1[4], acc2[4];
  #pragma unroll
  for (int mt = 0; mt < 4; mt++) {
    acc1[mt] = (f32x4){0.f, 0.f, 0.f, 0.f};
    acc2[mt] = (f32x4){0.f, 0.f, 0.f, 0.f};
  }
  #pragma unroll
  for (int kc = 0; kc < 2; kc++) {
    short8 bfv;
    #pragma unroll
    for (int j = 0; j < 8; j++) bfv[j] = (short)src[(size_t)(kc * 32 + q * 8 + j) * HWp + px];
    #pragma unroll
    for (int mt = 0; mt < 4; mt++) {
      short8 a1 = wf1[(mt * 2 + kc) * 64 + lane];
      acc1[mt] = __builtin_amdgcn_mfma_f32_16x16x32_bf16(a1, bfv, acc1[mt], 0, 0, 0);
      short8 a2 = wf2[(mt * 2 + kc) * 64 + lane];
      acc2[mt] = __builtin_amdgcn_mfma_f32_16x16x32_bf16(a2, bfv, acc2[mt], 0, 0, 0);
    }
  }
  unsigned short* d1 = (unsigned short*)out1 + (size_t)b * Cc * HWp;
  unsigned short* d2 = (unsigned short*)out2 + (size_t)b * Cc * HWp;
  #pragma unroll
  for (int mt = 0; mt < 4; mt++)
    #pragma unroll
    for (int j = 0; j < 4; j++) {
      int o = mt * 16 + q * 4 + j;
      d1[(size_t)o * HWp + px] = f2bu(acc1[mt][j] + b1[o]);
      d2[(size_t)o * HWp + px] = f2bu(acc2[mt][j] + b2[o]);
    }
}

// ---------------- c3 1x1 conv + residual + FUSED LayerNorm2 ----------------
__global__ __launch_bounds__(256) void k_c3y_ln2(
    const bf16* __restrict__ in, const short* __restrict__ wA,
    const float* __restrict__ bias, const float* __restrict__ beta,
    const float* __restrict__ inp, float* __restrict__ y,
    const float* __restrict__ n2w, const float* __restrict__ n2b,
    bf16* __restrict__ Xout) {
  int b = blockIdx.z;
  int lane = threadIdx.x & 63, w = threadIdx.x >> 6;
  int px = blockIdx.x * 64 + w * 16 + (lane & 15);
  int q = lane >> 4;
  const unsigned short* src = (const unsigned short*)in + (size_t)b * Cc * HWp;
  const short8* wf = (const short8*)wA;
  f32x4 acc[4];
  #pragma unroll
  for (int mt = 0; mt < 4; mt++) acc[mt] = (f32x4){0.f, 0.f, 0.f, 0.f};
  #pragma unroll
  for (int kc = 0; kc < 2; kc++) {
    short8 bfv;
    #pragma unroll
    for (int j = 0; j < 8; j++) bfv[j] = (short)src[(size_t)(kc * 32 + q * 8 + j) * HWp + px];
    #pragma unroll
    for (int mt = 0; mt < 4; mt++) {
      short8 af = wf[(mt * 2 + kc) * 64 + lane];
      acc[mt] = __builtin_amdgcn_mfma_f32_16x16x32_bf16(af, bfv, acc[mt], 0, 0, 0);
    }
  }
  float yv[4][4];
  float s = 0.f, s2 = 0.f;
  #pragma unroll
  for (int mt = 0; mt < 4; mt++)
    #pragma unroll
    for (int j = 0; j < 4; j++) {
      int o = mt * 16 + q * 4 + j;
      size_t oi = ((size_t)b * Cc + o) * HWp + px;
      float v = inp[oi] + (acc[mt][j] + bias[o]) * beta[o];
      y[oi] = v;
      yv[mt][j] = v;
      s += v; s2 += v * v;
    }
  s  += __shfl_xor(s, 16);  s  += __shfl_xor(s, 32);
  s2 += __shfl_xor(s2, 16); s2 += __shfl_xor(s2, 32);
  float mu = s * (1.f / 64.f);
  float var = s2 * (1.f / 64.f) - mu * mu;
  float rs = rsqrtf(fmaxf(var, 0.f) + 1e-6f);
  unsigned short* Xu = (unsigned short*)Xout + (size_t)b * Cc * HWp;
  #pragma unroll
  for (int mt = 0; mt < 4; mt++)
    #pragma unroll
    for (int j = 0; j < 4; j++) {
      int o = mt * 16 + q * 4 + j;
      Xu[(size_t)o * HWp + px] = f2bu((yv[mt][j] - mu) * rs * n2w[o] + n2b[o]);
    }
}

// ---------------- att via MFMA: M=32, K = [gate16 | pad16 | x64] ----------------
__global__ __launch_bounds__(256) void k_att_mfma(
    const bf16* __restrict__ g, const bf16* __restrict__ x,
    const short* __restrict__ wA, const float* __restrict__ c2cb,
    const float* __restrict__ c211b, const float* __restrict__ attg,
    bf16* __restrict__ att) {
  int b = blockIdx.z;
  int lane = threadIdx.x & 63, w = threadIdx.x >> 6;
  int px = blockIdx.x * 64 + w * 16 + (lane & 15);
  int q = lane >> 4;
  const unsigned short* gs = (const unsigned short*)g + (size_t)b * 32 * HWp;
  const unsigned short* xs = (const unsigned short*)x + (size_t)b * Cc * HWp;
  const short8* wf = (const short8*)wA;
  f32x4 acc[2];
  acc[0] = (f32x4){0.f, 0.f, 0.f, 0.f};
  acc[1] = (f32x4){0.f, 0.f, 0.f, 0.f};
  {
    short8 bfv;
    #pragma unroll
    for (int j = 0; j < 8; j++) {
      int k = q * 8 + j;
      short v = 0;
      if (q < 2) {
        float gv = ubf(gs[(size_t)k * HWp + px]) * ubf(gs[(size_t)(16 + k) * HWp + px]);
        v = (short)f2bu(gv);
      }
      bfv[j] = v;
    }
    #pragma unroll
    for (int mt = 0; mt < 2; mt++) {
      short8 af = wf[(mt * 3 + 0) * 64 + lane];
      acc[mt] = __builtin_amdgcn_mfma_f32_16x16x32_bf16(af, bfv, acc[mt], 0, 0, 0);
    }
  }
  #pragma unroll
  for (int kc = 1; kc < 3; kc++) {
    short8 bfv;
    #pragma unroll
    for (int j = 0; j < 8; j++)
      bfv[j] = (short)xs[(size_t)((kc - 1) * 32 + q * 8 + j) * HWp + px];
    #pragma unroll
    for (int mt = 0; mt < 2; mt++) {
      short8 af = wf[(mt * 3 + kc) * 64 + lane];
      acc[mt] = __builtin_amdgcn_mfma_f32_16x16x32_bf16(af, bfv, acc[mt], 0, 0, 0);
    }
  }
  unsigned short* dst = (unsigned short*)att + (size_t)b * 32 * HWp;
  #pragma unroll
  for (int mt = 0; mt < 2; mt++)
    #pragma unroll
    for (int j = 0; j < 4; j++) {
      int s = mt * 16 + q * 4 + j;
      dst[(size_t)s * HWp + px] = f2bu(acc[mt][j] + c2cb[s] * attg[s] + c211b[s]);
    }
}

// ---------------- c11b direct: grouped 5x5 conv, 16-row tiles ----------------
__global__ __launch_bounds__(256) void k_c11b_direct(
    const bf16* __restrict__ t1, const float* __restrict__ w,
    const float* __restrict__ bias, bf16* __restrict__ out) {
  __shared__ float xs[4 * 20 * 68];        // 21760 B
  __shared__ float wsm[4 * 5 * 4 * 5];
  __shared__ float bsm[4];
  int bz = blockIdx.z;                     // b*16 + g
  int b = bz >> 4, g = bz & 15;
  int h0 = blockIdx.y * 16;
  int w0 = blockIdx.x * 64;
  int t = threadIdx.x;
  for (int i = t; i < 400; i += 256) {
    int kj = i % 5, rem = i / 5;
    int o = rem & 3; rem >>= 2;
    int ki = rem % 5, ci = rem / 5;
    wsm[i] = w[((g * 4 + o) * 4 + ci) * 25 + ki * 5 + kj];
  }
  if (t < 4) bsm[t] = bias[g * 4 + t];
  const unsigned short* src = (const unsigned short*)t1 + ((size_t)b * Cc + g * 4) * HWp;
  for (int i = t; i < 4 * 20 * 68; i += 256) {
    int ci = i / 1360, rem2 = i - ci * 1360;
    int r = rem2 / 68, col = rem2 - r * 68;
    int hh = h0 + r - 2, ww = w0 + col - 2;
    float v = 0.f;
    if ((unsigned)hh < Hh && (unsigned)ww < Wd)
      v = ubf(src[(size_t)ci * HWp + hh * Wd + ww]);
    xs[i] = v;
  }
  __syncthreads();
  int wq = t & 15, hq = t >> 4;
  float acc[4][4];
  #pragma unroll
  for (int o = 0; o < 4; o++)
    #pragma unroll
    for (int j = 0; j < 4; j++) acc[o][j] = bsm[o];
  #pragma unroll
  for (int ci = 0; ci < 4; ci++) {
    #pragma unroll
    for (int ki = 0; ki < 5; ki++) {
      const float* wrow = &wsm[(ci * 5 + ki) * 20];
      float wv[20];
      #pragma unroll
      for (int x = 0; x < 20; x++) wv[x] = wrow[x];
      const float* xrow = &xs[ci * 1360 + (hq + ki) * 68 + wq * 4];
      float xv[8];
      #pragma unroll
      for (int x = 0; x < 8; x++) xv[x] = xrow[x];
      #pragma unroll
      for (int o = 0; o < 4; o++)
        #pragma unroll
        for (int j = 0; j < 4; j++)
          #pragma unroll
          for (int kj = 0; kj < 5; kj++)
            acc[o][j] = fmaf(wv[o * 5 + kj], xv[j + kj], acc[o][j]);
    }
  }
  int width = Wd - w0;
  if (wq * 4 < width) {
    unsigned short* dst = (unsigned short*)out + ((size_t)b * Cc + g * 4) * HWp
                        + (h0 + hq) * Wd + w0 + wq * 4;
    #pragma unroll
    for (int o = 0; o < 4; o++) {
      u16x4 pk;
      #pragma unroll
      for (int j = 0; j < 4; j++) pk[j] = f2bu(acc[o][j]);
      *(u16x4*)(dst + (size_t)o * HWp) = pk;
    }
  }
}

// ---------------- KBA via MFMA + FUSED depthwise-3x3 producer (uf computed in-LDS) ----------
// Block: (wtile 64, row, b*8+gp). LDS: fragL 20 KB + t2L [8][5][68] 5.4 KB +
// patchL [8][3][66] 3.1 KB + attL 4.2 KB + dw weights -> ~33.6 KB, 4 blocks/CU.
__global__ __launch_bounds__(256) void k_kba_mfma(
    const bf16* __restrict__ t2, const bf16* __restrict__ att,
    const bf16* __restrict__ x1, const float* __restrict__ scaV,
    const short* __restrict__ kbwF, const float* __restrict__ ga1,
    const float* __restrict__ c21w, const float* __restrict__ c21b,
    bf16* __restrict__ out) {
  __shared__ short8 fragL[1280];                   // 20480 B (2 groups x 640)
  __shared__ unsigned short t2L[8 * 5 * 68];       // 5440 B
  __shared__ unsigned short patchL[8 * 3 * 66];    // 3168 B
  __shared__ unsigned short attL[64][33];          // 4224 B
  __shared__ float wdw[80];                        // [8ch][9] + bias[8]
  int bz = blockIdx.z;
  int b = bz >> 3, gp = bz & 7;
  int h = blockIdx.y;
  int w0 = blockIdx.x * 64;
  int width = min(64, Wd - w0);
  int t = threadIdx.x;
  int c0 = gp * 8;
  // stage packed A-fragments (coalesced)
  const short8* src8 = (const short8*)kbwF + (size_t)gp * 1280;
  #pragma unroll
  for (int i = 0; i < 5; i++) fragL[t + i * 256] = src8[t + i * 256];
  // stage t2 patch: [8ch][5r][68c], rows h-2..h+2, cols w0-2..w0+65
  const unsigned short* t2u = (const unsigned short*)t2;
  for (int i = t; i < 8 * 5 * 68; i += 256) {
    int cl = i / 340, rem = i - cl * 340;
    int r = rem / 68, col = rem - r * 68;
    int hh = h + r - 2, ww = w0 + col - 2;
    unsigned short v = 0;
    if ((unsigned)hh < Hh && (unsigned)ww < Wd)
      v = t2u[((size_t)b * Cc + c0 + cl) * HWp + hh * Wd + ww];
    t2L[i] = v;
  }
  // dw weights + bias
  if (t < 72) wdw[t] = c21w[(c0 + t / 9) * 9 + t % 9];
  else if (t < 80) wdw[t] = c21b[c0 + (t - 72)];
  // stage att (bf16)
  const unsigned short* att_u = (const unsigned short*)att + (size_t)b * 32 * HWp;
  for (int i = t; i < 64 * 32; i += 256) {
    int px = i & 63, s = i >> 6;
    unsigned short v = 0;
    if (px < width) v = att_u[(size_t)s * HWp + h * Wd + w0 + px];
    attL[px][s] = v;
  }
  __syncthreads();
  // compute uf = dw3x3(t2)+bias into patchL (bf16, matches old standalone pass)
  for (int i = t; i < 8 * 3 * 66; i += 256) {
    int cl = i / 198, rem = i - cl * 198;
    int r = rem / 66, col = rem - r * 66;
    int hh = h + r - 1, ww = w0 + col - 1;
    unsigned short v = 0;
    if ((unsigned)hh < Hh && (unsigned)ww < Wd) {
      float acc = wdw[72 + cl];
      const float* wc = &wdw[cl * 9];
      #pragma unroll
      for (int ki = 0; ki < 3; ki++)
        #pragma unroll
        for (int kj = 0; kj < 3; kj++)
          acc = fmaf(wc[ki * 3 + kj], ubf(t2L[cl * 340 + (r + ki) * 68 + col + kj]), acc);
      v = f2bu(acc);
    }
    patchL[i] = v;
  }
  __syncthreads();
  int lane = t & 63, w = t >> 6;
  int n = lane & 15, q = lane >> 4;
  int pxl = w * 16 + n;
  float attR[8];
  #pragma unroll
  for (int mt = 0; mt < 8; mt++) attR[mt] = ubf(attL[pxl][4 * mt + q]);
  int offA[8];
  #pragma unroll
  for (int j = 0; j < 8; j++) {
    int k = q * 8 + j;
    int ci = k / 9, r = k - ci * 9, ki = r / 3, kj = r - ki * 3;
    offA[j] = ci * 198 + ki * 66 + pxl + kj;
  }
  int offB[4];
  #pragma unroll
  for (int j = 0; j < 4; j++) {
    int k = 32 + j, r = k - 27, ki = r / 3, kj = r - ki * 3;
    offB[j] = 3 * 198 + ki * 66 + pxl + kj;
  }
  const unsigned short* x1u = (const unsigned short*)x1 + (size_t)b * Cc * HWp + h * Wd + w0;
  unsigned short* outu = (unsigned short*)out + (size_t)b * Cc * HWp + h * Wd + w0;
  #pragma unroll
  for (int gl = 0; gl < 2; gl++) {
    int g = gp * 2 + gl;
    const short8* fgl = fragL + gl * 640;
    short8 b0, b1;
    #pragma unroll
    for (int j = 0; j < 8; j++) b0[j] = (short)patchL[gl * 792 + offA[j]];
    #pragma unroll
    for (int j = 0; j < 8; j++) b1[j] = 0;
    if (q == 0) {
      #pragma unroll
      for (int j = 0; j < 4; j++) b1[j] = (short)patchL[gl * 792 + offB[j]];
      b1[4] = (short)0x3F80;                 // B[36][*] = 1.0 (bias row)
    }
    f32x4 acc[8];
    #pragma unroll
    for (int mt = 0; mt < 8; mt++) acc[mt] = (f32x4){0.f, 0.f, 0.f, 0.f};
    #pragma unroll
    for (int mt = 0; mt < 8; mt++) {
      short8 a0 = fgl[mt * 64 + lane];
      acc[mt] = __builtin_amdgcn_mfma_f32_16x16x32_bf16(a0, b0, acc[mt], 0, 0, 0);
      short8 a1 = (short8){0,0,0,0,0,0,0,0};
      if (q == 0) a1 = fgl[512 + mt * 16 + n];
      acc[mt] = __builtin_amdgcn_mfma_f32_16x16x32_bf16(a1, b1, acc[mt], 0, 0, 0);
    }
    #pragma unroll
    for (int o = 0; o < 4; o++) {
      float P = 0.f;
      #pragma unroll
      for (int mt = 0; mt < 8; mt++) P += attR[mt] * acc[mt][o];
      P += __shfl_xor(P, 16);
      P += __shfl_xor(P, 32);
      if (o == q && pxl < width) {
        int c = g * 4 + q;
        float ufc = ubf(patchL[(gl * 4 + q) * 198 + 66 + pxl + 1]);   // center tap
        float xk = P * ga1[c] + ufc;
        float xv = xk * ubf(x1u[(size_t)c * HWp + pxl]) * scaV[b * 64 + c];
        outu[(size_t)c * HWp + pxl] = f2bu(xv);
      }
    }
  }
}

// ---------------- DFT pass via MFMA (5-ct loop, fragment reuse) ----------------
__global__ __launch_bounds__(64) void k_cpass_mfma(
    const bf16* __restrict__ inr, const bf16* __restrict__ ini,
    const short* __restrict__ cosF, const short* __restrict__ sinF,
    bf16* __restrict__ outr, bf16* __restrict__ outi,
    float sgn, float scale,
    const float* __restrict__ sclr, const float* __restrict__ scli) {
  int plane = blockIdx.z;
  int a0 = blockIdx.x * 16;
  int cth = blockIdx.y * 5;          // c-half: ct 0..4 or 5..9
  int lane = threadIdx.x;
  int n = lane & 15, q = lane >> 4;
  const unsigned short* pr = (const unsigned short*)inr + (size_t)plane * HWp;
  const unsigned short* pi = ini ? (const unsigned short*)ini + (size_t)plane * HWp : nullptr;
  float srm = sclr ? sclr[plane] : 1.f;
  float sim = scli ? scli[plane] : 1.f;
  short8 br[5], bi[5];
  #pragma unroll
  for (int kc = 0; kc < 5; kc++) {
    br[kc] = *(const short8*)(pr + (a0 + n) * 160 + kc * 32 + q * 8);
    if (pi) bi[kc] = *(const short8*)(pi + (a0 + n) * 160 + kc * 32 + q * 8);
  }
  const short8* cf = (const short8*)cosF;
  const short8* sf = (const short8*)sinF;
  unsigned short* qr = (unsigned short*)outr + (size_t)plane * HWp;
  unsigned short* qi = (unsigned short*)outi + (size_t)plane * HWp;
  for (int ctl = 0; ctl < 5; ctl++) {
    int ct = cth + ctl;
    f32x4 arr = (f32x4){0.f,0.f,0.f,0.f}, asr = (f32x4){0.f,0.f,0.f,0.f};
    f32x4 ari = (f32x4){0.f,0.f,0.f,0.f}, asi = (f32x4){0.f,0.f,0.f,0.f};
    #pragma unroll
    for (int kc = 0; kc < 5; kc++) {
      short8 ca = cf[(ct * 5 + kc) * 64 + lane];
      short8 sa = sf[(ct * 5 + kc) * 64 + lane];
      arr = __builtin_amdgcn_mfma_f32_16x16x32_bf16(ca, br[kc], arr, 0, 0, 0);
      asr = __builtin_amdgcn_mfma_f32_16x16x32_bf16(sa, br[kc], asr, 0, 0, 0);
      if (pi) {
        ari = __builtin_amdgcn_mfma_f32_16x16x32_bf16(ca, bi[kc], ari, 0, 0, 0);
        asi = __builtin_amdgcn_mfma_f32_16x16x32_bf16(sa, bi[kc], asi, 0, 0, 0);
      }
    }
    #pragma unroll
    for (int j = 0; j < 4; j++) {
      int c = ct * 16 + q * 4 + j;
      float xc = srm * arr[j], xs = srm * asr[j];
      float ic = pi ? sim * ari[j] : 0.f, is = pi ? sim * asi[j] : 0.f;
      float orv = (xc - sgn * is) * scale;
      float oiv = (sgn * xs + ic) * scale;
      qr[c * 160 + a0 + n] = f2bu(orv);
      qi[c * 160 + a0 + n] = f2bu(oiv);
    }
  }
}

// ---------------- final inverse DFT pass, fused |.|, *gamma, += y ----------------
__global__ __launch_bounds__(64) void k_cpass_final_mfma(
    const bf16* __restrict__ inr, const bf16* __restrict__ ini,
    const short* __restrict__ cosF, const short* __restrict__ sinF,
    float sgn, float scale,
    const float* __restrict__ gamma, float* __restrict__ dout) {
  int plane = blockIdx.z;
  int a0 = blockIdx.x * 16;
  int cth = blockIdx.y * 5;
  int lane = threadIdx.x;
  int n = lane & 15, q = lane >> 4;
  const unsigned short* pr = (const unsigned short*)inr + (size_t)plane * HWp;
  const unsigned short* pi = (const unsigned short*)ini + (size_t)plane * HWp;
  short8 br[5], bi[5];
  #pragma unroll
  for (int kc = 0; kc < 5; kc++) {
    br[kc] = *(const short8*)(pr + (a0 + n) * 160 + kc * 32 + q * 8);
    bi[kc] = *(const short8*)(pi + (a0 + n) * 160 + kc * 32 + q * 8);
  }
  const short8* cf = (const short8*)cosF;
  const short8* sf = (const short8*)sinF;
  float gm = gamma[plane & 63];
  float* dp = dout + (size_t)plane * HWp;
  for (int ctl = 0; ctl < 5; ctl++) {
    int ct = cth + ctl;
    f32x4 arr = (f32x4){0.f,0.f,0.f,0.f}, asr = (f32x4){0.f,0.f,0.f,0.f};
    f32x4 ari = (f32x4){0.f,0.f,0.f,0.f}, asi = (f32x4){0.f,0.f,0.f,0.f};
    #pragma unroll
    for (int kc = 0; kc < 5; kc++) {
      short8 ca = cf[(ct * 5 + kc) * 64 + lane];
      short8 sa = sf[(ct * 5 + kc) * 64 + lane];
      arr = __builtin_amdgcn_mfma_f32_16x16x32_bf16(ca, br[kc], arr, 0, 0, 0);
      asr = __builtin_amdgcn_mfma_f32_16x16x32_bf16(sa, br[kc], asr, 0, 0, 0);
      ari = __builtin_amdgcn_mfma_f32_16x16x32_bf16(ca, bi[kc], ari, 0, 0, 0);
      asi = __builtin_amdgcn_mfma_f32_16x16x32_bf16(sa, bi[kc], asi, 0, 0, 0);
    }
    #pragma unroll
    for (int j = 0; j < 4; j++) {
      int c = ct * 16 + q * 4 + j;
      float orv = (arr[j] - sgn * asi[j]) * scale;
      float oiv = (sgn * asr[j] + ari[j]) * scale;
      float z = sqrtf(orv * orv + oiv * oiv);
      dp[c * 160 + a0 + n] += z * gm;   // dout currently holds y
    }
  }
}

// ---------------- fc1 (128->256) + simple_gate, MFMA ----------------
__global__ __launch_bounds__(256) void k_fc1_mfma(
    const bf16* __restrict__ Fr, const bf16* __restrict__ Fi,
    const short* __restrict__ wA, const float* __restrict__ bias,
    bf16* __restrict__ G1, bf16* __restrict__ G2) {
  int b = blockIdx.z;
  int lane = threadIdx.x & 63, w = threadIdx.x >> 6;
  int px = blockIdx.x * 64 + w * 16 + (lane & 15);
  int q = lane >> 4;
  const unsigned short* fr = (const unsigned short*)Fr + (size_t)b * Cc * HWp;
  const unsigned short* fi = (const unsigned short*)Fi + (size_t)b * Cc * HWp;
  const short8* wf = (const short8*)wA;
  f32x4 acc[16];
  #pragma unroll
  for (int mt = 0; mt < 16; mt++) acc[mt] = (f32x4){0.f, 0.f, 0.f, 0.f};
  #pragma unroll
  for (int kc = 0; kc < 4; kc++) {
    const unsigned short* basep = (kc < 2) ? (fr + (size_t)(kc * 32) * HWp)
                                           : (fi + (size_t)((kc - 2) * 32) * HWp);
    short8 bfv;
    #pragma unroll
    for (int j = 0; j < 8; j++) bfv[j] = (short)basep[(size_t)(q * 8 + j) * HWp + px];
    #pragma unroll
    for (int mt = 0; mt < 16; mt++) {
      short8 af = wf[(mt * 4 + kc) * 64 + lane];
      acc[mt] = __builtin_amdgcn_mfma_f32_16x16x32_bf16(af, bfv, acc[mt], 0, 0, 0);
    }
  }
  unsigned short* g1 = (unsigned short*)G1 + (size_t)b * Cc * HWp;
  unsigned short* g2 = (unsigned short*)G2 + (size_t)b * Cc * HWp;
  #pragma unroll
  for (int mt = 0; mt < 8; mt++)
    #pragma unroll
    for (int j = 0; j < 4; j++) {
      int o = mt * 16 + q * 4 + j;
      float v1 = acc[mt][j] + bias[o];
      float v2 = acc[mt + 8][j] + bias[o + 128];
      unsigned short hv = f2bu(v1 * v2);
      if (o < 64) g1[(size_t)o * HWp + px] = hv;
      else        g2[(size_t)(o - 64) * HWp + px] = hv;
    }
}

// ---------------- fc2 (128->128) MFMA, split output into r / i planes ----------------
__global__ __launch_bounds__(256) void k_fc2_mfma(
    const bf16* __restrict__ G1, const bf16* __restrict__ G2,
    const short* __restrict__ wA, const float* __restrict__ bias,
    bf16* __restrict__ Or, bf16* __restrict__ Oi) {
  int b = blockIdx.z;
  int lane = threadIdx.x & 63, w = threadIdx.x >> 6;
  int px = blockIdx.x * 64 + w * 16 + (lane & 15);
  int q = lane >> 4;
  const unsigned short* g1 = (const unsigned short*)G1 + (size_t)b * Cc * HWp;
  const unsigned short* g2 = (const unsigned short*)G2 + (size_t)b * Cc * HWp;
  const short8* wf = (const short8*)wA;
  f32x4 acc[8];
  #pragma unroll
  for (int mt = 0; mt < 8; mt++) acc[mt] = (f32x4){0.f, 0.f, 0.f, 0.f};
  #pragma unroll
  for (int kc = 0; kc < 4; kc++) {
    const unsigned short* basep = (kc < 2) ? (g1 + (size_t)(kc * 32) * HWp)
                                           : (g2 + (size_t)((kc - 2) * 32) * HWp);
    short8 bfv;
    #pragma unroll
    for (int j = 0; j < 8; j++) bfv[j] = (short)basep[(size_t)(q * 8 + j) * HWp + px];
    #pragma unroll
    for (int mt = 0; mt < 8; mt++) {
      short8 af = wf[(mt * 4 + kc) * 64 + lane];
      acc[mt] = __builtin_amdgcn_mfma_f32_16x16x32_bf16(af, bfv, acc[mt], 0, 0, 0);
    }
  }
  unsigned short* orp = (unsigned short*)Or + (size_t)b * Cc * HWp;
  unsigned short* oip = (unsigned short*)Oi + (size_t)b * Cc * HWp;
  #pragma unroll
  for (int mt = 0; mt < 8; mt++)
    #pragma unroll
    for (int j = 0; j < 4; j++) {
      int o = mt * 16 + q * 4 + j;
      unsigned short hv = f2bu(acc[mt][j] + bias[o]);
      if (o < 64) orp[(size_t)o * HWp + px] = hv;
      else        oip[(size_t)(o - 64) * HWp + px] = hv;
    }
}

extern "C" void kernel_launch(void* const* d_in, const int* in_sizes, int n_in,
                              void* d_out, int out_size, void* d_ws, size_t ws_size,
                              hipStream_t stream) {
  const float* inp   = (const float*)d_in[0];
  const float* n1w   = (const float*)d_in[1];
  const float* n1b   = (const float*)d_in[2];
  const float* n2w   = (const float*)d_in[3];
  const float* n2b   = (const float*)d_in[4];
  const float* scaw  = (const float*)d_in[5];
  const float* scab  = (const float*)d_in[6];
  const float* c11aw = (const float*)d_in[7];
  const float* c11ab = (const float*)d_in[8];
  const float* c11bw = (const float*)d_in[9];
  const float* c11bb = (const float*)d_in[10];
  const float* c1w   = (const float*)d_in[11];
  const float* c1b   = (const float*)d_in[12];
  const float* c21w  = (const float*)d_in[13];
  const float* c21b  = (const float*)d_in[14];
  const float* c2aw  = (const float*)d_in[15];
  const float* c2ab  = (const float*)d_in[16];
  const float* c2cw  = (const float*)d_in[17];
  const float* c2cb  = (const float*)d_in[18];
  const float* c211w = (const float*)d_in[19];
  const float* c211b = (const float*)d_in[20];
  const float* c3w   = (const float*)d_in[21];
  const float* c3b   = (const float*)d_in[22];
  const float* kbw   = (const float*)d_in[23];
  const float* kbb   = (const float*)d_in[24];
  const float* ga1   = (const float*)d_in[25];
  const float* attg  = (const float*)d_in[26];
  const float* beta  = (const float*)d_in[27];
  const float* gamma = (const float*)d_in[28];
  const float* fc1w  = (const float*)d_in[29];
  const float* fc1b  = (const float*)d_in[30];
  const float* fc2w  = (const float*)d_in[31];
  const float* fc2b  = (const float*)d_in[32];
  const float* fscaw = (const float*)d_in[33];
  const float* fscab = (const float*)d_in[34];

  const size_t S = (size_t)Bn * Cc * HWp;   // 3,276,800 elements per slot
  bf16* A  = (bf16*)d_ws;                   // 4 bf16 slots = 26.2 MB total
  bf16* Bs = A + S;
  bf16* Cs = A + 2 * S;
  bf16* Ds = A + 3 * S;
  float* smalls = (float*)(A + 4 * S);      // fp32 smalls
  float* xm   = smalls;
  float* scaV = smalls + 128;
  float* rmv  = smalls + 256;               // rmv[128]|imv[128]
  float* sra  = smalls + 512;               // sra[128]|sia[128]
  short* wS   = (short*)(smalls + 1024);    // bf16 frag tables
  short* wAf1 = wS;                         // 32768
  short* wAf2 = wAf1 + 32768;               // 16384
  short* cosF = wAf2 + 16384;               // 25600
  short* sinF = cosF + 25600;               // 25600
  short* wA_c11a = sinF + 25600;            // 4096
  short* wA_c1   = wA_c11a + 4096;          // 4096
  short* wA_c3   = wA_c1 + 4096;            // 4096
  short* wA_att  = wA_c3 + 4096;            // 3072
  short* kbwF    = wA_att + 3072;           // 81920 used
  bf16* gbuf = Bs;            // [B,32,HW] (first half of Bs)
  bf16* attb = Bs + S / 2;    // [B,32,HW] (second half of Bs)
  float* yb  = (float*)d_out; // y lives in d_out (fp32)

  dim3 cgrid(10, 2, Bn * Cc);
  dim3 pgrid(400, 1, Bn);

  k_prep_all<<<dim3(672), dim3(256), 0, stream>>>(kbw, kbb, kbwF, fc1w, fc2w, wAf1, wAf2,
                                                  cosF, sinF, c11aw, c1w, c3w, c2cw, c211w,
                                                  attg, wA_c11a, wA_c1, wA_c3, wA_att);
  k_ln<<<dim3(800), dim3(256), 0, stream>>>(inp, n1w, n1b, A);          // A = x
  k_meanhw<<<dim3(128), dim3(256), 0, stream>>>(A, xm);
  k_small_mv<<<dim3(1), dim3(128), 0, stream>>>(xm, scaw, scab, scaV, 0);
  k_conv1x1_dual<<<pgrid, dim3(256), 0, stream>>>(A, wA_c11a, c11ab, wA_c1, c1b, Bs, Ds); // B=t1 D=t2
  k_c11b_direct<<<dim3(3, 10, Bn * 16), dim3(256), 0, stream>>>(Bs, c11bw, c11bb, Cs); // C = x1
  k_c2a4<<<dim3(25, 32, Bn), dim3(256), 0, stream>>>(A, c2aw, c2ab, gbuf);         // B.lo = g
  k_att_mfma<<<pgrid, dim3(256), 0, stream>>>(gbuf, A, wA_att, c2cb, c211b, attg, attb); // B.hi
  k_kba_mfma<<<dim3(3, 160, Bn * 8), dim3(256), 0, stream>>>(Ds, attb, Cs, scaV, kbwF, ga1,
                                                             c21w, c21b, A);       // A = xprod
  k_c3y_ln2<<<pgrid, dim3(256), 0, stream>>>(A, wA_c3, c3b, beta, inp, yb, n2w, n2b, Bs); // y, Bs=X
  // forward FFT2 (MFMA)
  k_cpass_mfma<<<cgrid, dim3(64), 0, stream>>>(Bs, (const bf16*)nullptr, cosF, sinF, Cs, Ds, -1.f, SCL, nullptr, nullptr);
  k_cpass_mfma<<<cgrid, dim3(64), 0, stream>>>(Cs, Ds, cosF, sinF, A, Bs, -1.f, SCL, nullptr, nullptr);
  k_fc1_mfma<<<pgrid, dim3(256), 0, stream>>>(A, Bs, wAf1, fc1b, Cs, Ds);          // C,D = gated
  k_fc2_mfma<<<pgrid, dim3(256), 0, stream>>>(Cs, Ds, wAf2, fc2b, A, Bs);          // A = r, Bs = i
  k_meanhw2<<<dim3(256), dim3(256), 0, stream>>>(A, Bs, rmv);                      // rmv|imv
  k_small_mv2<<<dim3(1), dim3(256), 0, stream>>>(rmv, fscaw, fscab, sra);          // sra|sia
  // inverse FFT2 (MFMA) with per-plane (1+ra)/(1+ia) scaling fused into first pass
  k_cpass_mfma<<<cgrid, dim3(64), 0, stream>>>(A, Bs, cosF, sinF, Cs, Ds, 1.f, SCL, sra, sra + 128);
  k_cpass_final_mfma<<<cgrid, dim3(64), 0, stream>>>(Cs, Ds, cosF, sinF, 1.f, SCL, gamma, yb);
}

// Round 14
// 446.040 us; speedup vs baseline: 1.0455x; 1.0455x over previous
//
#include <hip/hip_runtime.h>
#include <hip/hip_bf16.h>

typedef __hip_bfloat16 bf16;
typedef __attribute__((ext_vector_type(8))) short short8;
typedef __attribute__((ext_vector_type(4))) float f32x4;
typedef __attribute__((ext_vector_type(4))) unsigned short u16x4;

#define Hh 160
#define Wd 160
#define HWp (Hh*Wd)       // 25600
#define Bn 2
#define Cc 64
#define NPIX (Bn*HWp)     // 51200
#define SCL 0.07905694150420949f   // 1/sqrt(160)
#define TWO_PI_160 0.039269908169872414f  // 2*pi/160

static __device__ __forceinline__ float b2f(bf16 x) { return __bfloat162float(x); }
static __device__ __forceinline__ bf16 f2b(float f) { return __float2bfloat16(f); }
static __device__ __forceinline__ unsigned short f2bu(float f) {
  union { bf16 h; unsigned short u; } z; z.h = __float2bfloat16(f); return z.u;
}
static __device__ __forceinline__ float ubf(unsigned short u) {
  union { unsigned int i; float f; } z; z.i = ((unsigned int)u) << 16; return z.f;
}

// ---------------- LayerNorm over channel dim, single-pass ----------------
__global__ void k_ln(const float* __restrict__ in, const float* __restrict__ w,
                     const float* __restrict__ bb, bf16* __restrict__ out) {
  __shared__ float2 sm[4][64];
  int t = threadIdx.x;
  int pxl = t & 63, cq = t >> 6;
  int pix = blockIdx.x * 64 + pxl;          // 800 blocks cover NPIX
  int b = pix / HWp, p = pix - b * HWp;
  const float* src = in + ((size_t)b * Cc + cq * 16) * HWp + p;
  float v[16];
  float s = 0.f, s2 = 0.f;
  #pragma unroll
  for (int i = 0; i < 16; i++) {
    v[i] = src[(size_t)i * HWp];
    s += v[i]; s2 += v[i] * v[i];
  }
  sm[cq][pxl] = make_float2(s, s2);
  __syncthreads();
  float S = 0.f, S2 = 0.f;
  #pragma unroll
  for (int k = 0; k < 4; k++) { float2 z = sm[k][pxl]; S += z.x; S2 += z.y; }
  float mu = S * (1.f / 64.f);
  float var = S2 * (1.f / 64.f) - mu * mu;
  float rs = rsqrtf(fmaxf(var, 0.f) + 1e-6f);
  bf16* dst = out + ((size_t)b * Cc + cq * 16) * HWp + p;
  #pragma unroll
  for (int i = 0; i < 16; i++) {
    int c = cq * 16 + i;
    dst[(size_t)i * HWp] = f2b((v[i] - mu) * rs * w[c] + bb[c]);
  }
}

// ---------------- mean over HW per (b,c) plane (bf16 in) ----------------
__global__ void k_meanhw(const bf16* __restrict__ in, float* __restrict__ out) {
  int bc = blockIdx.x;
  const bf16* src = in + (size_t)bc * HWp;
  int t = threadIdx.x;
  float s = 0.f;
  for (int i = t; i < HWp; i += 256) s += b2f(src[i]);
  __shared__ float sm[256];
  sm[t] = s; __syncthreads();
  for (int off = 128; off; off >>= 1) { if (t < off) sm[t] += sm[t + off]; __syncthreads(); }
  if (t == 0) out[bc] = sm[0] * (1.f / HWp);
}

// ---------------- fused dual mean: bc<128 from in0, else in1 ----------------
__global__ void k_meanhw2(const bf16* __restrict__ in0, const bf16* __restrict__ in1,
                          float* __restrict__ out) {
  int bc = blockIdx.x;   // 0..255
  const bf16* src = (bc < 128) ? (in0 + (size_t)bc * HWp) : (in1 + (size_t)(bc - 128) * HWp);
  int t = threadIdx.x;
  float s = 0.f;
  for (int i = t; i < HWp; i += 256) s += b2f(src[i]);
  __shared__ float sm[256];
  sm[t] = s; __syncthreads();
  for (int off = 128; off; off >>= 1) { if (t < off) sm[t] += sm[t + off]; __syncthreads(); }
  if (t == 0) out[bc] = sm[0] * (1.f / HWp);
}

// ---------------- small matvec ----------------
__global__ void k_small_mv(const float* __restrict__ xin, const float* __restrict__ w,
                           const float* __restrict__ bias, float* __restrict__ out, int addone) {
  int t = threadIdx.x;              // 128 threads
  int b = t >> 6, o = t & 63;
  float acc = bias[o];
  for (int k = 0; k < 64; k++) acc += w[o * 64 + k] * xin[b * 64 + k];
  out[t] = addone ? (1.f + acc) : acc;
}

// ---------------- fused dual small matvec ----------------
__global__ void k_small_mv2(const float* __restrict__ xin, const float* __restrict__ w,
                            const float* __restrict__ bias, float* __restrict__ out) {
  int t = threadIdx.x;              // 256 threads
  int half = t >> 7, r = t & 127;
  int b = r >> 6, o = r & 63;
  const float* x = xin + half * 128 + b * 64;
  float acc = bias[o];
  for (int k = 0; k < 64; k++) acc += w[o * 64 + k] * x[k];
  out[half * 128 + r] = 1.f + acc;
}

// ---------------- c2a vectorized: grouped 3x3, 64->32, groups=32, 4 px/thread ----------------
__global__ void k_c2a4(const bf16* __restrict__ in, const float* __restrict__ w,
                       const float* __restrict__ bias, bf16* __restrict__ out) {
  int t = threadIdx.x;
  int o = blockIdx.y, b = blockIdx.z;       // o 0..31
  int pq = blockIdx.x * 256 + t;            // grid.x = 25
  int h = pq / 40, x4 = (pq - h * 40) * 4;
  float bs = bias[o];
  float acc[4] = {bs, bs, bs, bs};
  #pragma unroll
  for (int ci = 0; ci < 2; ci++) {
    const unsigned short* src = (const unsigned short*)in + ((size_t)b * Cc + o * 2 + ci) * HWp;
    float wv[9];
    #pragma unroll
    for (int i = 0; i < 9; i++) wv[i] = w[(o * 2 + ci) * 9 + i];
    #pragma unroll
    for (int ki = 0; ki < 3; ki++) {
      int hh = h + ki - 1;
      if ((unsigned)hh >= Hh) continue;
      const unsigned short* row = src + hh * Wd + x4;
      float v[6];
      u16x4 m = *(const u16x4*)row;
      v[1] = ubf(m[0]); v[2] = ubf(m[1]); v[3] = ubf(m[2]); v[4] = ubf(m[3]);
      v[0] = (x4 > 0) ? ubf(row[-1]) : 0.f;
      v[5] = (x4 + 4 < Wd) ? ubf(row[4]) : 0.f;
      #pragma unroll
      for (int j = 0; j < 4; j++)
        #pragma unroll
        for (int kj = 0; kj < 3; kj++)
          acc[j] = fmaf(wv[ki * 3 + kj], v[j + kj], acc[j]);
    }
  }
  u16x4 pk;
  #pragma unroll
  for (int j = 0; j < 4; j++) pk[j] = f2bu(acc[j]);
  *(u16x4*)((unsigned short*)out + ((size_t)b * 32 + o) * HWp + h * Wd + x4) = pk;
}

// ---------------- depthwise 3x3 vectorized, 4 px/thread ----------------
__global__ void k_c21dw4(const bf16* __restrict__ in, const float* __restrict__ w,
                         const float* __restrict__ bias, bf16* __restrict__ out) {
  int t = threadIdx.x;
  int c = blockIdx.y, b = blockIdx.z;
  int pq = blockIdx.x * 256 + t;            // grid.x = 25
  int h = pq / 40, x4 = (pq - h * 40) * 4;
  const unsigned short* src = (const unsigned short*)in + ((size_t)b * Cc + c) * HWp;
  float wv[9];
  #pragma unroll
  for (int i = 0; i < 9; i++) wv[i] = w[c * 9 + i];
  float bs = bias[c];
  float acc[4] = {bs, bs, bs, bs};
  #pragma unroll
  for (int ki = 0; ki < 3; ki++) {
    int hh = h + ki - 1;
    if ((unsigned)hh >= Hh) continue;
    const unsigned short* row = src + hh * Wd + x4;
    float v[6];
    u16x4 m = *(const u16x4*)row;
    v[1] = ubf(m[0]); v[2] = ubf(m[1]); v[3] = ubf(m[2]); v[4] = ubf(m[3]);
    v[0] = (x4 > 0) ? ubf(row[-1]) : 0.f;
    v[5] = (x4 + 4 < Wd) ? ubf(row[4]) : 0.f;
    #pragma unroll
    for (int j = 0; j < 4; j++)
      #pragma unroll
      for (int kj = 0; kj < 3; kj++)
        acc[j] = fmaf(wv[ki * 3 + kj], v[j + kj], acc[j]);
  }
  u16x4 pk;
  #pragma unroll
  for (int j = 0; j < 4; j++) pk[j] = f2bu(acc[j]);
  *(u16x4*)((unsigned short*)out + ((size_t)b * Cc + c) * HWp + h * Wd + x4) = pk;
}

// ---------------- fused weight prep ----------------
__global__ void k_prep_all(const float* __restrict__ kbw, const float* __restrict__ kbb,
                           short* __restrict__ kbwF,
                           const float* __restrict__ fc1w, const float* __restrict__ fc2w,
                           short* __restrict__ wAf1, short* __restrict__ wAf2,
                           short* __restrict__ cosF, short* __restrict__ sinF,
                           const float* __restrict__ c11aw, const float* __restrict__ c1w,
                           const float* __restrict__ c3w, const float* __restrict__ c2cw,
                           const float* __restrict__ c211w, const float* __restrict__ attg,
                           short* __restrict__ wA_c11a, short* __restrict__ wA_c1,
                           short* __restrict__ wA_c3, short* __restrict__ wA_att) {
  int i = blockIdx.x * 256 + threadIdx.x;   // 172032 total (672 blocks)
  if (i < 81920) {
    int g = i / 5120, r = i - g * 5120;
    float v = 0.f;
    if (r < 4096) {
      int j = r & 7, lane = (r >> 3) & 63, mt = r >> 9;
      int m = mt * 16 + (lane & 15);
      int s = m >> 2, o = m & 3;
      int k = (lane >> 4) * 8 + j;
      v = kbw[s * 2304 + g * 144 + o * 36 + k];
    } else {
      int r2 = r - 4096;
      int j = r2 & 7, n = (r2 >> 3) & 15, mt = r2 >> 7;
      int m = mt * 16 + n;
      int s = m >> 2, o = m & 3;
      int k = 32 + j;
      if (k < 36) v = kbw[s * 2304 + g * 144 + o * 36 + k];
      else if (k == 36) v = kbb[s * 64 + g * 4 + o];
    }
    kbwF[i] = (short)f2bu(v);
  } else if (i < 131072) {
    int i1 = i - 81920;
    if (i1 < 32768) {
      int j = i1 & 7, lane = (i1 >> 3) & 63, fk = i1 >> 9;
      int kc = fk & 3, mt = fk >> 2;
      int o = mt * 16 + (lane & 15);
      int k = kc * 32 + (lane >> 4) * 8 + j;
      wAf1[i1] = (short)f2bu(fc1w[o * 128 + k]);
    } else {
      int i2 = i1 - 32768;
      int j = i2 & 7, lane = (i2 >> 3) & 63, fk = i2 >> 9;
      int kc = fk & 3, mt = fk >> 2;
      int o = mt * 16 + (lane & 15);
      int k = kc * 32 + (lane >> 4) * 8 + j;
      wAf2[i2] = (short)f2bu(fc2w[o * 128 + k]);
    }
  } else if (i < 156672) {
    int i2 = i - 131072;
    int j = i2 & 7, lane = (i2 >> 3) & 63, fk = i2 >> 9;   // fk = ct*5+kc
    int kc = fk % 5, ct = fk / 5;
    int c = ct * 16 + (lane & 15);
    int bb2 = kc * 32 + (lane >> 4) * 8 + j;
    int m = (bb2 * c) % 160;
    float sv, cv;
    __sincosf((float)m * TWO_PI_160, &sv, &cv);
    cosF[i2] = (short)f2bu(cv);
    sinF[i2] = (short)f2bu(sv);
  } else {
    int i3 = i - 156672;
    if (i3 < 12288) {
      int wi = i3 / 4096, r = i3 - wi * 4096;
      int j = r & 7, lane = (r >> 3) & 63, fk = r >> 9;
      int kc = fk & 1, mt = fk >> 1;
      int o = mt * 16 + (lane & 15);
      int k = kc * 32 + (lane >> 4) * 8 + j;
      const float* w = (wi == 0) ? c11aw : (wi == 1) ? c1w : c3w;
      short* dst = (wi == 0) ? wA_c11a : (wi == 1) ? wA_c1 : wA_c3;
      dst[r] = (short)f2bu(w[o * 64 + k]);
    } else {
      int r = i3 - 12288;
      int j = r & 7, lane = (r >> 3) & 63, fk = r >> 9;
      int kc = fk % 3, mt = fk / 3;
      int s = mt * 16 + (lane & 15);
      int k = kc * 32 + (lane >> 4) * 8 + j;
      float v;
      if (k < 16) v = c2cw[s * 16 + k] * attg[s];
      else if (k < 32) v = 0.f;
      else v = c211w[s * 64 + (k - 32)];
      wA_att[r] = (short)f2bu(v);
    }
  }
}

// ---------------- dual 1x1 conv 64->64 via MFMA (t1 and t2 share input fragments) ----------------
__global__ __launch_bounds__(256) void k_conv1x1_dual(
    const bf16* __restrict__ in, const short* __restrict__ wA1,
    const float* __restrict__ b1, const short* __restrict__ wA2,
    const float* __restrict__ b2, bf16* __restrict__ out1, bf16* __restrict__ out2) {
  int b = blockIdx.z;
  int lane = threadIdx.x & 63, w = threadIdx.x >> 6;
  int px = blockIdx.x * 64 + w * 16 + (lane & 15);
  int q = lane >> 4;
  const unsigned short* src = (const unsigned short*)in + (size_t)b * Cc * HWp;
  const short8* wf1 = (const short8*)wA1;
  const short8* wf2 = (const short8*)wA2;
  f32x4 acc1[4], acc2[4];
  #pragma unroll
  for (int mt = 0; mt < 4; mt++) {
    acc1[mt] = (f32x4){0.f, 0.f, 0.f, 0.f};
    acc2[mt] = (f32x4){0.f, 0.f, 0.f, 0.f};
  }
  #pragma unroll
  for (int kc = 0; kc < 2; kc++) {
    short8 bfv;
    #pragma unroll
    for (int j = 0; j < 8; j++) bfv[j] = (short)src[(size_t)(kc * 32 + q * 8 + j) * HWp + px];
    #pragma unroll
    for (int mt = 0; mt < 4; mt++) {
      short8 a1 = wf1[(mt * 2 + kc) * 64 + lane];
      acc1[mt] = __builtin_amdgcn_mfma_f32_16x16x32_bf16(a1, bfv, acc1[mt], 0, 0, 0);
      short8 a2 = wf2[(mt * 2 + kc) * 64 + lane];
      acc2[mt] = __builtin_amdgcn_mfma_f32_16x16x32_bf16(a2, bfv, acc2[mt], 0, 0, 0);
    }
  }
  unsigned short* d1 = (unsigned short*)out1 + (size_t)b * Cc * HWp;
  unsigned short* d2 = (unsigned short*)out2 + (size_t)b * Cc * HWp;
  #pragma unroll
  for (int mt = 0; mt < 4; mt++)
    #pragma unroll
    for (int j = 0; j < 4; j++) {
      int o = mt * 16 + q * 4 + j;
      d1[(size_t)o * HWp + px] = f2bu(acc1[mt][j] + b1[o]);
      d2[(size_t)o * HWp + px] = f2bu(acc2[mt][j] + b2[o]);
    }
}

// ---------------- c3 1x1 conv + residual + FUSED LayerNorm2 ----------------
__global__ __launch_bounds__(256) void k_c3y_ln2(
    const bf16* __restrict__ in, const short* __restrict__ wA,
    const float* __restrict__ bias, const float* __restrict__ beta,
    const float* __restrict__ inp, float* __restrict__ y,
    const float* __restrict__ n2w, const float* __restrict__ n2b,
    bf16* __restrict__ Xout) {
  int b = blockIdx.z;
  int lane = threadIdx.x & 63, w = threadIdx.x >> 6;
  int px = blockIdx.x * 64 + w * 16 + (lane & 15);
  int q = lane >> 4;
  const unsigned short* src = (const unsigned short*)in + (size_t)b * Cc * HWp;
  const short8* wf = (const short8*)wA;
  f32x4 acc[4];
  #pragma unroll
  for (int mt = 0; mt < 4; mt++) acc[mt] = (f32x4){0.f, 0.f, 0.f, 0.f};
  #pragma unroll
  for (int kc = 0; kc < 2; kc++) {
    short8 bfv;
    #pragma unroll
    for (int j = 0; j < 8; j++) bfv[j] = (short)src[(size_t)(kc * 32 + q * 8 + j) * HWp + px];
    #pragma unroll
    for (int mt = 0; mt < 4; mt++) {
      short8 af = wf[(mt * 2 + kc) * 64 + lane];
      acc[mt] = __builtin_amdgcn_mfma_f32_16x16x32_bf16(af, bfv, acc[mt], 0, 0, 0);
    }
  }
  float yv[4][4];
  float s = 0.f, s2 = 0.f;
  #pragma unroll
  for (int mt = 0; mt < 4; mt++)
    #pragma unroll
    for (int j = 0; j < 4; j++) {
      int o = mt * 16 + q * 4 + j;
      size_t oi = ((size_t)b * Cc + o) * HWp + px;
      float v = inp[oi] + (acc[mt][j] + bias[o]) * beta[o];
      y[oi] = v;
      yv[mt][j] = v;
      s += v; s2 += v * v;
    }
  s  += __shfl_xor(s, 16);  s  += __shfl_xor(s, 32);
  s2 += __shfl_xor(s2, 16); s2 += __shfl_xor(s2, 32);
  float mu = s * (1.f / 64.f);
  float var = s2 * (1.f / 64.f) - mu * mu;
  float rs = rsqrtf(fmaxf(var, 0.f) + 1e-6f);
  unsigned short* Xu = (unsigned short*)Xout + (size_t)b * Cc * HWp;
  #pragma unroll
  for (int mt = 0; mt < 4; mt++)
    #pragma unroll
    for (int j = 0; j < 4; j++) {
      int o = mt * 16 + q * 4 + j;
      Xu[(size_t)o * HWp + px] = f2bu((yv[mt][j] - mu) * rs * n2w[o] + n2b[o]);
    }
}

// ---------------- att via MFMA: M=32, K = [gate16 | pad16 | x64] ----------------
__global__ __launch_bounds__(256) void k_att_mfma(
    const bf16* __restrict__ g, const bf16* __restrict__ x,
    const short* __restrict__ wA, const float* __restrict__ c2cb,
    const float* __restrict__ c211b, const float* __restrict__ attg,
    bf16* __restrict__ att) {
  int b = blockIdx.z;
  int lane = threadIdx.x & 63, w = threadIdx.x >> 6;
  int px = blockIdx.x * 64 + w * 16 + (lane & 15);
  int q = lane >> 4;
  const unsigned short* gs = (const unsigned short*)g + (size_t)b * 32 * HWp;
  const unsigned short* xs = (const unsigned short*)x + (size_t)b * Cc * HWp;
  const short8* wf = (const short8*)wA;
  f32x4 acc[2];
  acc[0] = (f32x4){0.f, 0.f, 0.f, 0.f};
  acc[1] = (f32x4){0.f, 0.f, 0.f, 0.f};
  {
    short8 bfv;
    #pragma unroll
    for (int j = 0; j < 8; j++) {
      int k = q * 8 + j;
      short v = 0;
      if (q < 2) {
        float gv = ubf(gs[(size_t)k * HWp + px]) * ubf(gs[(size_t)(16 + k) * HWp + px]);
        v = (short)f2bu(gv);
      }
      bfv[j] = v;
    }
    #pragma unroll
    for (int mt = 0; mt < 2; mt++) {
      short8 af = wf[(mt * 3 + 0) * 64 + lane];
      acc[mt] = __builtin_amdgcn_mfma_f32_16x16x32_bf16(af, bfv, acc[mt], 0, 0, 0);
    }
  }
  #pragma unroll
  for (int kc = 1; kc < 3; kc++) {
    short8 bfv;
    #pragma unroll
    for (int j = 0; j < 8; j++)
      bfv[j] = (short)xs[(size_t)((kc - 1) * 32 + q * 8 + j) * HWp + px];
    #pragma unroll
    for (int mt = 0; mt < 2; mt++) {
      short8 af = wf[(mt * 3 + kc) * 64 + lane];
      acc[mt] = __builtin_amdgcn_mfma_f32_16x16x32_bf16(af, bfv, acc[mt], 0, 0, 0);
    }
  }
  unsigned short* dst = (unsigned short*)att + (size_t)b * 32 * HWp;
  #pragma unroll
  for (int mt = 0; mt < 2; mt++)
    #pragma unroll
    for (int j = 0; j < 4; j++) {
      int s = mt * 16 + q * 4 + j;
      dst[(size_t)s * HWp + px] = f2bu(acc[mt][j] + c2cb[s] * attg[s] + c211b[s]);
    }
}

// ---------------- c11b direct: grouped 5x5 conv, 16-row tiles ----------------
__global__ __launch_bounds__(256) void k_c11b_direct(
    const bf16* __restrict__ t1, const float* __restrict__ w,
    const float* __restrict__ bias, bf16* __restrict__ out) {
  __shared__ float xs[4 * 20 * 68];        // 21760 B
  __shared__ float wsm[4 * 5 * 4 * 5];
  __shared__ float bsm[4];
  int bz = blockIdx.z;                     // b*16 + g
  int b = bz >> 4, g = bz & 15;
  int h0 = blockIdx.y * 16;
  int w0 = blockIdx.x * 64;
  int t = threadIdx.x;
  for (int i = t; i < 400; i += 256) {
    int kj = i % 5, rem = i / 5;
    int o = rem & 3; rem >>= 2;
    int ki = rem % 5, ci = rem / 5;
    wsm[i] = w[((g * 4 + o) * 4 + ci) * 25 + ki * 5 + kj];
  }
  if (t < 4) bsm[t] = bias[g * 4 + t];
  const unsigned short* src = (const unsigned short*)t1 + ((size_t)b * Cc + g * 4) * HWp;
  for (int i = t; i < 4 * 20 * 68; i += 256) {
    int ci = i / 1360, rem2 = i - ci * 1360;
    int r = rem2 / 68, col = rem2 - r * 68;
    int hh = h0 + r - 2, ww = w0 + col - 2;
    float v = 0.f;
    if ((unsigned)hh < Hh && (unsigned)ww < Wd)
      v = ubf(src[(size_t)ci * HWp + hh * Wd + ww]);
    xs[i] = v;
  }
  __syncthreads();
  int wq = t & 15, hq = t >> 4;
  float acc[4][4];
  #pragma unroll
  for (int o = 0; o < 4; o++)
    #pragma unroll
    for (int j = 0; j < 4; j++) acc[o][j] = bsm[o];
  #pragma unroll
  for (int ci = 0; ci < 4; ci++) {
    #pragma unroll
    for (int ki = 0; ki < 5; ki++) {
      const float* wrow = &wsm[(ci * 5 + ki) * 20];
      float wv[20];
      #pragma unroll
      for (int x = 0; x < 20; x++) wv[x] = wrow[x];
      const float* xrow = &xs[ci * 1360 + (hq + ki) * 68 + wq * 4];
      float xv[8];
      #pragma unroll
      for (int x = 0; x < 8; x++) xv[x] = xrow[x];
      #pragma unroll
      for (int o = 0; o < 4; o++)
        #pragma unroll
        for (int j = 0; j < 4; j++)
          #pragma unroll
          for (int kj = 0; kj < 5; kj++)
            acc[o][j] = fmaf(wv[o * 5 + kj], xv[j + kj], acc[o][j]);
    }
  }
  int width = Wd - w0;
  if (wq * 4 < width) {
    unsigned short* dst = (unsigned short*)out + ((size_t)b * Cc + g * 4) * HWp
                        + (h0 + hq) * Wd + w0 + wq * 4;
    #pragma unroll
    for (int o = 0; o < 4; o++) {
      u16x4 pk;
      #pragma unroll
      for (int j = 0; j < 4; j++) pk[j] = f2bu(acc[o][j]);
      *(u16x4*)(dst + (size_t)o * HWp) = pk;
    }
  }
}

// ---------------- KBA via MFMA: packed A-frags LDS-staged (20 KB), 2 groups/block ----------------
__global__ __launch_bounds__(256) void k_kba_mfma(
    const bf16* __restrict__ uf, const bf16* __restrict__ att,
    const bf16* __restrict__ x1, const float* __restrict__ scaV,
    const short* __restrict__ kbwF, const float* __restrict__ ga1,
    bf16* __restrict__ out) {
  __shared__ short8 fragL[1280];                   // 20480 B (2 groups x 640)
  __shared__ unsigned short patchL[8 * 3 * 66];    // 3168 B
  __shared__ unsigned short attL[64][33];          // 4224 B
  int bz = blockIdx.z;
  int b = bz >> 3, gp = bz & 7;
  int h = blockIdx.y;
  int w0 = blockIdx.x * 64;
  int width = min(64, Wd - w0);
  int t = threadIdx.x;
  int c0 = gp * 8;
  const short8* src8 = (const short8*)kbwF + (size_t)gp * 1280;
  #pragma unroll
  for (int i = 0; i < 5; i++) fragL[t + i * 256] = src8[t + i * 256];
  const unsigned short* uf_u = (const unsigned short*)uf;
  for (int i = t; i < 8 * 3 * 66; i += 256) {
    int cl = i / 198, rem = i - cl * 198;
    int r = rem / 66, col = rem - r * 66;
    int hh = h + r - 1, ww = w0 + col - 1;
    unsigned short v = 0;
    if ((unsigned)hh < Hh && (unsigned)ww < Wd)
      v = uf_u[((size_t)b * Cc + c0 + cl) * HWp + hh * Wd + ww];
    patchL[i] = v;
  }
  const unsigned short* att_u = (const unsigned short*)att + (size_t)b * 32 * HWp;
  for (int i = t; i < 64 * 32; i += 256) {
    int px = i & 63, s = i >> 6;
    unsigned short v = 0;
    if (px < width) v = att_u[(size_t)s * HWp + h * Wd + w0 + px];
    attL[px][s] = v;
  }
  __syncthreads();
  int lane = t & 63, w = t >> 6;
  int n = lane & 15, q = lane >> 4;
  int pxl = w * 16 + n;
  float attR[8];
  #pragma unroll
  for (int mt = 0; mt < 8; mt++) attR[mt] = ubf(attL[pxl][4 * mt + q]);
  int offA[8];
  #pragma unroll
  for (int j = 0; j < 8; j++) {
    int k = q * 8 + j;
    int ci = k / 9, r = k - ci * 9, ki = r / 3, kj = r - ki * 3;
    offA[j] = ci * 198 + ki * 66 + pxl + kj;
  }
  int offB[4];
  #pragma unroll
  for (int j = 0; j < 4; j++) {
    int k = 32 + j, r = k - 27, ki = r / 3, kj = r - ki * 3;
    offB[j] = 3 * 198 + ki * 66 + pxl + kj;
  }
  const unsigned short* x1u = (const unsigned short*)x1 + (size_t)b * Cc * HWp + h * Wd + w0;
  unsigned short* outu = (unsigned short*)out + (size_t)b * Cc * HWp + h * Wd + w0;
  #pragma unroll
  for (int gl = 0; gl < 2; gl++) {
    int g = gp * 2 + gl;
    const short8* fgl = fragL + gl * 640;
    short8 b0, b1;
    #pragma unroll
    for (int j = 0; j < 8; j++) b0[j] = (short)patchL[gl * 792 + offA[j]];
    #pragma unroll
    for (int j = 0; j < 8; j++) b1[j] = 0;
    if (q == 0) {
      #pragma unroll
      for (int j = 0; j < 4; j++) b1[j] = (short)patchL[gl * 792 + offB[j]];
      b1[4] = (short)0x3F80;                 // B[36][*] = 1.0 (bias row)
    }
    f32x4 acc[8];
    #pragma unroll
    for (int mt = 0; mt < 8; mt++) acc[mt] = (f32x4){0.f, 0.f, 0.f, 0.f};
    #pragma unroll
    for (int mt = 0; mt < 8; mt++) {
      short8 a0 = fgl[mt * 64 + lane];
      acc[mt] = __builtin_amdgcn_mfma_f32_16x16x32_bf16(a0, b0, acc[mt], 0, 0, 0);
      short8 a1 = (short8){0,0,0,0,0,0,0,0};
      if (q == 0) a1 = fgl[512 + mt * 16 + n];
      acc[mt] = __builtin_amdgcn_mfma_f32_16x16x32_bf16(a1, b1, acc[mt], 0, 0, 0);
    }
    #pragma unroll
    for (int o = 0; o < 4; o++) {
      float P = 0.f;
      #pragma unroll
      for (int mt = 0; mt < 8; mt++) P += attR[mt] * acc[mt][o];
      P += __shfl_xor(P, 16);
      P += __shfl_xor(P, 32);
      if (o == q && pxl < width) {
        int c = g * 4 + q;
        float ufc = ubf(patchL[(gl * 4 + q) * 198 + 66 + pxl + 1]);   // center tap
        float xk = P * ga1[c] + ufc;
        float xv = xk * ubf(x1u[(size_t)c * HWp + pxl]) * scaV[b * 64 + c];
        outu[(size_t)c * HWp + pxl] = f2bu(xv);
      }
    }
  }
}

// ---------------- DFT pass via MFMA (5-ct loop, fragment reuse) ----------------
__global__ __launch_bounds__(64) void k_cpass_mfma(
    const bf16* __restrict__ inr, const bf16* __restrict__ ini,
    const short* __restrict__ cosF, const short* __restrict__ sinF,
    bf16* __restrict__ outr, bf16* __restrict__ outi,
    float sgn, float scale,
    const float* __restrict__ sclr, const float* __restrict__ scli) {
  int plane = blockIdx.z;
  int a0 = blockIdx.x * 16;
  int cth = blockIdx.y * 5;          // c-half: ct 0..4 or 5..9
  int lane = threadIdx.x;
  int n = lane & 15, q = lane >> 4;
  const unsigned short* pr = (const unsigned short*)inr + (size_t)plane * HWp;
  const unsigned short* pi = ini ? (const unsigned short*)ini + (size_t)plane * HWp : nullptr;
  float srm = sclr ? sclr[plane] : 1.f;
  float sim = scli ? scli[plane] : 1.f;
  short8 br[5], bi[5];
  #pragma unroll
  for (int kc = 0; kc < 5; kc++) {
    br[kc] = *(const short8*)(pr + (a0 + n) * 160 + kc * 32 + q * 8);
    if (pi) bi[kc] = *(const short8*)(pi + (a0 + n) * 160 + kc * 32 + q * 8);
  }
  const short8* cf = (const short8*)cosF;
  const short8* sf = (const short8*)sinF;
  unsigned short* qr = (unsigned short*)outr + (size_t)plane * HWp;
  unsigned short* qi = (unsigned short*)outi + (size_t)plane * HWp;
  for (int ctl = 0; ctl < 5; ctl++) {
    int ct = cth + ctl;
    f32x4 arr = (f32x4){0.f,0.f,0.f,0.f}, asr = (f32x4){0.f,0.f,0.f,0.f};
    f32x4 ari = (f32x4){0.f,0.f,0.f,0.f}, asi = (f32x4){0.f,0.f,0.f,0.f};
    #pragma unroll
    for (int kc = 0; kc < 5; kc++) {
      short8 ca = cf[(ct * 5 + kc) * 64 + lane];
      short8 sa = sf[(ct * 5 + kc) * 64 + lane];
      arr = __builtin_amdgcn_mfma_f32_16x16x32_bf16(ca, br[kc], arr, 0, 0, 0);
      asr = __builtin_amdgcn_mfma_f32_16x16x32_bf16(sa, br[kc], asr, 0, 0, 0);
      if (pi) {
        ari = __builtin_amdgcn_mfma_f32_16x16x32_bf16(ca, bi[kc], ari, 0, 0, 0);
        asi = __builtin_amdgcn_mfma_f32_16x16x32_bf16(sa, bi[kc], asi, 0, 0, 0);
      }
    }
    #pragma unroll
    for (int j = 0; j < 4; j++) {
      int c = ct * 16 + q * 4 + j;
      float xc = srm * arr[j], xs = srm * asr[j];
      float ic = pi ? sim * ari[j] : 0.f, is = pi ? sim * asi[j] : 0.f;
      float orv = (xc - sgn * is) * scale;
      float oiv = (sgn * xs + ic) * scale;
      qr[c * 160 + a0 + n] = f2bu(orv);
      qi[c * 160 + a0 + n] = f2bu(oiv);
    }
  }
}

// ---------------- final inverse DFT pass, fused |.|, *gamma, += y ----------------
__global__ __launch_bounds__(64) void k_cpass_final_mfma(
    const bf16* __restrict__ inr, const bf16* __restrict__ ini,
    const short* __restrict__ cosF, const short* __restrict__ sinF,
    float sgn, float scale,
    const float* __restrict__ gamma, float* __restrict__ dout) {
  int plane = blockIdx.z;
  int a0 = blockIdx.x * 16;
  int cth = blockIdx.y * 5;
  int lane = threadIdx.x;
  int n = lane & 15, q = lane >> 4;
  const unsigned short* pr = (const unsigned short*)inr + (size_t)plane * HWp;
  const unsigned short* pi = (const unsigned short*)ini + (size_t)plane * HWp;
  short8 br[5], bi[5];
  #pragma unroll
  for (int kc = 0; kc < 5; kc++) {
    br[kc] = *(const short8*)(pr + (a0 + n) * 160 + kc * 32 + q * 8);
    bi[kc] = *(const short8*)(pi + (a0 + n) * 160 + kc * 32 + q * 8);
  }
  const short8* cf = (const short8*)cosF;
  const short8* sf = (const short8*)sinF;
  float gm = gamma[plane & 63];
  float* dp = dout + (size_t)plane * HWp;
  for (int ctl = 0; ctl < 5; ctl++) {
    int ct = cth + ctl;
    f32x4 arr = (f32x4){0.f,0.f,0.f,0.f}, asr = (f32x4){0.f,0.f,0.f,0.f};
    f32x4 ari = (f32x4){0.f,0.f,0.f,0.f}, asi = (f32x4){0.f,0.f,0.f,0.f};
    #pragma unroll
    for (int kc = 0; kc < 5; kc++) {
      short8 ca = cf[(ct * 5 + kc) * 64 + lane];
      short8 sa = sf[(ct * 5 + kc) * 64 + lane];
      arr = __builtin_amdgcn_mfma_f32_16x16x32_bf16(ca, br[kc], arr, 0, 0, 0);
      asr = __builtin_amdgcn_mfma_f32_16x16x32_bf16(sa, br[kc], asr, 0, 0, 0);
      ari = __builtin_amdgcn_mfma_f32_16x16x32_bf16(ca, bi[kc], ari, 0, 0, 0);
      asi = __builtin_amdgcn_mfma_f32_16x16x32_bf16(sa, bi[kc], asi, 0, 0, 0);
    }
    #pragma unroll
    for (int j = 0; j < 4; j++) {
      int c = ct * 16 + q * 4 + j;
      float orv = (arr[j] - sgn * asi[j]) * scale;
      float oiv = (sgn * asr[j] + ari[j]) * scale;
      float z = sqrtf(orv * orv + oiv * oiv);
      dp[c * 160 + a0 + n] += z * gm;   // dout currently holds y
    }
  }
}

// ---------------- fc1 (128->256) + simple_gate, MFMA ----------------
__global__ __launch_bounds__(256) void k_fc1_mfma(
    const bf16* __restrict__ Fr, const bf16* __restrict__ Fi,
    const short* __restrict__ wA, const float* __restrict__ bias,
    bf16* __restrict__ G1, bf16* __restrict__ G2) {
  int b = blockIdx.z;
  int lane = threadIdx.x & 63, w = threadIdx.x >> 6;
  int px = blockIdx.x * 64 + w * 16 + (lane & 15);
  int q = lane >> 4;
  const unsigned short* fr = (const unsigned short*)Fr + (size_t)b * Cc * HWp;
  const unsigned short* fi = (const unsigned short*)Fi + (size_t)b * Cc * HWp;
  const short8* wf = (const short8*)wA;
  f32x4 acc[16];
  #pragma unroll
  for (int mt = 0; mt < 16; mt++) acc[mt] = (f32x4){0.f, 0.f, 0.f, 0.f};
  #pragma unroll
  for (int kc = 0; kc < 4; kc++) {
    const unsigned short* basep = (kc < 2) ? (fr + (size_t)(kc * 32) * HWp)
                                           : (fi + (size_t)((kc - 2) * 32) * HWp);
    short8 bfv;
    #pragma unroll
    for (int j = 0; j < 8; j++) bfv[j] = (short)basep[(size_t)(q * 8 + j) * HWp + px];
    #pragma unroll
    for (int mt = 0; mt < 16; mt++) {
      short8 af = wf[(mt * 4 + kc) * 64 + lane];
      acc[mt] = __builtin_amdgcn_mfma_f32_16x16x32_bf16(af, bfv, acc[mt], 0, 0, 0);
    }
  }
  unsigned short* g1 = (unsigned short*)G1 + (size_t)b * Cc * HWp;
  unsigned short* g2 = (unsigned short*)G2 + (size_t)b * Cc * HWp;
  #pragma unroll
  for (int mt = 0; mt < 8; mt++)
    #pragma unroll
    for (int j = 0; j < 4; j++) {
      int o = mt * 16 + q * 4 + j;
      float v1 = acc[mt][j] + bias[o];
      float v2 = acc[mt + 8][j] + bias[o + 128];
      unsigned short hv = f2bu(v1 * v2);
      if (o < 64) g1[(size_t)o * HWp + px] = hv;
      else        g2[(size_t)(o - 64) * HWp + px] = hv;
    }
}

// ---------------- fc2 (128->128) MFMA, split output into r / i planes ----------------
__global__ __launch_bounds__(256) void k_fc2_mfma(
    const bf16* __restrict__ G1, const bf16* __restrict__ G2,
    const short* __restrict__ wA, const float* __restrict__ bias,
    bf16* __restrict__ Or, bf16* __restrict__ Oi) {
  int b = blockIdx.z;
  int lane = threadIdx.x & 63, w = threadIdx.x >> 6;
  int px = blockIdx.x * 64 + w * 16 + (lane & 15);
  int q = lane >> 4;
  const unsigned short* g1 = (const unsigned short*)G1 + (size_t)b * Cc * HWp;
  const unsigned short* g2 = (const unsigned short*)G2 + (size_t)b * Cc * HWp;
  const short8* wf = (const short8*)wA;
  f32x4 acc[8];
  #pragma unroll
  for (int mt = 0; mt < 8; mt++) acc[mt] = (f32x4){0.f, 0.f, 0.f, 0.f};
  #pragma unroll
  for (int kc = 0; kc < 4; kc++) {
    const unsigned short* basep = (kc < 2) ? (g1 + (size_t)(kc * 32) * HWp)
                                           : (g2 + (size_t)((kc - 2) * 32) * HWp);
    short8 bfv;
    #pragma unroll
    for (int j = 0; j < 8; j++) bfv[j] = (short)basep[(size_t)(q * 8 + j) * HWp + px];
    #pragma unroll
    for (int mt = 0; mt < 8; mt++) {
      short8 af = wf[(mt * 4 + kc) * 64 + lane];
      acc[mt] = __builtin_amdgcn_mfma_f32_16x16x32_bf16(af, bfv, acc[mt], 0, 0, 0);
    }
  }
  unsigned short* orp = (unsigned short*)Or + (size_t)b * Cc * HWp;
  unsigned short* oip = (unsigned short*)Oi + (size_t)b * Cc * HWp;
  #pragma unroll
  for (int mt = 0; mt < 8; mt++)
    #pragma unroll
    for (int j = 0; j < 4; j++) {
      int o = mt * 16 + q * 4 + j;
      unsigned short hv = f2bu(acc[mt][j] + bias[o]);
      if (o < 64) orp[(size_t)o * HWp + px] = hv;
      else        oip[(size_t)(o - 64) * HWp + px] = hv;
    }
}

extern "C" void kernel_launch(void* const* d_in, const int* in_sizes, int n_in,
                              void* d_out, int out_size, void* d_ws, size_t ws_size,
                              hipStream_t stream) {
  const float* inp   = (const float*)d_in[0];
  const float* n1w   = (const float*)d_in[1];
  const float* n1b   = (const float*)d_in[2];
  const float* n2w   = (const float*)d_in[3];
  const float* n2b   = (const float*)d_in[4];
  const float* scaw  = (const float*)d_in[5];
  const float* scab  = (const float*)d_in[6];
  const float* c11aw = (const float*)d_in[7];
  const float* c11ab = (const float*)d_in[8];
  const float* c11bw = (const float*)d_in[9];
  const float* c11bb = (const float*)d_in[10];
  const float* c1w   = (const float*)d_in[11];
  const float* c1b   = (const float*)d_in[12];
  const float* c21w  = (const float*)d_in[13];
  const float* c21b  = (const float*)d_in[14];
  const float* c2aw  = (const float*)d_in[15];
  const float* c2ab  = (const float*)d_in[16];
  const float* c2cw  = (const float*)d_in[17];
  const float* c2cb  = (const float*)d_in[18];
  const float* c211w = (const float*)d_in[19];
  const float* c211b = (const float*)d_in[20];
  const float* c3w   = (const float*)d_in[21];
  const float* c3b   = (const float*)d_in[22];
  const float* kbw   = (const float*)d_in[23];
  const float* kbb   = (const float*)d_in[24];
  const float* ga1   = (const float*)d_in[25];
  const float* attg  = (const float*)d_in[26];
  const float* beta  = (const float*)d_in[27];
  const float* gamma = (const float*)d_in[28];
  const float* fc1w  = (const float*)d_in[29];
  const float* fc1b  = (const float*)d_in[30];
  const float* fc2w  = (const float*)d_in[31];
  const float* fc2b  = (const float*)d_in[32];
  const float* fscaw = (const float*)d_in[33];
  const float* fscab = (const float*)d_in[34];

  const size_t S = (size_t)Bn * Cc * HWp;   // 3,276,800 elements per slot
  bf16* A  = (bf16*)d_ws;                   // 4 bf16 slots = 26.2 MB total
  bf16* Bs = A + S;
  bf16* Cs = A + 2 * S;
  bf16* Ds = A + 3 * S;
  float* smalls = (float*)(A + 4 * S);      // fp32 smalls
  float* xm   = smalls;
  float* scaV = smalls + 128;
  float* rmv  = smalls + 256;               // rmv[128]|imv[128]
  float* sra  = smalls + 512;               // sra[128]|sia[128]
  short* wS   = (short*)(smalls + 1024);    // bf16 frag tables
  short* wAf1 = wS;                         // 32768
  short* wAf2 = wAf1 + 32768;               // 16384
  short* cosF = wAf2 + 16384;               // 25600
  short* sinF = cosF + 25600;               // 25600
  short* wA_c11a = sinF + 25600;            // 4096
  short* wA_c1   = wA_c11a + 4096;          // 4096
  short* wA_c3   = wA_c1 + 4096;            // 4096
  short* wA_att  = wA_c3 + 4096;            // 3072
  short* kbwF    = wA_att + 3072;           // 81920 used
  bf16* gbuf = Bs;            // [B,32,HW] (first half of Bs)
  bf16* attb = Bs + S / 2;    // [B,32,HW] (second half of Bs)
  float* yb  = (float*)d_out; // y lives in d_out (fp32)

  dim3 cgrid(10, 2, Bn * Cc);
  dim3 pgrid(400, 1, Bn);

  k_prep_all<<<dim3(672), dim3(256), 0, stream>>>(kbw, kbb, kbwF, fc1w, fc2w, wAf1, wAf2,
                                                  cosF, sinF, c11aw, c1w, c3w, c2cw, c211w,
                                                  attg, wA_c11a, wA_c1, wA_c3, wA_att);
  k_ln<<<dim3(800), dim3(256), 0, stream>>>(inp, n1w, n1b, A);          // A = x
  k_meanhw<<<dim3(128), dim3(256), 0, stream>>>(A, xm);
  k_small_mv<<<dim3(1), dim3(128), 0, stream>>>(xm, scaw, scab, scaV, 0);
  k_conv1x1_dual<<<pgrid, dim3(256), 0, stream>>>(A, wA_c11a, c11ab, wA_c1, c1b, Bs, Ds); // B=t1 D=t2
  k_c11b_direct<<<dim3(3, 10, Bn * 16), dim3(256), 0, stream>>>(Bs, c11bw, c11bb, Cs); // C = x1
  k_c2a4<<<dim3(25, 32, Bn), dim3(256), 0, stream>>>(A, c2aw, c2ab, gbuf);         // B.lo = g
  k_att_mfma<<<pgrid, dim3(256), 0, stream>>>(gbuf, A, wA_att, c2cb, c211b, attg, attb); // B.hi
  k_c21dw4<<<dim3(25, 64, Bn), dim3(256), 0, stream>>>(Ds, c21w, c21b, A);         // A = uf
  k_kba_mfma<<<dim3(3, 160, Bn * 8), dim3(256), 0, stream>>>(A, attb, Cs, scaV, kbwF, ga1, Ds);
  k_c3y_ln2<<<pgrid, dim3(256), 0, stream>>>(Ds, wA_c3, c3b, beta, inp, yb, n2w, n2b, A); // y, A=X
  // forward FFT2 (MFMA)
  k_cpass_mfma<<<cgrid, dim3(64), 0, stream>>>(A, (const bf16*)nullptr, cosF, sinF, Bs, Cs, -1.f, SCL, nullptr, nullptr);
  k_cpass_mfma<<<cgrid, dim3(64), 0, stream>>>(Bs, Cs, cosF, sinF, Ds, A, -1.f, SCL, nullptr, nullptr);
  k_fc1_mfma<<<pgrid, dim3(256), 0, stream>>>(Ds, A, wAf1, fc1b, Bs, Cs);          // B,C = gated
  k_fc2_mfma<<<pgrid, dim3(256), 0, stream>>>(Bs, Cs, wAf2, fc2b, Ds, A);          // D = r, A = i
  k_meanhw2<<<dim3(256), dim3(256), 0, stream>>>(Ds, A, rmv);                      // rmv|imv
  k_small_mv2<<<dim3(1), dim3(256), 0, stream>>>(rmv, fscaw, fscab, sra);          // sra|sia
  // inverse FFT2 (MFMA) with per-plane (1+ra)/(1+ia) scaling fused into first pass
  k_cpass_mfma<<<cgrid, dim3(64), 0, stream>>>(Ds, A, cosF, sinF, Bs, Cs, 1.f, SCL, sra, sra + 128);
  k_cpass_final_mfma<<<cgrid, dim3(64), 0, stream>>>(Bs, Cs, cosF, sinF, 1.f, SCL, gamma, yb);
}

// Round 15
// 430.020 us; speedup vs baseline: 1.0844x; 1.0373x over previous
//
#include <hip/hip_runtime.h>
#include <hip/hip_bf16.h>

typedef __hip_bfloat16 bf16;
typedef __attribute__((ext_vector_type(8))) short short8;
typedef __attribute__((ext_vector_type(4))) float f32x4;
typedef __attribute__((ext_vector_type(4))) unsigned short u16x4;

#define Hh 160
#define Wd 160
#define HWp (Hh*Wd)       // 25600
#define Bn 2
#define Cc 64
#define NPIX (Bn*HWp)     // 51200
#define SCL 0.07905694150420949f   // 1/sqrt(160)
#define TWO_PI_160 0.039269908169872414f  // 2*pi/160

static __device__ __forceinline__ float b2f(bf16 x) { return __bfloat162float(x); }
static __device__ __forceinline__ bf16 f2b(float f) { return __float2bfloat16(f); }
static __device__ __forceinline__ unsigned short f2bu(float f) {
  union { bf16 h; unsigned short u; } z; z.h = __float2bfloat16(f); return z.u;
}
static __device__ __forceinline__ float ubf(unsigned short u) {
  union { unsigned int i; float f; } z; z.i = ((unsigned int)u) << 16; return z.f;
}

// ---------------- LayerNorm over channel dim, single-pass ----------------
__global__ void k_ln(const float* __restrict__ in, const float* __restrict__ w,
                     const float* __restrict__ bb, bf16* __restrict__ out) {
  __shared__ float2 sm[4][64];
  int t = threadIdx.x;
  int pxl = t & 63, cq = t >> 6;
  int pix = blockIdx.x * 64 + pxl;          // 800 blocks cover NPIX
  int b = pix / HWp, p = pix - b * HWp;
  const float* src = in + ((size_t)b * Cc + cq * 16) * HWp + p;
  float v[16];
  float s = 0.f, s2 = 0.f;
  #pragma unroll
  for (int i = 0; i < 16; i++) {
    v[i] = src[(size_t)i * HWp];
    s += v[i]; s2 += v[i] * v[i];
  }
  sm[cq][pxl] = make_float2(s, s2);
  __syncthreads();
  float S = 0.f, S2 = 0.f;
  #pragma unroll
  for (int k = 0; k < 4; k++) { float2 z = sm[k][pxl]; S += z.x; S2 += z.y; }
  float mu = S * (1.f / 64.f);
  float var = S2 * (1.f / 64.f) - mu * mu;
  float rs = rsqrtf(fmaxf(var, 0.f) + 1e-6f);
  bf16* dst = out + ((size_t)b * Cc + cq * 16) * HWp + p;
  #pragma unroll
  for (int i = 0; i < 16; i++) {
    int c = cq * 16 + i;
    dst[(size_t)i * HWp] = f2b((v[i] - mu) * rs * w[c] + bb[c]);
  }
}

// ---------------- mean over HW per (b,c) plane (bf16 in) ----------------
__global__ void k_meanhw(const bf16* __restrict__ in, float* __restrict__ out) {
  int bc = blockIdx.x;
  const bf16* src = in + (size_t)bc * HWp;
  int t = threadIdx.x;
  float s = 0.f;
  for (int i = t; i < HWp; i += 256) s += b2f(src[i]);
  __shared__ float sm[256];
  sm[t] = s; __syncthreads();
  for (int off = 128; off; off >>= 1) { if (t < off) sm[t] += sm[t + off]; __syncthreads(); }
  if (t == 0) out[bc] = sm[0] * (1.f / HWp);
}

// ---------------- fused dual mean: bc<128 from in0, else in1 ----------------
__global__ void k_meanhw2(const bf16* __restrict__ in0, const bf16* __restrict__ in1,
                          float* __restrict__ out) {
  int bc = blockIdx.x;   // 0..255
  const bf16* src = (bc < 128) ? (in0 + (size_t)bc * HWp) : (in1 + (size_t)(bc - 128) * HWp);
  int t = threadIdx.x;
  float s = 0.f;
  for (int i = t; i < HWp; i += 256) s += b2f(src[i]);
  __shared__ float sm[256];
  sm[t] = s; __syncthreads();
  for (int off = 128; off; off >>= 1) { if (t < off) sm[t] += sm[t + off]; __syncthreads(); }
  if (t == 0) out[bc] = sm[0] * (1.f / HWp);
}

// ---------------- small matvec ----------------
__global__ void k_small_mv(const float* __restrict__ xin, const float* __restrict__ w,
                           const float* __restrict__ bias, float* __restrict__ out, int addone) {
  int t = threadIdx.x;              // 128 threads
  int b = t >> 6, o = t & 63;
  float acc = bias[o];
  for (int k = 0; k < 64; k++) acc += w[o * 64 + k] * xin[b * 64 + k];
  out[t] = addone ? (1.f + acc) : acc;
}

// ---------------- fused dual small matvec ----------------
__global__ void k_small_mv2(const float* __restrict__ xin, const float* __restrict__ w,
                            const float* __restrict__ bias, float* __restrict__ out) {
  int t = threadIdx.x;              // 256 threads
  int half = t >> 7, r = t & 127;
  int b = r >> 6, o = r & 63;
  const float* x = xin + half * 128 + b * 64;
  float acc = bias[o];
  for (int k = 0; k < 64; k++) acc += w[o * 64 + k] * x[k];
  out[half * 128 + r] = 1.f + acc;
}

// ---------------- c2a vectorized: grouped 3x3, 64->32, groups=32, 4 px/thread ----------------
__global__ void k_c2a4(const bf16* __restrict__ in, const float* __restrict__ w,
                       const float* __restrict__ bias, bf16* __restrict__ out) {
  int t = threadIdx.x;
  int o = blockIdx.y, b = blockIdx.z;       // o 0..31
  int pq = blockIdx.x * 256 + t;            // grid.x = 25
  int h = pq / 40, x4 = (pq - h * 40) * 4;
  float bs = bias[o];
  float acc[4] = {bs, bs, bs, bs};
  #pragma unroll
  for (int ci = 0; ci < 2; ci++) {
    const unsigned short* src = (const unsigned short*)in + ((size_t)b * Cc + o * 2 + ci) * HWp;
    float wv[9];
    #pragma unroll
    for (int i = 0; i < 9; i++) wv[i] = w[(o * 2 + ci) * 9 + i];
    #pragma unroll
    for (int ki = 0; ki < 3; ki++) {
      int hh = h + ki - 1;
      if ((unsigned)hh >= Hh) continue;
      const unsigned short* row = src + hh * Wd + x4;
      float v[6];
      u16x4 m = *(const u16x4*)row;
      v[1] = ubf(m[0]); v[2] = ubf(m[1]); v[3] = ubf(m[2]); v[4] = ubf(m[3]);
      v[0] = (x4 > 0) ? ubf(row[-1]) : 0.f;
      v[5] = (x4 + 4 < Wd) ? ubf(row[4]) : 0.f;
      #pragma unroll
      for (int j = 0; j < 4; j++)
        #pragma unroll
        for (int kj = 0; kj < 3; kj++)
          acc[j] = fmaf(wv[ki * 3 + kj], v[j + kj], acc[j]);
    }
  }
  u16x4 pk;
  #pragma unroll
  for (int j = 0; j < 4; j++) pk[j] = f2bu(acc[j]);
  *(u16x4*)((unsigned short*)out + ((size_t)b * 32 + o) * HWp + h * Wd + x4) = pk;
}

// ---------------- depthwise 3x3 vectorized, 4 px/thread ----------------
__global__ void k_c21dw4(const bf16* __restrict__ in, const float* __restrict__ w,
                         const float* __restrict__ bias, bf16* __restrict__ out) {
  int t = threadIdx.x;
  int c = blockIdx.y, b = blockIdx.z;
  int pq = blockIdx.x * 256 + t;            // grid.x = 25
  int h = pq / 40, x4 = (pq - h * 40) * 4;
  const unsigned short* src = (const unsigned short*)in + ((size_t)b * Cc + c) * HWp;
  float wv[9];
  #pragma unroll
  for (int i = 0; i < 9; i++) wv[i] = w[c * 9 + i];
  float bs = bias[c];
  float acc[4] = {bs, bs, bs, bs};
  #pragma unroll
  for (int ki = 0; ki < 3; ki++) {
    int hh = h + ki - 1;
    if ((unsigned)hh >= Hh) continue;
    const unsigned short* row = src + hh * Wd + x4;
    float v[6];
    u16x4 m = *(const u16x4*)row;
    v[1] = ubf(m[0]); v[2] = ubf(m[1]); v[3] = ubf(m[2]); v[4] = ubf(m[3]);
    v[0] = (x4 > 0) ? ubf(row[-1]) : 0.f;
    v[5] = (x4 + 4 < Wd) ? ubf(row[4]) : 0.f;
    #pragma unroll
    for (int j = 0; j < 4; j++)
      #pragma unroll
      for (int kj = 0; kj < 3; kj++)
        acc[j] = fmaf(wv[ki * 3 + kj], v[j + kj], acc[j]);
  }
  u16x4 pk;
  #pragma unroll
  for (int j = 0; j < 4; j++) pk[j] = f2bu(acc[j]);
  *(u16x4*)((unsigned short*)out + ((size_t)b * Cc + c) * HWp + h * Wd + x4) = pk;
}

// ---------------- fused weight prep ----------------
__global__ void k_prep_all(const float* __restrict__ kbw, const float* __restrict__ kbb,
                           short* __restrict__ kbwF,
                           const float* __restrict__ fc1w, const float* __restrict__ fc2w,
                           short* __restrict__ wAf1, short* __restrict__ wAf2,
                           short* __restrict__ cosF, short* __restrict__ sinF,
                           const float* __restrict__ c11aw, const float* __restrict__ c1w,
                           const float* __restrict__ c3w, const float* __restrict__ c2cw,
                           const float* __restrict__ c211w, const float* __restrict__ attg,
                           short* __restrict__ wA_c11a, short* __restrict__ wA_c1,
                           short* __restrict__ wA_c3, short* __restrict__ wA_att) {
  int i = blockIdx.x * 256 + threadIdx.x;   // 172032 total (672 blocks)
  if (i < 81920) {
    int g = i / 5120, r = i - g * 5120;
    float v = 0.f;
    if (r < 4096) {
      int j = r & 7, lane = (r >> 3) & 63, mt = r >> 9;
      int m = mt * 16 + (lane & 15);
      int s = m >> 2, o = m & 3;
      int k = (lane >> 4) * 8 + j;
      v = kbw[s * 2304 + g * 144 + o * 36 + k];
    } else {
      int r2 = r - 4096;
      int j = r2 & 7, n = (r2 >> 3) & 15, mt = r2 >> 7;
      int m = mt * 16 + n;
      int s = m >> 2, o = m & 3;
      int k = 32 + j;
      if (k < 36) v = kbw[s * 2304 + g * 144 + o * 36 + k];
      else if (k == 36) v = kbb[s * 64 + g * 4 + o];
    }
    kbwF[i] = (short)f2bu(v);
  } else if (i < 131072) {
    int i1 = i - 81920;
    if (i1 < 32768) {
      int j = i1 & 7, lane = (i1 >> 3) & 63, fk = i1 >> 9;
      int kc = fk & 3, mt = fk >> 2;
      int o = mt * 16 + (lane & 15);
      int k = kc * 32 + (lane >> 4) * 8 + j;
      wAf1[i1] = (short)f2bu(fc1w[o * 128 + k]);
    } else {
      int i2 = i1 - 32768;
      int j = i2 & 7, lane = (i2 >> 3) & 63, fk = i2 >> 9;
      int kc = fk & 3, mt = fk >> 2;
      int o = mt * 16 + (lane & 15);
      int k = kc * 32 + (lane >> 4) * 8 + j;
      wAf2[i2] = (short)f2bu(fc2w[o * 128 + k]);
    }
  } else if (i < 156672) {
    int i2 = i - 131072;
    int j = i2 & 7, lane = (i2 >> 3) & 63, fk = i2 >> 9;   // fk = ct*5+kc
    int kc = fk % 5, ct = fk / 5;
    int c = ct * 16 + (lane & 15);
    int bb2 = kc * 32 + (lane >> 4) * 8 + j;
    int m = (bb2 * c) % 160;
    float sv, cv;
    __sincosf((float)m * TWO_PI_160, &sv, &cv);
    cosF[i2] = (short)f2bu(cv);
    sinF[i2] = (short)f2bu(sv);
  } else {
    int i3 = i - 156672;
    if (i3 < 12288) {
      int wi = i3 / 4096, r = i3 - wi * 4096;
      int j = r & 7, lane = (r >> 3) & 63, fk = r >> 9;
      int kc = fk & 1, mt = fk >> 1;
      int o = mt * 16 + (lane & 15);
      int k = kc * 32 + (lane >> 4) * 8 + j;
      const float* w = (wi == 0) ? c11aw : (wi == 1) ? c1w : c3w;
      short* dst = (wi == 0) ? wA_c11a : (wi == 1) ? wA_c1 : wA_c3;
      dst[r] = (short)f2bu(w[o * 64 + k]);
    } else {
      int r = i3 - 12288;
      int j = r & 7, lane = (r >> 3) & 63, fk = r >> 9;
      int kc = fk % 3, mt = fk / 3;
      int s = mt * 16 + (lane & 15);
      int k = kc * 32 + (lane >> 4) * 8 + j;
      float v;
      if (k < 16) v = c2cw[s * 16 + k] * attg[s];
      else if (k < 32) v = 0.f;
      else v = c211w[s * 64 + (k - 32)];
      wA_att[r] = (short)f2bu(v);
    }
  }
}

// ---------------- dual 1x1 conv 64->64 via MFMA (t1 and t2 share input fragments) ----------------
__global__ __launch_bounds__(256) void k_conv1x1_dual(
    const bf16* __restrict__ in, const short* __restrict__ wA1,
    const float* __restrict__ b1, const short* __restrict__ wA2,
    const float* __restrict__ b2, bf16* __restrict__ out1, bf16* __restrict__ out2) {
  int b = blockIdx.z;
  int lane = threadIdx.x & 63, w = threadIdx.x >> 6;
  int px = blockIdx.x * 64 + w * 16 + (lane & 15);
  int q = lane >> 4;
  const unsigned short* src = (const unsigned short*)in + (size_t)b * Cc * HWp;
  const short8* wf1 = (const short8*)wA1;
  const short8* wf2 = (const short8*)wA2;
  f32x4 acc1[4], acc2[4];
  #pragma unroll
  for (int mt = 0; mt < 4; mt++) {
    acc1[mt] = (f32x4){0.f, 0.f, 0.f, 0.f};
    acc2[mt] = (f32x4){0.f, 0.f, 0.f, 0.f};
  }
  #pragma unroll
  for (int kc = 0; kc < 2; kc++) {
    short8 bfv;
    #pragma unroll
    for (int j = 0; j < 8; j++) bfv[j] = (short)src[(size_t)(kc * 32 + q * 8 + j) * HWp + px];
    #pragma unroll
    for (int mt = 0; mt < 4; mt++) {
      short8 a1 = wf1[(mt * 2 + kc) * 64 + lane];
      acc1[mt] = __builtin_amdgcn_mfma_f32_16x16x32_bf16(a1, bfv, acc1[mt], 0, 0, 0);
      short8 a2 = wf2[(mt * 2 + kc) * 64 + lane];
      acc2[mt] = __builtin_amdgcn_mfma_f32_16x16x32_bf16(a2, bfv, acc2[mt], 0, 0, 0);
    }
  }
  unsigned short* d1 = (unsigned short*)out1 + (size_t)b * Cc * HWp;
  unsigned short* d2 = (unsigned short*)out2 + (size_t)b * Cc * HWp;
  #pragma unroll
  for (int mt = 0; mt < 4; mt++)
    #pragma unroll
    for (int j = 0; j < 4; j++) {
      int o = mt * 16 + q * 4 + j;
      d1[(size_t)o * HWp + px] = f2bu(acc1[mt][j] + b1[o]);
      d2[(size_t)o * HWp + px] = f2bu(acc2[mt][j] + b2[o]);
    }
}

// ---------------- c3 1x1 conv + residual + FUSED LayerNorm2 ----------------
__global__ __launch_bounds__(256) void k_c3y_ln2(
    const bf16* __restrict__ in, const short* __restrict__ wA,
    const float* __restrict__ bias, const float* __restrict__ beta,
    const float* __restrict__ inp, float* __restrict__ y,
    const float* __restrict__ n2w, const float* __restrict__ n2b,
    bf16* __restrict__ Xout) {
  int b = blockIdx.z;
  int lane = threadIdx.x & 63, w = threadIdx.x >> 6;
  int px = blockIdx.x * 64 + w * 16 + (lane & 15);
  int q = lane >> 4;
  const unsigned short* src = (const unsigned short*)in + (size_t)b * Cc * HWp;
  const short8* wf = (const short8*)wA;
  f32x4 acc[4];
  #pragma unroll
  for (int mt = 0; mt < 4; mt++) acc[mt] = (f32x4){0.f, 0.f, 0.f, 0.f};
  #pragma unroll
  for (int kc = 0; kc < 2; kc++) {
    short8 bfv;
    #pragma unroll
    for (int j = 0; j < 8; j++) bfv[j] = (short)src[(size_t)(kc * 32 + q * 8 + j) * HWp + px];
    #pragma unroll
    for (int mt = 0; mt < 4; mt++) {
      short8 af = wf[(mt * 2 + kc) * 64 + lane];
      acc[mt] = __builtin_amdgcn_mfma_f32_16x16x32_bf16(af, bfv, acc[mt], 0, 0, 0);
    }
  }
  float yv[4][4];
  float s = 0.f, s2 = 0.f;
  #pragma unroll
  for (int mt = 0; mt < 4; mt++)
    #pragma unroll
    for (int j = 0; j < 4; j++) {
      int o = mt * 16 + q * 4 + j;
      size_t oi = ((size_t)b * Cc + o) * HWp + px;
      float v = inp[oi] + (acc[mt][j] + bias[o]) * beta[o];
      y[oi] = v;
      yv[mt][j] = v;
      s += v; s2 += v * v;
    }
  s  += __shfl_xor(s, 16);  s  += __shfl_xor(s, 32);
  s2 += __shfl_xor(s2, 16); s2 += __shfl_xor(s2, 32);
  float mu = s * (1.f / 64.f);
  float var = s2 * (1.f / 64.f) - mu * mu;
  float rs = rsqrtf(fmaxf(var, 0.f) + 1e-6f);
  unsigned short* Xu = (unsigned short*)Xout + (size_t)b * Cc * HWp;
  #pragma unroll
  for (int mt = 0; mt < 4; mt++)
    #pragma unroll
    for (int j = 0; j < 4; j++) {
      int o = mt * 16 + q * 4 + j;
      Xu[(size_t)o * HWp + px] = f2bu((yv[mt][j] - mu) * rs * n2w[o] + n2b[o]);
    }
}

// ---------------- att via MFMA: M=32, K = [gate16 | pad16 | x64] ----------------
__global__ __launch_bounds__(256) void k_att_mfma(
    const bf16* __restrict__ g, const bf16* __restrict__ x,
    const short* __restrict__ wA, const float* __restrict__ c2cb,
    const float* __restrict__ c211b, const float* __restrict__ attg,
    bf16* __restrict__ att) {
  int b = blockIdx.z;
  int lane = threadIdx.x & 63, w = threadIdx.x >> 6;
  int px = blockIdx.x * 64 + w * 16 + (lane & 15);
  int q = lane >> 4;
  const unsigned short* gs = (const unsigned short*)g + (size_t)b * 32 * HWp;
  const unsigned short* xs = (const unsigned short*)x + (size_t)b * Cc * HWp;
  const short8* wf = (const short8*)wA;
  f32x4 acc[2];
  acc[0] = (f32x4){0.f, 0.f, 0.f, 0.f};
  acc[1] = (f32x4){0.f, 0.f, 0.f, 0.f};
  {
    short8 bfv;
    #pragma unroll
    for (int j = 0; j < 8; j++) {
      int k = q * 8 + j;
      short v = 0;
      if (q < 2) {
        float gv = ubf(gs[(size_t)k * HWp + px]) * ubf(gs[(size_t)(16 + k) * HWp + px]);
        v = (short)f2bu(gv);
      }
      bfv[j] = v;
    }
    #pragma unroll
    for (int mt = 0; mt < 2; mt++) {
      short8 af = wf[(mt * 3 + 0) * 64 + lane];
      acc[mt] = __builtin_amdgcn_mfma_f32_16x16x32_bf16(af, bfv, acc[mt], 0, 0, 0);
    }
  }
  #pragma unroll
  for (int kc = 1; kc < 3; kc++) {
    short8 bfv;
    #pragma unroll
    for (int j = 0; j < 8; j++)
      bfv[j] = (short)xs[(size_t)((kc - 1) * 32 + q * 8 + j) * HWp + px];
    #pragma unroll
    for (int mt = 0; mt < 2; mt++) {
      short8 af = wf[(mt * 3 + kc) * 64 + lane];
      acc[mt] = __builtin_amdgcn_mfma_f32_16x16x32_bf16(af, bfv, acc[mt], 0, 0, 0);
    }
  }
  unsigned short* dst = (unsigned short*)att + (size_t)b * 32 * HWp;
  #pragma unroll
  for (int mt = 0; mt < 2; mt++)
    #pragma unroll
    for (int j = 0; j < 4; j++) {
      int s = mt * 16 + q * 4 + j;
      dst[(size_t)s * HWp + px] = f2bu(acc[mt][j] + c2cb[s] * attg[s] + c211b[s]);
    }
}

// ---------------- c11b direct: grouped 5x5 conv, 16-row tiles ----------------
__global__ __launch_bounds__(256) void k_c11b_direct(
    const bf16* __restrict__ t1, const float* __restrict__ w,
    const float* __restrict__ bias, bf16* __restrict__ out) {
  __shared__ float xs[4 * 20 * 68];        // 21760 B
  __shared__ float wsm[4 * 5 * 4 * 5];
  __shared__ float bsm[4];
  int bz = blockIdx.z;                     // b*16 + g
  int b = bz >> 4, g = bz & 15;
  int h0 = blockIdx.y * 16;
  int w0 = blockIdx.x * 64;
  int t = threadIdx.x;
  for (int i = t; i < 400; i += 256) {
    int kj = i % 5, rem = i / 5;
    int o = rem & 3; rem >>= 2;
    int ki = rem % 5, ci = rem / 5;
    wsm[i] = w[((g * 4 + o) * 4 + ci) * 25 + ki * 5 + kj];
  }
  if (t < 4) bsm[t] = bias[g * 4 + t];
  const unsigned short* src = (const unsigned short*)t1 + ((size_t)b * Cc + g * 4) * HWp;
  for (int i = t; i < 4 * 20 * 68; i += 256) {
    int ci = i / 1360, rem2 = i - ci * 1360;
    int r = rem2 / 68, col = rem2 - r * 68;
    int hh = h0 + r - 2, ww = w0 + col - 2;
    float v = 0.f;
    if ((unsigned)hh < Hh && (unsigned)ww < Wd)
      v = ubf(src[(size_t)ci * HWp + hh * Wd + ww]);
    xs[i] = v;
  }
  __syncthreads();
  int wq = t & 15, hq = t >> 4;
  float acc[4][4];
  #pragma unroll
  for (int o = 0; o < 4; o++)
    #pragma unroll
    for (int j = 0; j < 4; j++) acc[o][j] = bsm[o];
  #pragma unroll
  for (int ci = 0; ci < 4; ci++) {
    #pragma unroll
    for (int ki = 0; ki < 5; ki++) {
      const float* wrow = &wsm[(ci * 5 + ki) * 20];
      float wv[20];
      #pragma unroll
      for (int x = 0; x < 20; x++) wv[x] = wrow[x];
      const float* xrow = &xs[ci * 1360 + (hq + ki) * 68 + wq * 4];
      float xv[8];
      #pragma unroll
      for (int x = 0; x < 8; x++) xv[x] = xrow[x];
      #pragma unroll
      for (int o = 0; o < 4; o++)
        #pragma unroll
        for (int j = 0; j < 4; j++)
          #pragma unroll
          for (int kj = 0; kj < 5; kj++)
            acc[o][j] = fmaf(wv[o * 5 + kj], xv[j + kj], acc[o][j]);
    }
  }
  int width = Wd - w0;
  if (wq * 4 < width) {
    unsigned short* dst = (unsigned short*)out + ((size_t)b * Cc + g * 4) * HWp
                        + (h0 + hq) * Wd + w0 + wq * 4;
    #pragma unroll
    for (int o = 0; o < 4; o++) {
      u16x4 pk;
      #pragma unroll
      for (int j = 0; j < 4; j++) pk[j] = f2bu(acc[o][j]);
      *(u16x4*)(dst + (size_t)o * HWp) = pk;
    }
  }
}

// ---------------- KBA via MFMA: packed A-frags LDS-staged (20 KB), 2 groups/block ----------------
__global__ __launch_bounds__(256) void k_kba_mfma(
    const bf16* __restrict__ uf, const bf16* __restrict__ att,
    const bf16* __restrict__ x1, const float* __restrict__ scaV,
    const short* __restrict__ kbwF, const float* __restrict__ ga1,
    bf16* __restrict__ out) {
  __shared__ short8 fragL[1280];                   // 20480 B (2 groups x 640)
  __shared__ unsigned short patchL[8 * 3 * 66];    // 3168 B
  __shared__ unsigned short attL[64][33];          // 4224 B
  int bz = blockIdx.z;
  int b = bz >> 3, gp = bz & 7;
  int h = blockIdx.y;
  int w0 = blockIdx.x * 64;
  int width = min(64, Wd - w0);
  int t = threadIdx.x;
  int c0 = gp * 8;
  const short8* src8 = (const short8*)kbwF + (size_t)gp * 1280;
  #pragma unroll
  for (int i = 0; i < 5; i++) fragL[t + i * 256] = src8[t + i * 256];
  const unsigned short* uf_u = (const unsigned short*)uf;
  for (int i = t; i < 8 * 3 * 66; i += 256) {
    int cl = i / 198, rem = i - cl * 198;
    int r = rem / 66, col = rem - r * 66;
    int hh = h + r - 1, ww = w0 + col - 1;
    unsigned short v = 0;
    if ((unsigned)hh < Hh && (unsigned)ww < Wd)
      v = uf_u[((size_t)b * Cc + c0 + cl) * HWp + hh * Wd + ww];
    patchL[i] = v;
  }
  const unsigned short* att_u = (const unsigned short*)att + (size_t)b * 32 * HWp;
  for (int i = t; i < 64 * 32; i += 256) {
    int px = i & 63, s = i >> 6;
    unsigned short v = 0;
    if (px < width) v = att_u[(size_t)s * HWp + h * Wd + w0 + px];
    attL[px][s] = v;
  }
  __syncthreads();
  int lane = t & 63, w = t >> 6;
  int n = lane & 15, q = lane >> 4;
  int pxl = w * 16 + n;
  float attR[8];
  #pragma unroll
  for (int mt = 0; mt < 8; mt++) attR[mt] = ubf(attL[pxl][4 * mt + q]);
  int offA[8];
  #pragma unroll
  for (int j = 0; j < 8; j++) {
    int k = q * 8 + j;
    int ci = k / 9, r = k - ci * 9, ki = r / 3, kj = r - ki * 3;
    offA[j] = ci * 198 + ki * 66 + pxl + kj;
  }
  int offB[4];
  #pragma unroll
  for (int j = 0; j < 4; j++) {
    int k = 32 + j, r = k - 27, ki = r / 3, kj = r - ki * 3;
    offB[j] = 3 * 198 + ki * 66 + pxl + kj;
  }
  const unsigned short* x1u = (const unsigned short*)x1 + (size_t)b * Cc * HWp + h * Wd + w0;
  unsigned short* outu = (unsigned short*)out + (size_t)b * Cc * HWp + h * Wd + w0;
  #pragma unroll
  for (int gl = 0; gl < 2; gl++) {
    int g = gp * 2 + gl;
    const short8* fgl = fragL + gl * 640;
    short8 b0, b1;
    #pragma unroll
    for (int j = 0; j < 8; j++) b0[j] = (short)patchL[gl * 792 + offA[j]];
    #pragma unroll
    for (int j = 0; j < 8; j++) b1[j] = 0;
    if (q == 0) {
      #pragma unroll
      for (int j = 0; j < 4; j++) b1[j] = (short)patchL[gl * 792 + offB[j]];
      b1[4] = (short)0x3F80;                 // B[36][*] = 1.0 (bias row)
    }
    f32x4 acc[8];
    #pragma unroll
    for (int mt = 0; mt < 8; mt++) acc[mt] = (f32x4){0.f, 0.f, 0.f, 0.f};
    #pragma unroll
    for (int mt = 0; mt < 8; mt++) {
      short8 a0 = fgl[mt * 64 + lane];
      acc[mt] = __builtin_amdgcn_mfma_f32_16x16x32_bf16(a0, b0, acc[mt], 0, 0, 0);
      short8 a1 = (short8){0,0,0,0,0,0,0,0};
      if (q == 0) a1 = fgl[512 + mt * 16 + n];
      acc[mt] = __builtin_amdgcn_mfma_f32_16x16x32_bf16(a1, b1, acc[mt], 0, 0, 0);
    }
    #pragma unroll
    for (int o = 0; o < 4; o++) {
      float P = 0.f;
      #pragma unroll
      for (int mt = 0; mt < 8; mt++) P += attR[mt] * acc[mt][o];
      P += __shfl_xor(P, 16);
      P += __shfl_xor(P, 32);
      if (o == q && pxl < width) {
        int c = g * 4 + q;
        float ufc = ubf(patchL[(gl * 4 + q) * 198 + 66 + pxl + 1]);   // center tap
        float xk = P * ga1[c] + ufc;
        float xv = xk * ubf(x1u[(size_t)c * HWp + pxl]) * scaV[b * 64 + c];
        outu[(size_t)c * HWp + pxl] = f2bu(xv);
      }
    }
  }
}

// ---------------- DFT pass via MFMA (5-ct loop, fragment reuse) ----------------
__global__ __launch_bounds__(64) void k_cpass_mfma(
    const bf16* __restrict__ inr, const bf16* __restrict__ ini,
    const short* __restrict__ cosF, const short* __restrict__ sinF,
    bf16* __restrict__ outr, bf16* __restrict__ outi,
    float sgn, float scale,
    const float* __restrict__ sclr, const float* __restrict__ scli) {
  int plane = blockIdx.z;
  int a0 = blockIdx.x * 16;
  int cth = blockIdx.y * 5;          // c-half: ct 0..4 or 5..9
  int lane = threadIdx.x;
  int n = lane & 15, q = lane >> 4;
  const unsigned short* pr = (const unsigned short*)inr + (size_t)plane * HWp;
  const unsigned short* pi = ini ? (const unsigned short*)ini + (size_t)plane * HWp : nullptr;
  float srm = sclr ? sclr[plane] : 1.f;
  float sim = scli ? scli[plane] : 1.f;
  short8 br[5], bi[5];
  #pragma unroll
  for (int kc = 0; kc < 5; kc++) {
    br[kc] = *(const short8*)(pr + (a0 + n) * 160 + kc * 32 + q * 8);
    if (pi) bi[kc] = *(const short8*)(pi + (a0 + n) * 160 + kc * 32 + q * 8);
  }
  const short8* cf = (const short8*)cosF;
  const short8* sf = (const short8*)sinF;
  unsigned short* qr = (unsigned short*)outr + (size_t)plane * HWp;
  unsigned short* qi = (unsigned short*)outi + (size_t)plane * HWp;
  for (int ctl = 0; ctl < 5; ctl++) {
    int ct = cth + ctl;
    f32x4 arr = (f32x4){0.f,0.f,0.f,0.f}, asr = (f32x4){0.f,0.f,0.f,0.f};
    f32x4 ari = (f32x4){0.f,0.f,0.f,0.f}, asi = (f32x4){0.f,0.f,0.f,0.f};
    #pragma unroll
    for (int kc = 0; kc < 5; kc++) {
      short8 ca = cf[(ct * 5 + kc) * 64 + lane];
      short8 sa = sf[(ct * 5 + kc) * 64 + lane];
      arr = __builtin_amdgcn_mfma_f32_16x16x32_bf16(ca, br[kc], arr, 0, 0, 0);
      asr = __builtin_amdgcn_mfma_f32_16x16x32_bf16(sa, br[kc], asr, 0, 0, 0);
      if (pi) {
        ari = __builtin_amdgcn_mfma_f32_16x16x32_bf16(ca, bi[kc], ari, 0, 0, 0);
        asi = __builtin_amdgcn_mfma_f32_16x16x32_bf16(sa, bi[kc], asi, 0, 0, 0);
      }
    }
    #pragma unroll
    for (int j = 0; j < 4; j++) {
      int c = ct * 16 + q * 4 + j;
      float xc = srm * arr[j], xs = srm * asr[j];
      float ic = pi ? sim * ari[j] : 0.f, is = pi ? sim * asi[j] : 0.f;
      float orv = (xc - sgn * is) * scale;
      float oiv = (sgn * xs + ic) * scale;
      qr[c * 160 + a0 + n] = f2bu(orv);
      qi[c * 160 + a0 + n] = f2bu(oiv);
    }
  }
}

// ---------------- final inverse DFT pass, fused |.|, *gamma, += y ----------------
__global__ __launch_bounds__(64) void k_cpass_final_mfma(
    const bf16* __restrict__ inr, const bf16* __restrict__ ini,
    const short* __restrict__ cosF, const short* __restrict__ sinF,
    float sgn, float scale,
    const float* __restrict__ gamma, float* __restrict__ dout) {
  int plane = blockIdx.z;
  int a0 = blockIdx.x * 16;
  int cth = blockIdx.y * 5;
  int lane = threadIdx.x;
  int n = lane & 15, q = lane >> 4;
  const unsigned short* pr = (const unsigned short*)inr + (size_t)plane * HWp;
  const unsigned short* pi = (const unsigned short*)ini + (size_t)plane * HWp;
  short8 br[5], bi[5];
  #pragma unroll
  for (int kc = 0; kc < 5; kc++) {
    br[kc] = *(const short8*)(pr + (a0 + n) * 160 + kc * 32 + q * 8);
    bi[kc] = *(const short8*)(pi + (a0 + n) * 160 + kc * 32 + q * 8);
  }
  const short8* cf = (const short8*)cosF;
  const short8* sf = (const short8*)sinF;
  float gm = gamma[plane & 63];
  float* dp = dout + (size_t)plane * HWp;
  for (int ctl = 0; ctl < 5; ctl++) {
    int ct = cth + ctl;
    f32x4 arr = (f32x4){0.f,0.f,0.f,0.f}, asr = (f32x4){0.f,0.f,0.f,0.f};
    f32x4 ari = (f32x4){0.f,0.f,0.f,0.f}, asi = (f32x4){0.f,0.f,0.f,0.f};
    #pragma unroll
    for (int kc = 0; kc < 5; kc++) {
      short8 ca = cf[(ct * 5 + kc) * 64 + lane];
      short8 sa = sf[(ct * 5 + kc) * 64 + lane];
      arr = __builtin_amdgcn_mfma_f32_16x16x32_bf16(ca, br[kc], arr, 0, 0, 0);
      asr = __builtin_amdgcn_mfma_f32_16x16x32_bf16(sa, br[kc], asr, 0, 0, 0);
      ari = __builtin_amdgcn_mfma_f32_16x16x32_bf16(ca, bi[kc], ari, 0, 0, 0);
      asi = __builtin_amdgcn_mfma_f32_16x16x32_bf16(sa, bi[kc], asi, 0, 0, 0);
    }
    #pragma unroll
    for (int j = 0; j < 4; j++) {
      int c = ct * 16 + q * 4 + j;
      float orv = (arr[j] - sgn * asi[j]) * scale;
      float oiv = (sgn * asr[j] + ari[j]) * scale;
      float z = sqrtf(orv * orv + oiv * oiv);
      dp[c * 160 + a0 + n] += z * gm;   // dout currently holds y
    }
  }
}

// ---------------- FUSED fc1+gate+fc2: gated intermediate stays in LDS ----------------
// Phase 1: fc1 (128->256) + simple_gate -> gl[128][66] u16 (16.9 KB, padded stride).
// Phase 2: fc2 (128->128) reading B-frags from LDS; writes r/i planes.
// In-place safe: each block reads only its own 64 pixel-columns (consumed into regs
// before the barrier) and writes the same columns after.
__global__ __launch_bounds__(256) void k_fc12_mfma(
    const bf16* __restrict__ Fr, const bf16* __restrict__ Fi,
    const short* __restrict__ wA1, const float* __restrict__ b1,
    const short* __restrict__ wA2, const float* __restrict__ b2,
    bf16* __restrict__ Or, bf16* __restrict__ Oi) {
  __shared__ unsigned short gl[128][66];   // 16896 B
  int b = blockIdx.z;
  int lane = threadIdx.x & 63, w = threadIdx.x >> 6;
  int n = lane & 15, q = lane >> 4;
  int pxl = w * 16 + n;
  int px = blockIdx.x * 64 + pxl;
  const unsigned short* fr = (const unsigned short*)Fr + (size_t)b * Cc * HWp;
  const unsigned short* fi = (const unsigned short*)Fi + (size_t)b * Cc * HWp;
  const short8* wf1 = (const short8*)wA1;
  f32x4 acc[16];
  #pragma unroll
  for (int mt = 0; mt < 16; mt++) acc[mt] = (f32x4){0.f, 0.f, 0.f, 0.f};
  #pragma unroll
  for (int kc = 0; kc < 4; kc++) {
    const unsigned short* basep = (kc < 2) ? (fr + (size_t)(kc * 32) * HWp)
                                           : (fi + (size_t)((kc - 2) * 32) * HWp);
    short8 bfv;
    #pragma unroll
    for (int j = 0; j < 8; j++) bfv[j] = (short)basep[(size_t)(q * 8 + j) * HWp + px];
    #pragma unroll
    for (int mt = 0; mt < 16; mt++) {
      short8 af = wf1[(mt * 4 + kc) * 64 + lane];
      acc[mt] = __builtin_amdgcn_mfma_f32_16x16x32_bf16(af, bfv, acc[mt], 0, 0, 0);
    }
  }
  #pragma unroll
  for (int mt = 0; mt < 8; mt++)
    #pragma unroll
    for (int j = 0; j < 4; j++) {
      int o = mt * 16 + q * 4 + j;
      float v1 = acc[mt][j] + b1[o];
      float v2 = acc[mt + 8][j] + b1[o + 128];
      gl[o][pxl] = f2bu(v1 * v2);
    }
  __syncthreads();
  const short8* wf2 = (const short8*)wA2;
  f32x4 acc2[8];
  #pragma unroll
  for (int mt = 0; mt < 8; mt++) acc2[mt] = (f32x4){0.f, 0.f, 0.f, 0.f};
  #pragma unroll
  for (int kc = 0; kc < 4; kc++) {
    short8 bfv;
    #pragma unroll
    for (int j = 0; j < 8; j++) bfv[j] = (short)gl[kc * 32 + q * 8 + j][pxl];
    #pragma unroll
    for (int mt = 0; mt < 8; mt++) {
      short8 af = wf2[(mt * 4 + kc) * 64 + lane];
      acc2[mt] = __builtin_amdgcn_mfma_f32_16x16x32_bf16(af, bfv, acc2[mt], 0, 0, 0);
    }
  }
  unsigned short* orp = (unsigned short*)Or + (size_t)b * Cc * HWp;
  unsigned short* oip = (unsigned short*)Oi + (size_t)b * Cc * HWp;
  #pragma unroll
  for (int mt = 0; mt < 8; mt++)
    #pragma unroll
    for (int j = 0; j < 4; j++) {
      int o = mt * 16 + q * 4 + j;
      unsigned short hv = f2bu(acc2[mt][j] + b2[o]);
      if (o < 64) orp[(size_t)o * HWp + px] = hv;
      else        oip[(size_t)(o - 64) * HWp + px] = hv;
    }
}

extern "C" void kernel_launch(void* const* d_in, const int* in_sizes, int n_in,
                              void* d_out, int out_size, void* d_ws, size_t ws_size,
                              hipStream_t stream) {
  const float* inp   = (const float*)d_in[0];
  const float* n1w   = (const float*)d_in[1];
  const float* n1b   = (const float*)d_in[2];
  const float* n2w   = (const float*)d_in[3];
  const float* n2b   = (const float*)d_in[4];
  const float* scaw  = (const float*)d_in[5];
  const float* scab  = (const float*)d_in[6];
  const float* c11aw = (const float*)d_in[7];
  const float* c11ab = (const float*)d_in[8];
  const float* c11bw = (const float*)d_in[9];
  const float* c11bb = (const float*)d_in[10];
  const float* c1w   = (const float*)d_in[11];
  const float* c1b   = (const float*)d_in[12];
  const float* c21w  = (const float*)d_in[13];
  const float* c21b  = (const float*)d_in[14];
  const float* c2aw  = (const float*)d_in[15];
  const float* c2ab  = (const float*)d_in[16];
  const float* c2cw  = (const float*)d_in[17];
  const float* c2cb  = (const float*)d_in[18];
  const float* c211w = (const float*)d_in[19];
  const float* c211b = (const float*)d_in[20];
  const float* c3w   = (const float*)d_in[21];
  const float* c3b   = (const float*)d_in[22];
  const float* kbw   = (const float*)d_in[23];
  const float* kbb   = (const float*)d_in[24];
  const float* ga1   = (const float*)d_in[25];
  const float* attg  = (const float*)d_in[26];
  const float* beta  = (const float*)d_in[27];
  const float* gamma = (const float*)d_in[28];
  const float* fc1w  = (const float*)d_in[29];
  const float* fc1b  = (const float*)d_in[30];
  const float* fc2w  = (const float*)d_in[31];
  const float* fc2b  = (const float*)d_in[32];
  const float* fscaw = (const float*)d_in[33];
  const float* fscab = (const float*)d_in[34];

  const size_t S = (size_t)Bn * Cc * HWp;   // 3,276,800 elements per slot
  bf16* A  = (bf16*)d_ws;                   // 4 bf16 slots = 26.2 MB total
  bf16* Bs = A + S;
  bf16* Cs = A + 2 * S;
  bf16* Ds = A + 3 * S;
  float* smalls = (float*)(A + 4 * S);      // fp32 smalls
  float* xm   = smalls;
  float* scaV = smalls + 128;
  float* rmv  = smalls + 256;               // rmv[128]|imv[128]
  float* sra  = smalls + 512;               // sra[128]|sia[128]
  short* wS   = (short*)(smalls + 1024);    // bf16 frag tables
  short* wAf1 = wS;                         // 32768
  short* wAf2 = wAf1 + 32768;               // 16384
  short* cosF = wAf2 + 16384;               // 25600
  short* sinF = cosF + 25600;               // 25600
  short* wA_c11a = sinF + 25600;            // 4096
  short* wA_c1   = wA_c11a + 4096;          // 4096
  short* wA_c3   = wA_c1 + 4096;            // 4096
  short* wA_att  = wA_c3 + 4096;            // 3072
  short* kbwF    = wA_att + 3072;           // 81920 used
  bf16* gbuf = Bs;            // [B,32,HW] (first half of Bs)
  bf16* attb = Bs + S / 2;    // [B,32,HW] (second half of Bs)
  float* yb  = (float*)d_out; // y lives in d_out (fp32)

  dim3 cgrid(10, 2, Bn * Cc);
  dim3 pgrid(400, 1, Bn);

  k_prep_all<<<dim3(672), dim3(256), 0, stream>>>(kbw, kbb, kbwF, fc1w, fc2w, wAf1, wAf2,
                                                  cosF, sinF, c11aw, c1w, c3w, c2cw, c211w,
                                                  attg, wA_c11a, wA_c1, wA_c3, wA_att);
  k_ln<<<dim3(800), dim3(256), 0, stream>>>(inp, n1w, n1b, A);          // A = x
  k_meanhw<<<dim3(128), dim3(256), 0, stream>>>(A, xm);
  k_small_mv<<<dim3(1), dim3(128), 0, stream>>>(xm, scaw, scab, scaV, 0);
  k_conv1x1_dual<<<pgrid, dim3(256), 0, stream>>>(A, wA_c11a, c11ab, wA_c1, c1b, Bs, Ds); // B=t1 D=t2
  k_c11b_direct<<<dim3(3, 10, Bn * 16), dim3(256), 0, stream>>>(Bs, c11bw, c11bb, Cs); // C = x1
  k_c2a4<<<dim3(25, 32, Bn), dim3(256), 0, stream>>>(A, c2aw, c2ab, gbuf);         // B.lo = g
  k_att_mfma<<<pgrid, dim3(256), 0, stream>>>(gbuf, A, wA_att, c2cb, c211b, attg, attb); // B.hi
  k_c21dw4<<<dim3(25, 64, Bn), dim3(256), 0, stream>>>(Ds, c21w, c21b, A);         // A = uf
  k_kba_mfma<<<dim3(3, 160, Bn * 8), dim3(256), 0, stream>>>(A, attb, Cs, scaV, kbwF, ga1, Ds);
  k_c3y_ln2<<<pgrid, dim3(256), 0, stream>>>(Ds, wA_c3, c3b, beta, inp, yb, n2w, n2b, A); // y, A=X
  // forward FFT2 (MFMA)
  k_cpass_mfma<<<cgrid, dim3(64), 0, stream>>>(A, (const bf16*)nullptr, cosF, sinF, Bs, Cs, -1.f, SCL, nullptr, nullptr);
  k_cpass_mfma<<<cgrid, dim3(64), 0, stream>>>(Bs, Cs, cosF, sinF, Ds, A, -1.f, SCL, nullptr, nullptr);
  // fused fc1+gate+fc2 (in-place on Ds/A: each block owns its pixel columns)
  k_fc12_mfma<<<pgrid, dim3(256), 0, stream>>>(Ds, A, wAf1, fc1b, wAf2, fc2b, Ds, A); // D=r, A=i
  k_meanhw2<<<dim3(256), dim3(256), 0, stream>>>(Ds, A, rmv);                      // rmv|imv
  k_small_mv2<<<dim3(1), dim3(256), 0, stream>>>(rmv, fscaw, fscab, sra);          // sra|sia
  // inverse FFT2 (MFMA) with per-plane (1+ra)/(1+ia) scaling fused into first pass
  k_cpass_mfma<<<cgrid, dim3(64), 0, stream>>>(Ds, A, cosF, sinF, Bs, Cs, 1.f, SCL, sra, sra + 128);
  k_cpass_final_mfma<<<cgrid, dim3(64), 0, stream>>>(Bs, Cs, cosF, sinF, 1.f, SCL, gamma, yb);
}

// Round 17
// 425.377 us; speedup vs baseline: 1.0963x; 1.0109x over previous
//
#include <hip/hip_runtime.h>
#include <hip/hip_bf16.h>

typedef __hip_bfloat16 bf16;
typedef __attribute__((ext_vector_type(8))) short short8;
typedef __attribute__((ext_vector_type(4))) float f32x4;
typedef __attribute__((ext_vector_type(4))) unsigned short u16x4;

#define Hh 160
#define Wd 160
#define HWp (Hh*Wd)       // 25600
#define Bn 2
#define Cc 64
#define NPIX (Bn*HWp)     // 51200
#define SCL 0.07905694150420949f   // 1/sqrt(160)
#define TWO_PI_160 0.039269908169872414f  // 2*pi/160

static __device__ __forceinline__ float b2f(bf16 x) { return __bfloat162float(x); }
static __device__ __forceinline__ bf16 f2b(float f) { return __float2bfloat16(f); }
static __device__ __forceinline__ unsigned short f2bu(float f) {
  union { bf16 h; unsigned short u; } z; z.h = __float2bfloat16(f); return z.u;
}
static __device__ __forceinline__ float ubf(unsigned short u) {
  union { unsigned int i; float f; } z; z.i = ((unsigned int)u) << 16; return z.f;
}

// ---------------- LayerNorm over channel dim, single-pass ----------------
__global__ void k_ln(const float* __restrict__ in, const float* __restrict__ w,
                     const float* __restrict__ bb, bf16* __restrict__ out) {
  __shared__ float2 sm[4][64];
  int t = threadIdx.x;
  int pxl = t & 63, cq = t >> 6;
  int pix = blockIdx.x * 64 + pxl;          // 800 blocks cover NPIX
  int b = pix / HWp, p = pix - b * HWp;
  const float* src = in + ((size_t)b * Cc + cq * 16) * HWp + p;
  float v[16];
  float s = 0.f, s2 = 0.f;
  #pragma unroll
  for (int i = 0; i < 16; i++) {
    v[i] = src[(size_t)i * HWp];
    s += v[i]; s2 += v[i] * v[i];
  }
  sm[cq][pxl] = make_float2(s, s2);
  __syncthreads();
  float S = 0.f, S2 = 0.f;
  #pragma unroll
  for (int k = 0; k < 4; k++) { float2 z = sm[k][pxl]; S += z.x; S2 += z.y; }
  float mu = S * (1.f / 64.f);
  float var = S2 * (1.f / 64.f) - mu * mu;
  float rs = rsqrtf(fmaxf(var, 0.f) + 1e-6f);
  bf16* dst = out + ((size_t)b * Cc + cq * 16) * HWp + p;
  #pragma unroll
  for (int i = 0; i < 16; i++) {
    int c = cq * 16 + i;
    dst[(size_t)i * HWp] = f2b((v[i] - mu) * rs * w[c] + bb[c]);
  }
}

// ---------------- mean over HW per (b,c) plane (bf16 in) ----------------
__global__ void k_meanhw(const bf16* __restrict__ in, float* __restrict__ out) {
  int bc = blockIdx.x;
  const bf16* src = in + (size_t)bc * HWp;
  int t = threadIdx.x;
  float s = 0.f;
  for (int i = t; i < HWp; i += 256) s += b2f(src[i]);
  __shared__ float sm[256];
  sm[t] = s; __syncthreads();
  for (int off = 128; off; off >>= 1) { if (t < off) sm[t] += sm[t + off]; __syncthreads(); }
  if (t == 0) out[bc] = sm[0] * (1.f / HWp);
}

// ---------------- fused dual mean: bc<128 from in0, else in1 ----------------
__global__ void k_meanhw2(const bf16* __restrict__ in0, const bf16* __restrict__ in1,
                          float* __restrict__ out) {
  int bc = blockIdx.x;   // 0..255
  const bf16* src = (bc < 128) ? (in0 + (size_t)bc * HWp) : (in1 + (size_t)(bc - 128) * HWp);
  int t = threadIdx.x;
  float s = 0.f;
  for (int i = t; i < HWp; i += 256) s += b2f(src[i]);
  __shared__ float sm[256];
  sm[t] = s; __syncthreads();
  for (int off = 128; off; off >>= 1) { if (t < off) sm[t] += sm[t + off]; __syncthreads(); }
  if (t == 0) out[bc] = sm[0] * (1.f / HWp);
}

// ---------------- small matvec ----------------
__global__ void k_small_mv(const float* __restrict__ xin, const float* __restrict__ w,
                           const float* __restrict__ bias, float* __restrict__ out, int addone) {
  int t = threadIdx.x;              // 128 threads
  int b = t >> 6, o = t & 63;
  float acc = bias[o];
  for (int k = 0; k < 64; k++) acc += w[o * 64 + k] * xin[b * 64 + k];
  out[t] = addone ? (1.f + acc) : acc;
}

// ---------------- fused dual small matvec ----------------
__global__ void k_small_mv2(const float* __restrict__ xin, const float* __restrict__ w,
                            const float* __restrict__ bias, float* __restrict__ out) {
  int t = threadIdx.x;              // 256 threads
  int half = t >> 7, r = t & 127;
  int b = r >> 6, o = r & 63;
  const float* x = xin + half * 128 + b * 64;
  float acc = bias[o];
  for (int k = 0; k < 64; k++) acc += w[o * 64 + k] * x[k];
  out[half * 128 + r] = 1.f + acc;
}

// ---------------- depthwise 3x3 vectorized, 4 px/thread ----------------
__global__ void k_c21dw4(const bf16* __restrict__ in, const float* __restrict__ w,
                         const float* __restrict__ bias, bf16* __restrict__ out) {
  int t = threadIdx.x;
  int c = blockIdx.y, b = blockIdx.z;
  int pq = blockIdx.x * 256 + t;            // grid.x = 25
  int h = pq / 40, x4 = (pq - h * 40) * 4;
  const unsigned short* src = (const unsigned short*)in + ((size_t)b * Cc + c) * HWp;
  float wv[9];
  #pragma unroll
  for (int i = 0; i < 9; i++) wv[i] = w[c * 9 + i];
  float bs = bias[c];
  float acc[4] = {bs, bs, bs, bs};
  #pragma unroll
  for (int ki = 0; ki < 3; ki++) {
    int hh = h + ki - 1;
    if ((unsigned)hh >= Hh) continue;
    const unsigned short* row = src + hh * Wd + x4;
    float v[6];
    u16x4 m = *(const u16x4*)row;
    v[1] = ubf(m[0]); v[2] = ubf(m[1]); v[3] = ubf(m[2]); v[4] = ubf(m[3]);
    v[0] = (x4 > 0) ? ubf(row[-1]) : 0.f;
    v[5] = (x4 + 4 < Wd) ? ubf(row[4]) : 0.f;
    #pragma unroll
    for (int j = 0; j < 4; j++)
      #pragma unroll
      for (int kj = 0; kj < 3; kj++)
        acc[j] = fmaf(wv[ki * 3 + kj], v[j + kj], acc[j]);
  }
  u16x4 pk;
  #pragma unroll
  for (int j = 0; j < 4; j++) pk[j] = f2bu(acc[j]);
  *(u16x4*)((unsigned short*)out + ((size_t)b * Cc + c) * HWp + h * Wd + x4) = pk;
}

// ---------------- fused weight prep ----------------
__global__ void k_prep_all(const float* __restrict__ kbw, const float* __restrict__ kbb,
                           short* __restrict__ kbwF,
                           const float* __restrict__ fc1w, const float* __restrict__ fc2w,
                           short* __restrict__ wAf1, short* __restrict__ wAf2,
                           short* __restrict__ cosF, short* __restrict__ sinF,
                           const float* __restrict__ c11aw, const float* __restrict__ c1w,
                           const float* __restrict__ c3w, const float* __restrict__ c2cw,
                           const float* __restrict__ c211w, const float* __restrict__ attg,
                           short* __restrict__ wA_c11a, short* __restrict__ wA_c1,
                           short* __restrict__ wA_c3, short* __restrict__ wA_att) {
  int i = blockIdx.x * 256 + threadIdx.x;   // 172032 total (672 blocks)
  if (i < 81920) {
    int g = i / 5120, r = i - g * 5120;
    float v = 0.f;
    if (r < 4096) {
      int j = r & 7, lane = (r >> 3) & 63, mt = r >> 9;
      int m = mt * 16 + (lane & 15);
      int s = m >> 2, o = m & 3;
      int k = (lane >> 4) * 8 + j;
      v = kbw[s * 2304 + g * 144 + o * 36 + k];
    } else {
      int r2 = r - 4096;
      int j = r2 & 7, n = (r2 >> 3) & 15, mt = r2 >> 7;
      int m = mt * 16 + n;
      int s = m >> 2, o = m & 3;
      int k = 32 + j;
      if (k < 36) v = kbw[s * 2304 + g * 144 + o * 36 + k];
      else if (k == 36) v = kbb[s * 64 + g * 4 + o];
    }
    kbwF[i] = (short)f2bu(v);
  } else if (i < 131072) {
    int i1 = i - 81920;
    if (i1 < 32768) {
      int j = i1 & 7, lane = (i1 >> 3) & 63, fk = i1 >> 9;
      int kc = fk & 3, mt = fk >> 2;
      int o = mt * 16 + (lane & 15);
      int k = kc * 32 + (lane >> 4) * 8 + j;
      wAf1[i1] = (short)f2bu(fc1w[o * 128 + k]);
    } else {
      int i2 = i1 - 32768;
      int j = i2 & 7, lane = (i2 >> 3) & 63, fk = i2 >> 9;
      int kc = fk & 3, mt = fk >> 2;
      int o = mt * 16 + (lane & 15);
      int k = kc * 32 + (lane >> 4) * 8 + j;
      wAf2[i2] = (short)f2bu(fc2w[o * 128 + k]);
    }
  } else if (i < 156672) {
    int i2 = i - 131072;
    int j = i2 & 7, lane = (i2 >> 3) & 63, fk = i2 >> 9;   // fk = ct*5+kc
    int kc = fk % 5, ct = fk / 5;
    int c = ct * 16 + (lane & 15);
    int bb2 = kc * 32 + (lane >> 4) * 8 + j;
    int m = (bb2 * c) % 160;
    float sv, cv;
    __sincosf((float)m * TWO_PI_160, &sv, &cv);
    cosF[i2] = (short)f2bu(cv);
    sinF[i2] = (short)f2bu(sv);
  } else {
    int i3 = i - 156672;
    if (i3 < 12288) {
      int wi = i3 / 4096, r = i3 - wi * 4096;
      int j = r & 7, lane = (r >> 3) & 63, fk = r >> 9;
      int kc = fk & 1, mt = fk >> 1;
      int o = mt * 16 + (lane & 15);
      int k = kc * 32 + (lane >> 4) * 8 + j;
      const float* w = (wi == 0) ? c11aw : (wi == 1) ? c1w : c3w;
      short* dst = (wi == 0) ? wA_c11a : (wi == 1) ? wA_c1 : wA_c3;
      dst[r] = (short)f2bu(w[o * 64 + k]);
    } else {
      int r = i3 - 12288;
      int j = r & 7, lane = (r >> 3) & 63, fk = r >> 9;
      int kc = fk % 3, mt = fk / 3;
      int s = mt * 16 + (lane & 15);
      int k = kc * 32 + (lane >> 4) * 8 + j;
      float v;
      if (k < 16) v = c2cw[s * 16 + k] * attg[s];
      else if (k < 32) v = 0.f;
      else v = c211w[s * 64 + (k - 32)];
      wA_att[r] = (short)f2bu(v);
    }
  }
}

// ---------------- dual 1x1 conv 64->64 via MFMA (t1 and t2 share input fragments) ----------------
__global__ __launch_bounds__(256) void k_conv1x1_dual(
    const bf16* __restrict__ in, const short* __restrict__ wA1,
    const float* __restrict__ b1, const short* __restrict__ wA2,
    const float* __restrict__ b2, bf16* __restrict__ out1, bf16* __restrict__ out2) {
  int b = blockIdx.z;
  int lane = threadIdx.x & 63, w = threadIdx.x >> 6;
  int px = blockIdx.x * 64 + w * 16 + (lane & 15);
  int q = lane >> 4;
  const unsigned short* src = (const unsigned short*)in + (size_t)b * Cc * HWp;
  const short8* wf1 = (const short8*)wA1;
  const short8* wf2 = (const short8*)wA2;
  f32x4 acc1[4], acc2[4];
  #pragma unroll
  for (int mt = 0; mt < 4; mt++) {
    acc1[mt] = (f32x4){0.f, 0.f, 0.f, 0.f};
    acc2[mt] = (f32x4){0.f, 0.f, 0.f, 0.f};
  }
  #pragma unroll
  for (int kc = 0; kc < 2; kc++) {
    short8 bfv;
    #pragma unroll
    for (int j = 0; j < 8; j++) bfv[j] = (short)src[(size_t)(kc * 32 + q * 8 + j) * HWp + px];
    #pragma unroll
    for (int mt = 0; mt < 4; mt++) {
      short8 a1 = wf1[(mt * 2 + kc) * 64 + lane];
      acc1[mt] = __builtin_amdgcn_mfma_f32_16x16x32_bf16(a1, bfv, acc1[mt], 0, 0, 0);
      short8 a2 = wf2[(mt * 2 + kc) * 64 + lane];
      acc2[mt] = __builtin_amdgcn_mfma_f32_16x16x32_bf16(a2, bfv, acc2[mt], 0, 0, 0);
    }
  }
  unsigned short* d1 = (unsigned short*)out1 + (size_t)b * Cc * HWp;
  unsigned short* d2 = (unsigned short*)out2 + (size_t)b * Cc * HWp;
  #pragma unroll
  for (int mt = 0; mt < 4; mt++)
    #pragma unroll
    for (int j = 0; j < 4; j++) {
      int o = mt * 16 + q * 4 + j;
      d1[(size_t)o * HWp + px] = f2bu(acc1[mt][j] + b1[o]);
      d2[(size_t)o * HWp + px] = f2bu(acc2[mt][j] + b2[o]);
    }
}

// ---------------- c3 1x1 conv + residual + FUSED LayerNorm2 ----------------
__global__ __launch_bounds__(256) void k_c3y_ln2(
    const bf16* __restrict__ in, const short* __restrict__ wA,
    const float* __restrict__ bias, const float* __restrict__ beta,
    const float* __restrict__ inp, float* __restrict__ y,
    const float* __restrict__ n2w, const float* __restrict__ n2b,
    bf16* __restrict__ Xout) {
  int b = blockIdx.z;
  int lane = threadIdx.x & 63, w = threadIdx.x >> 6;
  int px = blockIdx.x * 64 + w * 16 + (lane & 15);
  int q = lane >> 4;
  const unsigned short* src = (const unsigned short*)in + (size_t)b * Cc * HWp;
  const short8* wf = (const short8*)wA;
  f32x4 acc[4];
  #pragma unroll
  for (int mt = 0; mt < 4; mt++) acc[mt] = (f32x4){0.f, 0.f, 0.f, 0.f};
  #pragma unroll
  for (int kc = 0; kc < 2; kc++) {
    short8 bfv;
    #pragma unroll
    for (int j = 0; j < 8; j++) bfv[j] = (short)src[(size_t)(kc * 32 + q * 8 + j) * HWp + px];
    #pragma unroll
    for (int mt = 0; mt < 4; mt++) {
      short8 af = wf[(mt * 2 + kc) * 64 + lane];
      acc[mt] = __builtin_amdgcn_mfma_f32_16x16x32_bf16(af, bfv, acc[mt], 0, 0, 0);
    }
  }
  float yv[4][4];
  float s = 0.f, s2 = 0.f;
  #pragma unroll
  for (int mt = 0; mt < 4; mt++)
    #pragma unroll
    for (int j = 0; j < 4; j++) {
      int o = mt * 16 + q * 4 + j;
      size_t oi = ((size_t)b * Cc + o) * HWp + px;
      float v = inp[oi] + (acc[mt][j] + bias[o]) * beta[o];
      y[oi] = v;
      yv[mt][j] = v;
      s += v; s2 += v * v;
    }
  s  += __shfl_xor(s, 16);  s  += __shfl_xor(s, 32);
  s2 += __shfl_xor(s2, 16); s2 += __shfl_xor(s2, 32);
  float mu = s * (1.f / 64.f);
  float var = s2 * (1.f / 64.f) - mu * mu;
  float rs = rsqrtf(fmaxf(var, 0.f) + 1e-6f);
  unsigned short* Xu = (unsigned short*)Xout + (size_t)b * Cc * HWp;
  #pragma unroll
  for (int mt = 0; mt < 4; mt++)
    #pragma unroll
    for (int j = 0; j < 4; j++) {
      int o = mt * 16 + q * 4 + j;
      Xu[(size_t)o * HWp + px] = f2bu((yv[mt][j] - mu) * rs * n2w[o] + n2b[o]);
    }
}

// ---------------- FUSED c2a + att: gate conv in LDS, then att MFMA ----------------
__global__ __launch_bounds__(256) void k_att_fused(
    const bf16* __restrict__ x, const float* __restrict__ c2aw, const float* __restrict__ c2ab,
    const short* __restrict__ wA, const float* __restrict__ c2cb,
    const float* __restrict__ c211b, const float* __restrict__ attg,
    bf16* __restrict__ att) {
  __shared__ unsigned short gateL[32][66];   // 4224 B
  int b = blockIdx.z;
  int t = threadIdx.x;
  int p0 = blockIdx.x * 64;
  const unsigned short* xs = (const unsigned short*)x + (size_t)b * Cc * HWp;
  // phase 1: gate conv (c2a): 32 o-channels x 16 quads
  for (int task = t; task < 512; task += 256) {
    int o = task >> 4, q4 = task & 15;
    int px4 = p0 + q4 * 4;
    int h = px4 / Wd, x4 = px4 - h * Wd;
    float bs = c2ab[o];
    float acc[4] = {bs, bs, bs, bs};
    #pragma unroll
    for (int ci = 0; ci < 2; ci++) {
      const unsigned short* src = xs + (size_t)(o * 2 + ci) * HWp;
      float wv[9];
      #pragma unroll
      for (int i = 0; i < 9; i++) wv[i] = c2aw[(o * 2 + ci) * 9 + i];
      #pragma unroll
      for (int ki = 0; ki < 3; ki++) {
        int hh = h + ki - 1;
        if ((unsigned)hh >= Hh) continue;
        const unsigned short* row = src + hh * Wd + x4;
        float v[6];
        u16x4 m = *(const u16x4*)row;
        v[1] = ubf(m[0]); v[2] = ubf(m[1]); v[3] = ubf(m[2]); v[4] = ubf(m[3]);
        v[0] = (x4 > 0) ? ubf(row[-1]) : 0.f;
        v[5] = (x4 + 4 < Wd) ? ubf(row[4]) : 0.f;
        #pragma unroll
        for (int j = 0; j < 4; j++)
          #pragma unroll
          for (int kj = 0; kj < 3; kj++)
            acc[j] = fmaf(wv[ki * 3 + kj], v[j + kj], acc[j]);
      }
    }
    #pragma unroll
    for (int j = 0; j < 4; j++) gateL[o][q4 * 4 + j] = f2bu(acc[j]);
  }
  __syncthreads();
  // phase 2: att MFMA
  int lane = t & 63, w = t >> 6;
  int pxl = w * 16 + (lane & 15);
  int px = p0 + pxl;
  int q = lane >> 4;
  const short8* wf = (const short8*)wA;
  f32x4 acc[2];
  acc[0] = (f32x4){0.f, 0.f, 0.f, 0.f};
  acc[1] = (f32x4){0.f, 0.f, 0.f, 0.f};
  {
    short8 bfv;
    #pragma unroll
    for (int j = 0; j < 8; j++) {
      int k = q * 8 + j;
      short v = 0;
      if (q < 2) {
        float gv = ubf(gateL[k][pxl]) * ubf(gateL[16 + k][pxl]);
        v = (short)f2bu(gv);
      }
      bfv[j] = v;
    }
    #pragma unroll
    for (int mt = 0; mt < 2; mt++) {
      short8 af = wf[(mt * 3 + 0) * 64 + lane];
      acc[mt] = __builtin_amdgcn_mfma_f32_16x16x32_bf16(af, bfv, acc[mt], 0, 0, 0);
    }
  }
  #pragma unroll
  for (int kc = 1; kc < 3; kc++) {
    short8 bfv;
    #pragma unroll
    for (int j = 0; j < 8; j++)
      bfv[j] = (short)xs[(size_t)((kc - 1) * 32 + q * 8 + j) * HWp + px];
    #pragma unroll
    for (int mt = 0; mt < 2; mt++) {
      short8 af = wf[(mt * 3 + kc) * 64 + lane];
      acc[mt] = __builtin_amdgcn_mfma_f32_16x16x32_bf16(af, bfv, acc[mt], 0, 0, 0);
    }
  }
  unsigned short* dst = (unsigned short*)att + (size_t)b * 32 * HWp;
  #pragma unroll
  for (int mt = 0; mt < 2; mt++)
    #pragma unroll
    for (int j = 0; j < 4; j++) {
      int s = mt * 16 + q * 4 + j;
      dst[(size_t)s * HWp + px] = f2bu(acc[mt][j] + c2cb[s] * attg[s] + c211b[s]);
    }
}

// ---------------- c11b direct: grouped 5x5 conv, 16-row tiles ----------------
__global__ __launch_bounds__(256) void k_c11b_direct(
    const bf16* __restrict__ t1, const float* __restrict__ w,
    const float* __restrict__ bias, bf16* __restrict__ out) {
  __shared__ float xs[4 * 20 * 68];        // 21760 B
  __shared__ float wsm[4 * 5 * 4 * 5];
  __shared__ float bsm[4];
  int bz = blockIdx.z;                     // b*16 + g
  int b = bz >> 4, g = bz & 15;
  int h0 = blockIdx.y * 16;
  int w0 = blockIdx.x * 64;
  int t = threadIdx.x;
  for (int i = t; i < 400; i += 256) {
    int kj = i % 5, rem = i / 5;
    int o = rem & 3; rem >>= 2;
    int ki = rem % 5, ci = rem / 5;
    wsm[i] = w[((g * 4 + o) * 4 + ci) * 25 + ki * 5 + kj];
  }
  if (t < 4) bsm[t] = bias[g * 4 + t];
  const unsigned short* src = (const unsigned short*)t1 + ((size_t)b * Cc + g * 4) * HWp;
  for (int i = t; i < 4 * 20 * 68; i += 256) {
    int ci = i / 1360, rem2 = i - ci * 1360;
    int r = rem2 / 68, col = rem2 - r * 68;
    int hh = h0 + r - 2, ww = w0 + col - 2;
    float v = 0.f;
    if ((unsigned)hh < Hh && (unsigned)ww < Wd)
      v = ubf(src[(size_t)ci * HWp + hh * Wd + ww]);
    xs[i] = v;
  }
  __syncthreads();
  int wq = t & 15, hq = t >> 4;
  float acc[4][4];
  #pragma unroll
  for (int o = 0; o < 4; o++)
    #pragma unroll
    for (int j = 0; j < 4; j++) acc[o][j] = bsm[o];
  #pragma unroll
  for (int ci = 0; ci < 4; ci++) {
    #pragma unroll
    for (int ki = 0; ki < 5; ki++) {
      const float* wrow = &wsm[(ci * 5 + ki) * 20];
      float wv[20];
      #pragma unroll
      for (int x = 0; x < 20; x++) wv[x] = wrow[x];
      const float* xrow = &xs[ci * 1360 + (hq + ki) * 68 + wq * 4];
      float xv[8];
      #pragma unroll
      for (int x = 0; x < 8; x++) xv[x] = xrow[x];
      #pragma unroll
      for (int o = 0; o < 4; o++)
        #pragma unroll
        for (int j = 0; j < 4; j++)
          #pragma unroll
          for (int kj = 0; kj < 5; kj++)
            acc[o][j] = fmaf(wv[o * 5 + kj], xv[j + kj], acc[o][j]);
    }
  }
  int width = Wd - w0;
  if (wq * 4 < width) {
    unsigned short* dst = (unsigned short*)out + ((size_t)b * Cc + g * 4) * HWp
                        + (h0 + hq) * Wd + w0 + wq * 4;
    #pragma unroll
    for (int o = 0; o < 4; o++) {
      u16x4 pk;
      #pragma unroll
      for (int j = 0; j < 4; j++) pk[j] = f2bu(acc[o][j]);
      *(u16x4*)(dst + (size_t)o * HWp) = pk;
    }
  }
}

// ---------------- KBA via MFMA: packed A-frags LDS-staged (20 KB), 2 groups/block ----------------
__global__ __launch_bounds__(256) void k_kba_mfma(
    const bf16* __restrict__ uf, const bf16* __restrict__ att,
    const bf16* __restrict__ x1, const float* __restrict__ scaV,
    const short* __restrict__ kbwF, const float* __restrict__ ga1,
    bf16* __restrict__ out) {
  __shared__ short8 fragL[1280];                   // 20480 B (2 groups x 640)
  __shared__ unsigned short patchL[8 * 3 * 66];    // 3168 B
  __shared__ unsigned short attL[64][33];          // 4224 B
  int bz = blockIdx.z;
  int b = bz >> 3, gp = bz & 7;
  int h = blockIdx.y;
  int w0 = blockIdx.x * 64;
  int width = min(64, Wd - w0);
  int t = threadIdx.x;
  int c0 = gp * 8;
  const short8* src8 = (const short8*)kbwF + (size_t)gp * 1280;
  #pragma unroll
  for (int i = 0; i < 5; i++) fragL[t + i * 256] = src8[t + i * 256];
  const unsigned short* uf_u = (const unsigned short*)uf;
  for (int i = t; i < 8 * 3 * 66; i += 256) {
    int cl = i / 198, rem = i - cl * 198;
    int r = rem / 66, col = rem - r * 66;
    int hh = h + r - 1, ww = w0 + col - 1;
    unsigned short v = 0;
    if ((unsigned)hh < Hh && (unsigned)ww < Wd)
      v = uf_u[((size_t)b * Cc + c0 + cl) * HWp + hh * Wd + ww];
    patchL[i] = v;
  }
  const unsigned short* att_u = (const unsigned short*)att + (size_t)b * 32 * HWp;
  for (int i = t; i < 64 * 32; i += 256) {
    int px = i & 63, s = i >> 6;
    unsigned short v = 0;
    if (px < width) v = att_u[(size_t)s * HWp + h * Wd + w0 + px];
    attL[px][s] = v;
  }
  __syncthreads();
  int lane = t & 63, w = t >> 6;
  int n = lane & 15, q = lane >> 4;
  int pxl = w * 16 + n;
  float attR[8];
  #pragma unroll
  for (int mt = 0; mt < 8; mt++) attR[mt] = ubf(attL[pxl][4 * mt + q]);
  int offA[8];
  #pragma unroll
  for (int j = 0; j < 8; j++) {
    int k = q * 8 + j;
    int ci = k / 9, r = k - ci * 9, ki = r / 3, kj = r - ki * 3;
    offA[j] = ci * 198 + ki * 66 + pxl + kj;
  }
  int offB[4];
  #pragma unroll
  for (int j = 0; j < 4; j++) {
    int k = 32 + j, r = k - 27, ki = r / 3, kj = r - ki * 3;
    offB[j] = 3 * 198 + ki * 66 + pxl + kj;
  }
  const unsigned short* x1u = (const unsigned short*)x1 + (size_t)b * Cc * HWp + h * Wd + w0;
  unsigned short* outu = (unsigned short*)out + (size_t)b * Cc * HWp + h * Wd + w0;
  #pragma unroll
  for (int gl = 0; gl < 2; gl++) {
    int g = gp * 2 + gl;
    const short8* fgl = fragL + gl * 640;
    short8 b0, b1;
    #pragma unroll
    for (int j = 0; j < 8; j++) b0[j] = (short)patchL[gl * 792 + offA[j]];
    #pragma unroll
    for (int j = 0; j < 8; j++) b1[j] = 0;
    if (q == 0) {
      #pragma unroll
      for (int j = 0; j < 4; j++) b1[j] = (short)patchL[gl * 792 + offB[j]];
      b1[4] = (short)0x3F80;                 // B[36][*] = 1.0 (bias row)
    }
    f32x4 acc[8];
    #pragma unroll
    for (int mt = 0; mt < 8; mt++) acc[mt] = (f32x4){0.f, 0.f, 0.f, 0.f};
    #pragma unroll
    for (int mt = 0; mt < 8; mt++) {
      short8 a0 = fgl[mt * 64 + lane];
      acc[mt] = __builtin_amdgcn_mfma_f32_16x16x32_bf16(a0, b0, acc[mt], 0, 0, 0);
      short8 a1 = (short8){0,0,0,0,0,0,0,0};
      if (q == 0) a1 = fgl[512 + mt * 16 + n];
      acc[mt] = __builtin_amdgcn_mfma_f32_16x16x32_bf16(a1, b1, acc[mt], 0, 0, 0);
    }
    #pragma unroll
    for (int o = 0; o < 4; o++) {
      float P = 0.f;
      #pragma unroll
      for (int mt = 0; mt < 8; mt++) P += attR[mt] * acc[mt][o];
      P += __shfl_xor(P, 16);
      P += __shfl_xor(P, 32);
      if (o == q && pxl < width) {
        int c = g * 4 + q;
        float ufc = ubf(patchL[(gl * 4 + q) * 198 + 66 + pxl + 1]);   // center tap
        float xk = P * ga1[c] + ufc;
        float xv = xk * ubf(x1u[(size_t)c * HWp + pxl]) * scaV[b * 64 + c];
        outu[(size_t)c * HWp + pxl] = f2bu(xv);
      }
    }
  }
}

// ---------------- DFT pass via MFMA (5-ct loop, fragment reuse) ----------------
__global__ __launch_bounds__(64) void k_cpass_mfma(
    const bf16* __restrict__ inr, const bf16* __restrict__ ini,
    const short* __restrict__ cosF, const short* __restrict__ sinF,
    bf16* __restrict__ outr, bf16* __restrict__ outi,
    float sgn, float scale,
    const float* __restrict__ sclr, const float* __restrict__ scli) {
  int plane = blockIdx.z;
  int a0 = blockIdx.x * 16;
  int cth = blockIdx.y * 5;          // c-half: ct 0..4 or 5..9
  int lane = threadIdx.x;
  int n = lane & 15, q = lane >> 4;
  const unsigned short* pr = (const unsigned short*)inr + (size_t)plane * HWp;
  const unsigned short* pi = ini ? (const unsigned short*)ini + (size_t)plane * HWp : nullptr;
  float srm = sclr ? sclr[plane] : 1.f;
  float sim = scli ? scli[plane] : 1.f;
  short8 br[5], bi[5];
  #pragma unroll
  for (int kc = 0; kc < 5; kc++) {
    br[kc] = *(const short8*)(pr + (a0 + n) * 160 + kc * 32 + q * 8);
    if (pi) bi[kc] = *(const short8*)(pi + (a0 + n) * 160 + kc * 32 + q * 8);
  }
  const short8* cf = (const short8*)cosF;
  const short8* sf = (const short8*)sinF;
  unsigned short* qr = (unsigned short*)outr + (size_t)plane * HWp;
  unsigned short* qi = (unsigned short*)outi + (size_t)plane * HWp;
  for (int ctl = 0; ctl < 5; ctl++) {
    int ct = cth + ctl;
    f32x4 arr = (f32x4){0.f,0.f,0.f,0.f}, asr = (f32x4){0.f,0.f,0.f,0.f};
    f32x4 ari = (f32x4){0.f,0.f,0.f,0.f}, asi = (f32x4){0.f,0.f,0.f,0.f};
    #pragma unroll
    for (int kc = 0; kc < 5; kc++) {
      short8 ca = cf[(ct * 5 + kc) * 64 + lane];
      short8 sa = sf[(ct * 5 + kc) * 64 + lane];
      arr = __builtin_amdgcn_mfma_f32_16x16x32_bf16(ca, br[kc], arr, 0, 0, 0);
      asr = __builtin_amdgcn_mfma_f32_16x16x32_bf16(sa, br[kc], asr, 0, 0, 0);
      if (pi) {
        ari = __builtin_amdgcn_mfma_f32_16x16x32_bf16(ca, bi[kc], ari, 0, 0, 0);
        asi = __builtin_amdgcn_mfma_f32_16x16x32_bf16(sa, bi[kc], asi, 0, 0, 0);
      }
    }
    #pragma unroll
    for (int j = 0; j < 4; j++) {
      int c = ct * 16 + q * 4 + j;
      float xc = srm * arr[j], xs = srm * asr[j];
      float ic = pi ? sim * ari[j] : 0.f, is = pi ? sim * asi[j] : 0.f;
      float orv = (xc - sgn * is) * scale;
      float oiv = (sgn * xs + ic) * scale;
      qr[c * 160 + a0 + n] = f2bu(orv);
      qi[c * 160 + a0 + n] = f2bu(oiv);
    }
  }
}

// ---------------- final inverse DFT pass, fused |.|, *gamma, += y ----------------
__global__ __launch_bounds__(64) void k_cpass_final_mfma(
    const bf16* __restrict__ inr, const bf16* __restrict__ ini,
    const short* __restrict__ cosF, const short* __restrict__ sinF,
    float sgn, float scale,
    const float* __restrict__ gamma, float* __restrict__ dout) {
  int plane = blockIdx.z;
  int a0 = blockIdx.x * 16;
  int cth = blockIdx.y * 5;
  int lane = threadIdx.x;
  int n = lane & 15, q = lane >> 4;
  const unsigned short* pr = (const unsigned short*)inr + (size_t)plane * HWp;
  const unsigned short* pi = (const unsigned short*)ini + (size_t)plane * HWp;
  short8 br[5], bi[5];
  #pragma unroll
  for (int kc = 0; kc < 5; kc++) {
    br[kc] = *(const short8*)(pr + (a0 + n) * 160 + kc * 32 + q * 8);
    bi[kc] = *(const short8*)(pi + (a0 + n) * 160 + kc * 32 + q * 8);
  }
  const short8* cf = (const short8*)cosF;
  const short8* sf = (const short8*)sinF;
  float gm = gamma[plane & 63];
  float* dp = dout + (size_t)plane * HWp;
  for (int ctl = 0; ctl < 5; ctl++) {
    int ct = cth + ctl;
    f32x4 arr = (f32x4){0.f,0.f,0.f,0.f}, asr = (f32x4){0.f,0.f,0.f,0.f};
    f32x4 ari = (f32x4){0.f,0.f,0.f,0.f}, asi = (f32x4){0.f,0.f,0.f,0.f};
    #pragma unroll
    for (int kc = 0; kc < 5; kc++) {
      short8 ca = cf[(ct * 5 + kc) * 64 + lane];
      short8 sa = sf[(ct * 5 + kc) * 64 + lane];
      arr = __builtin_amdgcn_mfma_f32_16x16x32_bf16(ca, br[kc], arr, 0, 0, 0);
      asr = __builtin_amdgcn_mfma_f32_16x16x32_bf16(sa, br[kc], asr, 0, 0, 0);
      ari = __builtin_amdgcn_mfma_f32_16x16x32_bf16(ca, bi[kc], ari, 0, 0, 0);
      asi = __builtin_amdgcn_mfma_f32_16x16x32_bf16(sa, bi[kc], asi, 0, 0, 0);
    }
    #pragma unroll
    for (int j = 0; j < 4; j++) {
      int c = ct * 16 + q * 4 + j;
      float orv = (arr[j] - sgn * asi[j]) * scale;
      float oiv = (sgn * asr[j] + ari[j]) * scale;
      float z = sqrtf(orv * orv + oiv * oiv);
      dp[c * 160 + a0 + n] += z * gm;   // dout currently holds y
    }
  }
}

// ---------------- FUSED fc1+gate+fc2: gated intermediate stays in LDS ----------------
__global__ __launch_bounds__(256) void k_fc12_mfma(
    const bf16* __restrict__ Fr, const bf16* __restrict__ Fi,
    const short* __restrict__ wA1, const float* __restrict__ b1,
    const short* __restrict__ wA2, const float* __restrict__ b2,
    bf16* __restrict__ Or, bf16* __restrict__ Oi) {
  __shared__ unsigned short gl[128][66];   // 16896 B
  int b = blockIdx.z;
  int lane = threadIdx.x & 63, w = threadIdx.x >> 6;
  int n = lane & 15, q = lane >> 4;
  int pxl = w * 16 + n;
  int px = blockIdx.x * 64 + pxl;
  const unsigned short* fr = (const unsigned short*)Fr + (size_t)b * Cc * HWp;
  const unsigned short* fi = (const unsigned short*)Fi + (size_t)b * Cc * HWp;
  const short8* wf1 = (const short8*)wA1;
  f32x4 acc[16];
  #pragma unroll
  for (int mt = 0; mt < 16; mt++) acc[mt] = (f32x4){0.f, 0.f, 0.f, 0.f};
  #pragma unroll
  for (int kc = 0; kc < 4; kc++) {
    const unsigned short* basep = (kc < 2) ? (fr + (size_t)(kc * 32) * HWp)
                                           : (fi + (size_t)((kc - 2) * 32) * HWp);
    short8 bfv;
    #pragma unroll
    for (int j = 0; j < 8; j++) bfv[j] = (short)basep[(size_t)(q * 8 + j) * HWp + px];
    #pragma unroll
    for (int mt = 0; mt < 16; mt++) {
      short8 af = wf1[(mt * 4 + kc) * 64 + lane];
      acc[mt] = __builtin_amdgcn_mfma_f32_16x16x32_bf16(af, bfv, acc[mt], 0, 0, 0);
    }
  }
  #pragma unroll
  for (int mt = 0; mt < 8; mt++)
    #pragma unroll
    for (int j = 0; j < 4; j++) {
      int o = mt * 16 + q * 4 + j;
      float v1 = acc[mt][j] + b1[o];
      float v2 = acc[mt + 8][j] + b1[o + 128];
      gl[o][pxl] = f2bu(v1 * v2);
    }
  __syncthreads();
  const short8* wf2 = (const short8*)wA2;
  f32x4 acc2[8];
  #pragma unroll
  for (int mt = 0; mt < 8; mt++) acc2[mt] = (f32x4){0.f, 0.f, 0.f, 0.f};
  #pragma unroll
  for (int kc = 0; kc < 4; kc++) {
    short8 bfv;
    #pragma unroll
    for (int j = 0; j < 8; j++) bfv[j] = (short)gl[kc * 32 + q * 8 + j][pxl];
    #pragma unroll
    for (int mt = 0; mt < 8; mt++) {
      short8 af = wf2[(mt * 4 + kc) * 64 + lane];
      acc2[mt] = __builtin_amdgcn_mfma_f32_16x16x32_bf16(af, bfv, acc2[mt], 0, 0, 0);
    }
  }
  unsigned short* orp = (unsigned short*)Or + (size_t)b * Cc * HWp;
  unsigned short* oip = (unsigned short*)Oi + (size_t)b * Cc * HWp;
  #pragma unroll
  for (int mt = 0; mt < 8; mt++)
    #pragma unroll
    for (int j = 0; j < 4; j++) {
      int o = mt * 16 + q * 4 + j;
      unsigned short hv = f2bu(acc2[mt][j] + b2[o]);
      if (o < 64) orp[(size_t)o * HWp + px] = hv;
      else        oip[(size_t)(o - 64) * HWp + px] = hv;
    }
}

extern "C" void kernel_launch(void* const* d_in, const int* in_sizes, int n_in,
                              void* d_out, int out_size, void* d_ws, size_t ws_size,
                              hipStream_t stream) {
  const float* inp   = (const float*)d_in[0];
  const float* n1w   = (const float*)d_in[1];
  const float* n1b   = (const float*)d_in[2];
  const float* n2w   = (const float*)d_in[3];
  const float* n2b   = (const float*)d_in[4];
  const float* scaw  = (const float*)d_in[5];
  const float* scab  = (const float*)d_in[6];
  const float* c11aw = (const float*)d_in[7];
  const float* c11ab = (const float*)d_in[8];
  const float* c11bw = (const float*)d_in[9];
  const float* c11bb = (const float*)d_in[10];
  const float* c1w   = (const float*)d_in[11];
  const float* c1b   = (const float*)d_in[12];
  const float* c21w  = (const float*)d_in[13];
  const float* c21b  = (const float*)d_in[14];
  const float* c2aw  = (const float*)d_in[15];
  const float* c2ab  = (const float*)d_in[16];
  const float* c2cw  = (const float*)d_in[17];
  const float* c2cb  = (const float*)d_in[18];
  const float* c211w = (const float*)d_in[19];
  const float* c211b = (const float*)d_in[20];
  const float* c3w   = (const float*)d_in[21];
  const float* c3b   = (const float*)d_in[22];
  const float* kbw   = (const float*)d_in[23];
  const float* kbb   = (const float*)d_in[24];
  const float* ga1   = (const float*)d_in[25];
  const float* attg  = (const float*)d_in[26];
  const float* beta  = (const float*)d_in[27];
  const float* gamma = (const float*)d_in[28];
  const float* fc1w  = (const float*)d_in[29];
  const float* fc1b  = (const float*)d_in[30];
  const float* fc2w  = (const float*)d_in[31];
  const float* fc2b  = (const float*)d_in[32];
  const float* fscaw = (const float*)d_in[33];
  const float* fscab = (const float*)d_in[34];

  const size_t S = (size_t)Bn * Cc * HWp;   // 3,276,800 elements per slot
  bf16* A  = (bf16*)d_ws;                   // 4 bf16 slots = 26.2 MB total
  bf16* Bs = A + S;
  bf16* Cs = A + 2 * S;
  bf16* Ds = A + 3 * S;
  float* smalls = (float*)(A + 4 * S);      // fp32 smalls
  float* xm   = smalls;
  float* scaV = smalls + 128;
  float* rmv  = smalls + 256;               // rmv[128]|imv[128]
  float* sra  = smalls + 512;               // sra[128]|sia[128]
  short* wS   = (short*)(smalls + 1024);    // bf16 frag tables
  short* wAf1 = wS;                         // 32768
  short* wAf2 = wAf1 + 32768;               // 16384
  short* cosF = wAf2 + 16384;               // 25600
  short* sinF = cosF + 25600;               // 25600
  short* wA_c11a = sinF + 25600;            // 4096
  short* wA_c1   = wA_c11a + 4096;          // 4096
  short* wA_c3   = wA_c1 + 4096;            // 4096
  short* wA_att  = wA_c3 + 4096;            // 3072
  short* kbwF    = wA_att + 3072;           // 81920 used
  bf16* attb = Bs + S / 2;    // [B,32,HW] (second half of Bs)
  float* yb  = (float*)d_out; // y lives in d_out (fp32)

  dim3 cgrid(10, 2, Bn * Cc);
  dim3 pgrid(400, 1, Bn);

  k_prep_all<<<dim3(672), dim3(256), 0, stream>>>(kbw, kbb, kbwF, fc1w, fc2w, wAf1, wAf2,
                                                  cosF, sinF, c11aw, c1w, c3w, c2cw, c211w,
                                                  attg, wA_c11a, wA_c1, wA_c3, wA_att);
  k_ln<<<dim3(800), dim3(256), 0, stream>>>(inp, n1w, n1b, A);          // A = x
  k_meanhw<<<dim3(128), dim3(256), 0, stream>>>(A, xm);
  k_small_mv<<<dim3(1), dim3(128), 0, stream>>>(xm, scaw, scab, scaV, 0);
  k_conv1x1_dual<<<pgrid, dim3(256), 0, stream>>>(A, wA_c11a, c11ab, wA_c1, c1b, Bs, Ds); // B=t1 D=t2
  k_c11b_direct<<<dim3(3, 10, Bn * 16), dim3(256), 0, stream>>>(Bs, c11bw, c11bb, Cs); // C = x1
  k_att_fused<<<pgrid, dim3(256), 0, stream>>>(A, c2aw, c2ab, wA_att, c2cb, c211b, attg, attb);
  k_c21dw4<<<dim3(25, 64, Bn), dim3(256), 0, stream>>>(Ds, c21w, c21b, A);         // A = uf
  k_kba_mfma<<<dim3(3, 160, Bn * 8), dim3(256), 0, stream>>>(A, attb, Cs, scaV, kbwF, ga1, Ds);
  k_c3y_ln2<<<pgrid, dim3(256), 0, stream>>>(Ds, wA_c3, c3b, beta, inp, yb, n2w, n2b, A); // y, A=X
  // forward FFT2 (MFMA)
  k_cpass_mfma<<<cgrid, dim3(64), 0, stream>>>(A, (const bf16*)nullptr, cosF, sinF, Bs, Cs, -1.f, SCL, nullptr, nullptr);
  k_cpass_mfma<<<cgrid, dim3(64), 0, stream>>>(Bs, Cs, cosF, sinF, Ds, A, -1.f, SCL, nullptr, nullptr);
  // fused fc1+gate+fc2 (in-place on Ds/A: each block owns its pixel columns)
  k_fc12_mfma<<<pgrid, dim3(256), 0, stream>>>(Ds, A, wAf1, fc1b, wAf2, fc2b, Ds, A); // D=r, A=i
  k_meanhw2<<<dim3(256), dim3(256), 0, stream>>>(Ds, A, rmv);                      // rmv|imv
  k_small_mv2<<<dim3(1), dim3(256), 0, stream>>>(rmv, fscaw, fscab, sra);          // sra|sia
  // inverse FFT2 (MFMA) with per-plane (1+ra)/(1+ia) scaling fused into first pass
  k_cpass_mfma<<<cgrid, dim3(64), 0, stream>>>(Ds, A, cosF, sinF, Bs, Cs, 1.f, SCL, sra, sra + 128);
  k_cpass_final_mfma<<<cgrid, dim3(64), 0, stream>>>(Bs, Cs, cosF, sinF, 1.f, SCL, gamma, yb);
}

// Round 18
// 403.954 us; speedup vs baseline: 1.1544x; 1.0530x over previous
//
#include <hip/hip_runtime.h>
#include <hip/hip_bf16.h>

typedef __hip_bfloat16 bf16;
typedef __attribute__((ext_vector_type(8))) short short8;
typedef __attribute__((ext_vector_type(4))) float f32x4;
typedef __attribute__((ext_vector_type(4))) unsigned short u16x4;

#define Hh 160
#define Wd 160
#define HWp (Hh*Wd)       // 25600
#define Bn 2
#define Cc 64
#define NPIX (Bn*HWp)     // 51200
#define SCL 0.07905694150420949f   // 1/sqrt(160)
#define TWO_PI_160 0.039269908169872414f  // 2*pi/160

static __device__ __forceinline__ float b2f(bf16 x) { return __bfloat162float(x); }
static __device__ __forceinline__ bf16 f2b(float f) { return __float2bfloat16(f); }
static __device__ __forceinline__ unsigned short f2bu(float f) {
  union { bf16 h; unsigned short u; } z; z.h = __float2bfloat16(f); return z.u;
}
static __device__ __forceinline__ float ubf(unsigned short u) {
  union { unsigned int i; float f; } z; z.i = ((unsigned int)u) << 16; return z.f;
}

// ---------------- LayerNorm single-pass + per-block channel partial sums (plain stores) --------
__global__ void k_ln(const float* __restrict__ in, const float* __restrict__ w,
                     const float* __restrict__ bb, bf16* __restrict__ out,
                     float* __restrict__ lnpart) {
  __shared__ float2 sm[4][64];
  int t = threadIdx.x;
  int pxl = t & 63, cq = t >> 6;
  int pix = blockIdx.x * 64 + pxl;          // 800 blocks cover NPIX
  int b = pix / HWp, p = pix - b * HWp;
  const float* src = in + ((size_t)b * Cc + cq * 16) * HWp + p;
  float v[16];
  float s = 0.f, s2 = 0.f;
  #pragma unroll
  for (int i = 0; i < 16; i++) {
    v[i] = src[(size_t)i * HWp];
    s += v[i]; s2 += v[i] * v[i];
  }
  sm[cq][pxl] = make_float2(s, s2);
  __syncthreads();
  float S = 0.f, S2 = 0.f;
  #pragma unroll
  for (int k = 0; k < 4; k++) { float2 z = sm[k][pxl]; S += z.x; S2 += z.y; }
  float mu = S * (1.f / 64.f);
  float var = S2 * (1.f / 64.f) - mu * mu;
  float rs = rsqrtf(fmaxf(var, 0.f) + 1e-6f);
  bf16* dst = out + ((size_t)b * Cc + cq * 16) * HWp + p;
  #pragma unroll
  for (int i = 0; i < 16; i++) {
    int c = cq * 16 + i;
    float val = (v[i] - mu) * rs * w[c] + bb[c];
    dst[(size_t)i * HWp] = f2b(val);
    float r = val;                                  // per-block channel sum (64 px)
    r += __shfl_xor(r, 1);  r += __shfl_xor(r, 2);  r += __shfl_xor(r, 4);
    r += __shfl_xor(r, 8);  r += __shfl_xor(r, 16); r += __shfl_xor(r, 32);
    if (pxl == 0) lnpart[blockIdx.x * 64 + c] = r;  // plain store, no atomics
  }
}

// ---------------- reduce lnpart (800x64) + matvec -> scaV ----------------
__global__ void k_small_mv_r(const float* __restrict__ lnpart, const float* __restrict__ w,
                             const float* __restrict__ bias, float* __restrict__ scaV) {
  __shared__ float part[2][128];
  __shared__ float xmL[2][64];
  int t = threadIdx.x;              // 256
  int pair = t & 127, split = t >> 7;
  int b = pair >> 6, o = pair & 63;
  float s = 0.f;
  const float* base = lnpart + (size_t)(b * 400 + split * 200) * 64 + o;
  for (int i = 0; i < 200; i++) s += base[i * 64];
  part[split][pair] = s;
  __syncthreads();
  if (split == 0) xmL[b][o] = (part[0][pair] + part[1][pair]) * (1.f / HWp);
  __syncthreads();
  if (t < 128) {
    float acc = bias[o];
    for (int k = 0; k < 64; k++) acc += w[o * 64 + k] * xmL[b][k];
    scaV[t] = acc;
  }
}

// ---------------- reduce fcpart (800x128) + matvec -> sra|sia ----------------
__global__ void k_small_mv2_r(const float* __restrict__ fcpart, const float* __restrict__ w,
                              const float* __restrict__ bias, float* __restrict__ out) {
  __shared__ float xvL[2][2][64];   // [half][b][c]
  int t = threadIdx.x;              // 256
  int half = t >> 7, r = t & 127;
  int b = r >> 6, o = r & 63;
  int ch = half * 64 + o;           // r-plane channels 0..63, i-plane 64..127
  float s = 0.f;
  const float* base = fcpart + (size_t)(b * 400) * 128 + ch;
  for (int i = 0; i < 400; i++) s += base[i * 128];
  xvL[half][b][o] = s * (1.f / HWp);
  __syncthreads();
  float acc = bias[o];
  for (int k = 0; k < 64; k++) acc += w[o * 64 + k] * xvL[half][b][k];
  out[half * 128 + b * 64 + o] = 1.f + acc;
}

// ---------------- depthwise 3x3 vectorized, 4 px/thread ----------------
__global__ void k_c21dw4(const bf16* __restrict__ in, const float* __restrict__ w,
                         const float* __restrict__ bias, bf16* __restrict__ out) {
  int t = threadIdx.x;
  int c = blockIdx.y, b = blockIdx.z;
  int pq = blockIdx.x * 256 + t;            // grid.x = 25
  int h = pq / 40, x4 = (pq - h * 40) * 4;
  const unsigned short* src = (const unsigned short*)in + ((size_t)b * Cc + c) * HWp;
  float wv[9];
  #pragma unroll
  for (int i = 0; i < 9; i++) wv[i] = w[c * 9 + i];
  float bs = bias[c];
  float acc[4] = {bs, bs, bs, bs};
  #pragma unroll
  for (int ki = 0; ki < 3; ki++) {
    int hh = h + ki - 1;
    if ((unsigned)hh >= Hh) continue;
    const unsigned short* row = src + hh * Wd + x4;
    float v[6];
    u16x4 m = *(const u16x4*)row;
    v[1] = ubf(m[0]); v[2] = ubf(m[1]); v[3] = ubf(m[2]); v[4] = ubf(m[3]);
    v[0] = (x4 > 0) ? ubf(row[-1]) : 0.f;
    v[5] = (x4 + 4 < Wd) ? ubf(row[4]) : 0.f;
    #pragma unroll
    for (int j = 0; j < 4; j++)
      #pragma unroll
      for (int kj = 0; kj < 3; kj++)
        acc[j] = fmaf(wv[ki * 3 + kj], v[j + kj], acc[j]);
  }
  u16x4 pk;
  #pragma unroll
  for (int j = 0; j < 4; j++) pk[j] = f2bu(acc[j]);
  *(u16x4*)((unsigned short*)out + ((size_t)b * Cc + c) * HWp + h * Wd + x4) = pk;
}

// ---------------- fused weight prep ----------------
__global__ void k_prep_all(const float* __restrict__ kbw, const float* __restrict__ kbb,
                           short* __restrict__ kbwF,
                           const float* __restrict__ fc1w, const float* __restrict__ fc2w,
                           short* __restrict__ wAf1, short* __restrict__ wAf2,
                           short* __restrict__ cosF, short* __restrict__ sinF,
                           const float* __restrict__ c11aw, const float* __restrict__ c1w,
                           const float* __restrict__ c3w, const float* __restrict__ c2cw,
                           const float* __restrict__ c211w, const float* __restrict__ attg,
                           short* __restrict__ wA_c11a, short* __restrict__ wA_c1,
                           short* __restrict__ wA_c3, short* __restrict__ wA_att) {
  int i = blockIdx.x * 256 + threadIdx.x;   // 172032 total (672 blocks)
  if (i < 81920) {
    int g = i / 5120, r = i - g * 5120;
    float v = 0.f;
    if (r < 4096) {
      int j = r & 7, lane = (r >> 3) & 63, mt = r >> 9;
      int m = mt * 16 + (lane & 15);
      int s = m >> 2, o = m & 3;
      int k = (lane >> 4) * 8 + j;
      v = kbw[s * 2304 + g * 144 + o * 36 + k];
    } else {
      int r2 = r - 4096;
      int j = r2 & 7, n = (r2 >> 3) & 15, mt = r2 >> 7;
      int m = mt * 16 + n;
      int s = m >> 2, o = m & 3;
      int k = 32 + j;
      if (k < 36) v = kbw[s * 2304 + g * 144 + o * 36 + k];
      else if (k == 36) v = kbb[s * 64 + g * 4 + o];
    }
    kbwF[i] = (short)f2bu(v);
  } else if (i < 131072) {
    int i1 = i - 81920;
    if (i1 < 32768) {
      int j = i1 & 7, lane = (i1 >> 3) & 63, fk = i1 >> 9;
      int kc = fk & 3, mt = fk >> 2;
      int o = mt * 16 + (lane & 15);
      int k = kc * 32 + (lane >> 4) * 8 + j;
      wAf1[i1] = (short)f2bu(fc1w[o * 128 + k]);
    } else {
      int i2 = i1 - 32768;
      int j = i2 & 7, lane = (i2 >> 3) & 63, fk = i2 >> 9;
      int kc = fk & 3, mt = fk >> 2;
      int o = mt * 16 + (lane & 15);
      int k = kc * 32 + (lane >> 4) * 8 + j;
      wAf2[i2] = (short)f2bu(fc2w[o * 128 + k]);
    }
  } else if (i < 156672) {
    int i2 = i - 131072;
    int j = i2 & 7, lane = (i2 >> 3) & 63, fk = i2 >> 9;   // fk = ct*5+kc
    int kc = fk % 5, ct = fk / 5;
    int c = ct * 16 + (lane & 15);
    int bb2 = kc * 32 + (lane >> 4) * 8 + j;
    int m = (bb2 * c) % 160;
    float sv, cv;
    __sincosf((float)m * TWO_PI_160, &sv, &cv);
    cosF[i2] = (short)f2bu(cv);
    sinF[i2] = (short)f2bu(sv);
  } else {
    int i3 = i - 156672;
    if (i3 < 12288) {
      int wi = i3 / 4096, r = i3 - wi * 4096;
      int j = r & 7, lane = (r >> 3) & 63, fk = r >> 9;
      int kc = fk & 1, mt = fk >> 1;
      int o = mt * 16 + (lane & 15);
      int k = kc * 32 + (lane >> 4) * 8 + j;
      const float* w = (wi == 0) ? c11aw : (wi == 1) ? c1w : c3w;
      short* dst = (wi == 0) ? wA_c11a : (wi == 1) ? wA_c1 : wA_c3;
      dst[r] = (short)f2bu(w[o * 64 + k]);
    } else {
      int r = i3 - 12288;
      int j = r & 7, lane = (r >> 3) & 63, fk = r >> 9;
      int kc = fk % 3, mt = fk / 3;
      int s = mt * 16 + (lane & 15);
      int k = kc * 32 + (lane >> 4) * 8 + j;
      float v;
      if (k < 16) v = c2cw[s * 16 + k] * attg[s];
      else if (k < 32) v = 0.f;
      else v = c211w[s * 64 + (k - 32)];
      wA_att[r] = (short)f2bu(v);
    }
  }
}

// ---------------- dual 1x1 conv 64->64 via MFMA ----------------
__global__ __launch_bounds__(256) void k_conv1x1_dual(
    const bf16* __restrict__ in, const short* __restrict__ wA1,
    const float* __restrict__ b1, const short* __restrict__ wA2,
    const float* __restrict__ b2, bf16* __restrict__ out1, bf16* __restrict__ out2) {
  int b = blockIdx.z;
  int lane = threadIdx.x & 63, w = threadIdx.x >> 6;
  int px = blockIdx.x * 64 + w * 16 + (lane & 15);
  int q = lane >> 4;
  const unsigned short* src = (const unsigned short*)in + (size_t)b * Cc * HWp;
  const short8* wf1 = (const short8*)wA1;
  const short8* wf2 = (const short8*)wA2;
  f32x4 acc1[4], acc2[4];
  #pragma unroll
  for (int mt = 0; mt < 4; mt++) {
    acc1[mt] = (f32x4){0.f, 0.f, 0.f, 0.f};
    acc2[mt] = (f32x4){0.f, 0.f, 0.f, 0.f};
  }
  #pragma unroll
  for (int kc = 0; kc < 2; kc++) {
    short8 bfv;
    #pragma unroll
    for (int j = 0; j < 8; j++) bfv[j] = (short)src[(size_t)(kc * 32 + q * 8 + j) * HWp + px];
    #pragma unroll
    for (int mt = 0; mt < 4; mt++) {
      short8 a1 = wf1[(mt * 2 + kc) * 64 + lane];
      acc1[mt] = __builtin_amdgcn_mfma_f32_16x16x32_bf16(a1, bfv, acc1[mt], 0, 0, 0);
      short8 a2 = wf2[(mt * 2 + kc) * 64 + lane];
      acc2[mt] = __builtin_amdgcn_mfma_f32_16x16x32_bf16(a2, bfv, acc2[mt], 0, 0, 0);
    }
  }
  unsigned short* d1 = (unsigned short*)out1 + (size_t)b * Cc * HWp;
  unsigned short* d2 = (unsigned short*)out2 + (size_t)b * Cc * HWp;
  #pragma unroll
  for (int mt = 0; mt < 4; mt++)
    #pragma unroll
    for (int j = 0; j < 4; j++) {
      int o = mt * 16 + q * 4 + j;
      d1[(size_t)o * HWp + px] = f2bu(acc1[mt][j] + b1[o]);
      d2[(size_t)o * HWp + px] = f2bu(acc2[mt][j] + b2[o]);
    }
}

// ---------------- c3 1x1 conv + residual + FUSED LayerNorm2 ----------------
__global__ __launch_bounds__(256) void k_c3y_ln2(
    const bf16* __restrict__ in, const short* __restrict__ wA,
    const float* __restrict__ bias, const float* __restrict__ beta,
    const float* __restrict__ inp, float* __restrict__ y,
    const float* __restrict__ n2w, const float* __restrict__ n2b,
    bf16* __restrict__ Xout) {
  int b = blockIdx.z;
  int lane = threadIdx.x & 63, w = threadIdx.x >> 6;
  int px = blockIdx.x * 64 + w * 16 + (lane & 15);
  int q = lane >> 4;
  const unsigned short* src = (const unsigned short*)in + (size_t)b * Cc * HWp;
  const short8* wf = (const short8*)wA;
  f32x4 acc[4];
  #pragma unroll
  for (int mt = 0; mt < 4; mt++) acc[mt] = (f32x4){0.f, 0.f, 0.f, 0.f};
  #pragma unroll
  for (int kc = 0; kc < 2; kc++) {
    short8 bfv;
    #pragma unroll
    for (int j = 0; j < 8; j++) bfv[j] = (short)src[(size_t)(kc * 32 + q * 8 + j) * HWp + px];
    #pragma unroll
    for (int mt = 0; mt < 4; mt++) {
      short8 af = wf[(mt * 2 + kc) * 64 + lane];
      acc[mt] = __builtin_amdgcn_mfma_f32_16x16x32_bf16(af, bfv, acc[mt], 0, 0, 0);
    }
  }
  float yv[4][4];
  float s = 0.f, s2 = 0.f;
  #pragma unroll
  for (int mt = 0; mt < 4; mt++)
    #pragma unroll
    for (int j = 0; j < 4; j++) {
      int o = mt * 16 + q * 4 + j;
      size_t oi = ((size_t)b * Cc + o) * HWp + px;
      float v = inp[oi] + (acc[mt][j] + bias[o]) * beta[o];
      y[oi] = v;
      yv[mt][j] = v;
      s += v; s2 += v * v;
    }
  s  += __shfl_xor(s, 16);  s  += __shfl_xor(s, 32);
  s2 += __shfl_xor(s2, 16); s2 += __shfl_xor(s2, 32);
  float mu = s * (1.f / 64.f);
  float var = s2 * (1.f / 64.f) - mu * mu;
  float rs = rsqrtf(fmaxf(var, 0.f) + 1e-6f);
  unsigned short* Xu = (unsigned short*)Xout + (size_t)b * Cc * HWp;
  #pragma unroll
  for (int mt = 0; mt < 4; mt++)
    #pragma unroll
    for (int j = 0; j < 4; j++) {
      int o = mt * 16 + q * 4 + j;
      Xu[(size_t)o * HWp + px] = f2bu((yv[mt][j] - mu) * rs * n2w[o] + n2b[o]);
    }
}

// ---------------- FUSED c2a + att: gate conv in LDS, then att MFMA ----------------
__global__ __launch_bounds__(256) void k_att_fused(
    const bf16* __restrict__ x, const float* __restrict__ c2aw, const float* __restrict__ c2ab,
    const short* __restrict__ wA, const float* __restrict__ c2cb,
    const float* __restrict__ c211b, const float* __restrict__ attg,
    bf16* __restrict__ att) {
  __shared__ unsigned short gateL[32][66];   // 4224 B
  int b = blockIdx.z;
  int t = threadIdx.x;
  int p0 = blockIdx.x * 64;
  const unsigned short* xs = (const unsigned short*)x + (size_t)b * Cc * HWp;
  for (int task = t; task < 512; task += 256) {
    int o = task >> 4, q4 = task & 15;
    int px4 = p0 + q4 * 4;
    int h = px4 / Wd, x4 = px4 - h * Wd;
    float bs = c2ab[o];
    float acc[4] = {bs, bs, bs, bs};
    #pragma unroll
    for (int ci = 0; ci < 2; ci++) {
      const unsigned short* src = xs + (size_t)(o * 2 + ci) * HWp;
      float wv[9];
      #pragma unroll
      for (int i = 0; i < 9; i++) wv[i] = c2aw[(o * 2 + ci) * 9 + i];
      #pragma unroll
      for (int ki = 0; ki < 3; ki++) {
        int hh = h + ki - 1;
        if ((unsigned)hh >= Hh) continue;
        const unsigned short* row = src + hh * Wd + x4;
        float v[6];
        u16x4 m = *(const u16x4*)row;
        v[1] = ubf(m[0]); v[2] = ubf(m[1]); v[3] = ubf(m[2]); v[4] = ubf(m[3]);
        v[0] = (x4 > 0) ? ubf(row[-1]) : 0.f;
        v[5] = (x4 + 4 < Wd) ? ubf(row[4]) : 0.f;
        #pragma unroll
        for (int j = 0; j < 4; j++)
          #pragma unroll
          for (int kj = 0; kj < 3; kj++)
            acc[j] = fmaf(wv[ki * 3 + kj], v[j + kj], acc[j]);
      }
    }
    #pragma unroll
    for (int j = 0; j < 4; j++) gateL[o][q4 * 4 + j] = f2bu(acc[j]);
  }
  __syncthreads();
  int lane = t & 63, w = t >> 6;
  int pxl = w * 16 + (lane & 15);
  int px = p0 + pxl;
  int q = lane >> 4;
  const short8* wf = (const short8*)wA;
  f32x4 acc[2];
  acc[0] = (f32x4){0.f, 0.f, 0.f, 0.f};
  acc[1] = (f32x4){0.f, 0.f, 0.f, 0.f};
  {
    short8 bfv;
    #pragma unroll
    for (int j = 0; j < 8; j++) {
      int k = q * 8 + j;
      short v = 0;
      if (q < 2) {
        float gv = ubf(gateL[k][pxl]) * ubf(gateL[16 + k][pxl]);
        v = (short)f2bu(gv);
      }
      bfv[j] = v;
    }
    #pragma unroll
    for (int mt = 0; mt < 2; mt++) {
      short8 af = wf[(mt * 3 + 0) * 64 + lane];
      acc[mt] = __builtin_amdgcn_mfma_f32_16x16x32_bf16(af, bfv, acc[mt], 0, 0, 0);
    }
  }
  #pragma unroll
  for (int kc = 1; kc < 3; kc++) {
    short8 bfv;
    #pragma unroll
    for (int j = 0; j < 8; j++)
      bfv[j] = (short)xs[(size_t)((kc - 1) * 32 + q * 8 + j) * HWp + px];
    #pragma unroll
    for (int mt = 0; mt < 2; mt++) {
      short8 af = wf[(mt * 3 + kc) * 64 + lane];
      acc[mt] = __builtin_amdgcn_mfma_f32_16x16x32_bf16(af, bfv, acc[mt], 0, 0, 0);
    }
  }
  unsigned short* dst = (unsigned short*)att + (size_t)b * 32 * HWp;
  #pragma unroll
  for (int mt = 0; mt < 2; mt++)
    #pragma unroll
    for (int j = 0; j < 4; j++) {
      int s = mt * 16 + q * 4 + j;
      dst[(size_t)s * HWp + px] = f2bu(acc[mt][j] + c2cb[s] * attg[s] + c211b[s]);
    }
}

// ---------------- c11b direct: grouped 5x5 conv, 16-row tiles ----------------
__global__ __launch_bounds__(256) void k_c11b_direct(
    const bf16* __restrict__ t1, const float* __restrict__ w,
    const float* __restrict__ bias, bf16* __restrict__ out) {
  __shared__ float xs[4 * 20 * 68];        // 21760 B
  __shared__ float wsm[4 * 5 * 4 * 5];
  __shared__ float bsm[4];
  int bz = blockIdx.z;                     // b*16 + g
  int b = bz >> 4, g = bz & 15;
  int h0 = blockIdx.y * 16;
  int w0 = blockIdx.x * 64;
  int t = threadIdx.x;
  for (int i = t; i < 400; i += 256) {
    int kj = i % 5, rem = i / 5;
    int o = rem & 3; rem >>= 2;
    int ki = rem % 5, ci = rem / 5;
    wsm[i] = w[((g * 4 + o) * 4 + ci) * 25 + ki * 5 + kj];
  }
  if (t < 4) bsm[t] = bias[g * 4 + t];
  const unsigned short* src = (const unsigned short*)t1 + ((size_t)b * Cc + g * 4) * HWp;
  for (int i = t; i < 4 * 20 * 68; i += 256) {
    int ci = i / 1360, rem2 = i - ci * 1360;
    int r = rem2 / 68, col = rem2 - r * 68;
    int hh = h0 + r - 2, ww = w0 + col - 2;
    float v = 0.f;
    if ((unsigned)hh < Hh && (unsigned)ww < Wd)
      v = ubf(src[(size_t)ci * HWp + hh * Wd + ww]);
    xs[i] = v;
  }
  __syncthreads();
  int wq = t & 15, hq = t >> 4;
  float acc[4][4];
  #pragma unroll
  for (int o = 0; o < 4; o++)
    #pragma unroll
    for (int j = 0; j < 4; j++) acc[o][j] = bsm[o];
  #pragma unroll
  for (int ci = 0; ci < 4; ci++) {
    #pragma unroll
    for (int ki = 0; ki < 5; ki++) {
      const float* wrow = &wsm[(ci * 5 + ki) * 20];
      float wv[20];
      #pragma unroll
      for (int x = 0; x < 20; x++) wv[x] = wrow[x];
      const float* xrow = &xs[ci * 1360 + (hq + ki) * 68 + wq * 4];
      float xv[8];
      #pragma unroll
      for (int x = 0; x < 8; x++) xv[x] = xrow[x];
      #pragma unroll
      for (int o = 0; o < 4; o++)
        #pragma unroll
        for (int j = 0; j < 4; j++)
          #pragma unroll
          for (int kj = 0; kj < 5; kj++)
            acc[o][j] = fmaf(wv[o * 5 + kj], xv[j + kj], acc[o][j]);
    }
  }
  int width = Wd - w0;
  if (wq * 4 < width) {
    unsigned short* dst = (unsigned short*)out + ((size_t)b * Cc + g * 4) * HWp
                        + (h0 + hq) * Wd + w0 + wq * 4;
    #pragma unroll
    for (int o = 0; o < 4; o++) {
      u16x4 pk;
      #pragma unroll
      for (int j = 0; j < 4; j++) pk[j] = f2bu(acc[o][j]);
      *(u16x4*)(dst + (size_t)o * HWp) = pk;
    }
  }
}

// ---------------- KBA via MFMA: packed A-frags LDS-staged (20 KB), 2 groups/block ----------------
__global__ __launch_bounds__(256) void k_kba_mfma(
    const bf16* __restrict__ uf, const bf16* __restrict__ att,
    const bf16* __restrict__ x1, const float* __restrict__ scaV,
    const short* __restrict__ kbwF, const float* __restrict__ ga1,
    bf16* __restrict__ out) {
  __shared__ short8 fragL[1280];                   // 20480 B (2 groups x 640)
  __shared__ unsigned short patchL[8 * 3 * 66];    // 3168 B
  __shared__ unsigned short attL[64][33];          // 4224 B
  int bz = blockIdx.z;
  int b = bz >> 3, gp = bz & 7;
  int h = blockIdx.y;
  int w0 = blockIdx.x * 64;
  int width = min(64, Wd - w0);
  int t = threadIdx.x;
  int c0 = gp * 8;
  const short8* src8 = (const short8*)kbwF + (size_t)gp * 1280;
  #pragma unroll
  for (int i = 0; i < 5; i++) fragL[t + i * 256] = src8[t + i * 256];
  const unsigned short* uf_u = (const unsigned short*)uf;
  for (int i = t; i < 8 * 3 * 66; i += 256) {
    int cl = i / 198, rem = i - cl * 198;
    int r = rem / 66, col = rem - r * 66;
    int hh = h + r - 1, ww = w0 + col - 1;
    unsigned short v = 0;
    if ((unsigned)hh < Hh && (unsigned)ww < Wd)
      v = uf_u[((size_t)b * Cc + c0 + cl) * HWp + hh * Wd + ww];
    patchL[i] = v;
  }
  const unsigned short* att_u = (const unsigned short*)att + (size_t)b * 32 * HWp;
  for (int i = t; i < 64 * 32; i += 256) {
    int px = i & 63, s = i >> 6;
    unsigned short v = 0;
    if (px < width) v = att_u[(size_t)s * HWp + h * Wd + w0 + px];
    attL[px][s] = v;
  }
  __syncthreads();
  int lane = t & 63, w = t >> 6;
  int n = lane & 15, q = lane >> 4;
  int pxl = w * 16 + n;
  float attR[8];
  #pragma unroll
  for (int mt = 0; mt < 8; mt++) attR[mt] = ubf(attL[pxl][4 * mt + q]);
  int offA[8];
  #pragma unroll
  for (int j = 0; j < 8; j++) {
    int k = q * 8 + j;
    int ci = k / 9, r = k - ci * 9, ki = r / 3, kj = r - ki * 3;
    offA[j] = ci * 198 + ki * 66 + pxl + kj;
  }
  int offB[4];
  #pragma unroll
  for (int j = 0; j < 4; j++) {
    int k = 32 + j, r = k - 27, ki = r / 3, kj = r - ki * 3;
    offB[j] = 3 * 198 + ki * 66 + pxl + kj;
  }
  const unsigned short* x1u = (const unsigned short*)x1 + (size_t)b * Cc * HWp + h * Wd + w0;
  unsigned short* outu = (unsigned short*)out + (size_t)b * Cc * HWp + h * Wd + w0;
  #pragma unroll
  for (int gl = 0; gl < 2; gl++) {
    int g = gp * 2 + gl;
    const short8* fgl = fragL + gl * 640;
    short8 b0, b1;
    #pragma unroll
    for (int j = 0; j < 8; j++) b0[j] = (short)patchL[gl * 792 + offA[j]];
    #pragma unroll
    for (int j = 0; j < 8; j++) b1[j] = 0;
    if (q == 0) {
      #pragma unroll
      for (int j = 0; j < 4; j++) b1[j] = (short)patchL[gl * 792 + offB[j]];
      b1[4] = (short)0x3F80;                 // B[36][*] = 1.0 (bias row)
    }
    f32x4 acc[8];
    #pragma unroll
    for (int mt = 0; mt < 8; mt++) acc[mt] = (f32x4){0.f, 0.f, 0.f, 0.f};
    #pragma unroll
    for (int mt = 0; mt < 8; mt++) {
      short8 a0 = fgl[mt * 64 + lane];
      acc[mt] = __builtin_amdgcn_mfma_f32_16x16x32_bf16(a0, b0, acc[mt], 0, 0, 0);
      short8 a1 = (short8){0,0,0,0,0,0,0,0};
      if (q == 0) a1 = fgl[512 + mt * 16 + n];
      acc[mt] = __builtin_amdgcn_mfma_f32_16x16x32_bf16(a1, b1, acc[mt], 0, 0, 0);
    }
    #pragma unroll
    for (int o = 0; o < 4; o++) {
      float P = 0.f;
      #pragma unroll
      for (int mt = 0; mt < 8; mt++) P += attR[mt] * acc[mt][o];
      P += __shfl_xor(P, 16);
      P += __shfl_xor(P, 32);
      if (o == q && pxl < width) {
        int c = g * 4 + q;
        float ufc = ubf(patchL[(gl * 4 + q) * 198 + 66 + pxl + 1]);   // center tap
        float xk = P * ga1[c] + ufc;
        float xv = xk * ubf(x1u[(size_t)c * HWp + pxl]) * scaV[b * 64 + c];
        outu[(size_t)c * HWp + pxl] = f2bu(xv);
      }
    }
  }
}

// ---------------- DFT pass via MFMA (5-ct loop, fragment reuse) ----------------
__global__ __launch_bounds__(64) void k_cpass_mfma(
    const bf16* __restrict__ inr, const bf16* __restrict__ ini,
    const short* __restrict__ cosF, const short* __restrict__ sinF,
    bf16* __restrict__ outr, bf16* __restrict__ outi,
    float sgn, float scale,
    const float* __restrict__ sclr, const float* __restrict__ scli) {
  int plane = blockIdx.z;
  int a0 = blockIdx.x * 16;
  int cth = blockIdx.y * 5;          // c-half: ct 0..4 or 5..9
  int lane = threadIdx.x;
  int n = lane & 15, q = lane >> 4;
  const unsigned short* pr = (const unsigned short*)inr + (size_t)plane * HWp;
  const unsigned short* pi = ini ? (const unsigned short*)ini + (size_t)plane * HWp : nullptr;
  float srm = sclr ? sclr[plane] : 1.f;
  float sim = scli ? scli[plane] : 1.f;
  short8 br[5], bi[5];
  #pragma unroll
  for (int kc = 0; kc < 5; kc++) {
    br[kc] = *(const short8*)(pr + (a0 + n) * 160 + kc * 32 + q * 8);
    if (pi) bi[kc] = *(const short8*)(pi + (a0 + n) * 160 + kc * 32 + q * 8);
  }
  const short8* cf = (const short8*)cosF;
  const short8* sf = (const short8*)sinF;
  unsigned short* qr = (unsigned short*)outr + (size_t)plane * HWp;
  unsigned short* qi = (unsigned short*)outi + (size_t)plane * HWp;
  for (int ctl = 0; ctl < 5; ctl++) {
    int ct = cth + ctl;
    f32x4 arr = (f32x4){0.f,0.f,0.f,0.f}, asr = (f32x4){0.f,0.f,0.f,0.f};
    f32x4 ari = (f32x4){0.f,0.f,0.f,0.f}, asi = (f32x4){0.f,0.f,0.f,0.f};
    #pragma unroll
    for (int kc = 0; kc < 5; kc++) {
      short8 ca = cf[(ct * 5 + kc) * 64 + lane];
      short8 sa = sf[(ct * 5 + kc) * 64 + lane];
      arr = __builtin_amdgcn_mfma_f32_16x16x32_bf16(ca, br[kc], arr, 0, 0, 0);
      asr = __builtin_amdgcn_mfma_f32_16x16x32_bf16(sa, br[kc], asr, 0, 0, 0);
      if (pi) {
        ari = __builtin_amdgcn_mfma_f32_16x16x32_bf16(ca, bi[kc], ari, 0, 0, 0);
        asi = __builtin_amdgcn_mfma_f32_16x16x32_bf16(sa, bi[kc], asi, 0, 0, 0);
      }
    }
    #pragma unroll
    for (int j = 0; j < 4; j++) {
      int c = ct * 16 + q * 4 + j;
      float xc = srm * arr[j], xs = srm * asr[j];
      float ic = pi ? sim * ari[j] : 0.f, is = pi ? sim * asi[j] : 0.f;
      float orv = (xc - sgn * is) * scale;
      float oiv = (sgn * xs + ic) * scale;
      qr[c * 160 + a0 + n] = f2bu(orv);
      qi[c * 160 + a0 + n] = f2bu(oiv);
    }
  }
}

// ---------------- final inverse DFT pass, fused |.|, *gamma, += y ----------------
__global__ __launch_bounds__(64) void k_cpass_final_mfma(
    const bf16* __restrict__ inr, const bf16* __restrict__ ini,
    const short* __restrict__ cosF, const short* __restrict__ sinF,
    float sgn, float scale,
    const float* __restrict__ gamma, float* __restrict__ dout) {
  int plane = blockIdx.z;
  int a0 = blockIdx.x * 16;
  int cth = blockIdx.y * 5;
  int lane = threadIdx.x;
  int n = lane & 15, q = lane >> 4;
  const unsigned short* pr = (const unsigned short*)inr + (size_t)plane * HWp;
  const unsigned short* pi = (const unsigned short*)ini + (size_t)plane * HWp;
  short8 br[5], bi[5];
  #pragma unroll
  for (int kc = 0; kc < 5; kc++) {
    br[kc] = *(const short8*)(pr + (a0 + n) * 160 + kc * 32 + q * 8);
    bi[kc] = *(const short8*)(pi + (a0 + n) * 160 + kc * 32 + q * 8);
  }
  const short8* cf = (const short8*)cosF;
  const short8* sf = (const short8*)sinF;
  float gm = gamma[plane & 63];
  float* dp = dout + (size_t)plane * HWp;
  for (int ctl = 0; ctl < 5; ctl++) {
    int ct = cth + ctl;
    f32x4 arr = (f32x4){0.f,0.f,0.f,0.f}, asr = (f32x4){0.f,0.f,0.f,0.f};
    f32x4 ari = (f32x4){0.f,0.f,0.f,0.f}, asi = (f32x4){0.f,0.f,0.f,0.f};
    #pragma unroll
    for (int kc = 0; kc < 5; kc++) {
      short8 ca = cf[(ct * 5 + kc) * 64 + lane];
      short8 sa = sf[(ct * 5 + kc) * 64 + lane];
      arr = __builtin_amdgcn_mfma_f32_16x16x32_bf16(ca, br[kc], arr, 0, 0, 0);
      asr = __builtin_amdgcn_mfma_f32_16x16x32_bf16(sa, br[kc], asr, 0, 0, 0);
      ari = __builtin_amdgcn_mfma_f32_16x16x32_bf16(ca, bi[kc], ari, 0, 0, 0);
      asi = __builtin_amdgcn_mfma_f32_16x16x32_bf16(sa, bi[kc], asi, 0, 0, 0);
    }
    #pragma unroll
    for (int j = 0; j < 4; j++) {
      int c = ct * 16 + q * 4 + j;
      float orv = (arr[j] - sgn * asi[j]) * scale;
      float oiv = (sgn * asr[j] + ari[j]) * scale;
      float z = sqrtf(orv * orv + oiv * oiv);
      dp[c * 160 + a0 + n] += z * gm;   // dout currently holds y
    }
  }
}

// ---------------- FUSED fc1+gate+fc2 (+ per-block plane-mean partials) ----------------
__global__ __launch_bounds__(256) void k_fc12_mfma(
    const bf16* __restrict__ Fr, const bf16* __restrict__ Fi,
    const short* __restrict__ wA1, const float* __restrict__ b1,
    const short* __restrict__ wA2, const float* __restrict__ b2,
    bf16* __restrict__ Or, bf16* __restrict__ Oi, float* __restrict__ fcpart) {
  __shared__ unsigned short gl[128][66];   // 16896 B
  __shared__ float psum[4][128];           // 2048 B
  int b = blockIdx.z;
  int lane = threadIdx.x & 63, w = threadIdx.x >> 6;
  int n = lane & 15, q = lane >> 4;
  int pxl = w * 16 + n;
  int px = blockIdx.x * 64 + pxl;
  const unsigned short* fr = (const unsigned short*)Fr + (size_t)b * Cc * HWp;
  const unsigned short* fi = (const unsigned short*)Fi + (size_t)b * Cc * HWp;
  const short8* wf1 = (const short8*)wA1;
  f32x4 acc[16];
  #pragma unroll
  for (int mt = 0; mt < 16; mt++) acc[mt] = (f32x4){0.f, 0.f, 0.f, 0.f};
  #pragma unroll
  for (int kc = 0; kc < 4; kc++) {
    const unsigned short* basep = (kc < 2) ? (fr + (size_t)(kc * 32) * HWp)
                                           : (fi + (size_t)((kc - 2) * 32) * HWp);
    short8 bfv;
    #pragma unroll
    for (int j = 0; j < 8; j++) bfv[j] = (short)basep[(size_t)(q * 8 + j) * HWp + px];
    #pragma unroll
    for (int mt = 0; mt < 16; mt++) {
      short8 af = wf1[(mt * 4 + kc) * 64 + lane];
      acc[mt] = __builtin_amdgcn_mfma_f32_16x16x32_bf16(af, bfv, acc[mt], 0, 0, 0);
    }
  }
  #pragma unroll
  for (int mt = 0; mt < 8; mt++)
    #pragma unroll
    for (int j = 0; j < 4; j++) {
      int o = mt * 16 + q * 4 + j;
      float v1 = acc[mt][j] + b1[o];
      float v2 = acc[mt + 8][j] + b1[o + 128];
      gl[o][pxl] = f2bu(v1 * v2);
    }
  __syncthreads();
  const short8* wf2 = (const short8*)wA2;
  f32x4 acc2[8];
  #pragma unroll
  for (int mt = 0; mt < 8; mt++) acc2[mt] = (f32x4){0.f, 0.f, 0.f, 0.f};
  #pragma unroll
  for (int kc = 0; kc < 4; kc++) {
    short8 bfv;
    #pragma unroll
    for (int j = 0; j < 8; j++) bfv[j] = (short)gl[kc * 32 + q * 8 + j][pxl];
    #pragma unroll
    for (int mt = 0; mt < 8; mt++) {
      short8 af = wf2[(mt * 4 + kc) * 64 + lane];
      acc2[mt] = __builtin_amdgcn_mfma_f32_16x16x32_bf16(af, bfv, acc2[mt], 0, 0, 0);
    }
  }
  unsigned short* orp = (unsigned short*)Or + (size_t)b * Cc * HWp;
  unsigned short* oip = (unsigned short*)Oi + (size_t)b * Cc * HWp;
  #pragma unroll
  for (int mt = 0; mt < 8; mt++)
    #pragma unroll
    for (int j = 0; j < 4; j++) {
      int o = mt * 16 + q * 4 + j;
      float v = acc2[mt][j] + b2[o];
      unsigned short hv = f2bu(v);
      if (o < 64) orp[(size_t)o * HWp + px] = hv;
      else        oip[(size_t)(o - 64) * HWp + px] = hv;
      // per-wave 16-px partial sum (xor of bits 0..3 stays inside the q-group)
      float rsum = v;
      rsum += __shfl_xor(rsum, 1); rsum += __shfl_xor(rsum, 2);
      rsum += __shfl_xor(rsum, 4); rsum += __shfl_xor(rsum, 8);
      if (n == 0) psum[w][o] = rsum;
    }
  __syncthreads();
  if (threadIdx.x < 128) {
    int o = threadIdx.x;
    fcpart[((size_t)b * 400 + blockIdx.x) * 128 + o] =
        psum[0][o] + psum[1][o] + psum[2][o] + psum[3][o];
  }
}

extern "C" void kernel_launch(void* const* d_in, const int* in_sizes, int n_in,
                              void* d_out, int out_size, void* d_ws, size_t ws_size,
                              hipStream_t stream) {
  const float* inp   = (const float*)d_in[0];
  const float* n1w   = (const float*)d_in[1];
  const float* n1b   = (const float*)d_in[2];
  const float* n2w   = (const float*)d_in[3];
  const float* n2b   = (const float*)d_in[4];
  const float* scaw  = (const float*)d_in[5];
  const float* scab  = (const float*)d_in[6];
  const float* c11aw = (const float*)d_in[7];
  const float* c11ab = (const float*)d_in[8];
  const float* c11bw = (const float*)d_in[9];
  const float* c11bb = (const float*)d_in[10];
  const float* c1w   = (const float*)d_in[11];
  const float* c1b   = (const float*)d_in[12];
  const float* c21w  = (const float*)d_in[13];
  const float* c21b  = (const float*)d_in[14];
  const float* c2aw  = (const float*)d_in[15];
  const float* c2ab  = (const float*)d_in[16];
  const float* c2cw  = (const float*)d_in[17];
  const float* c2cb  = (const float*)d_in[18];
  const float* c211w = (const float*)d_in[19];
  const float* c211b = (const float*)d_in[20];
  const float* c3w   = (const float*)d_in[21];
  const float* c3b   = (const float*)d_in[22];
  const float* kbw   = (const float*)d_in[23];
  const float* kbb   = (const float*)d_in[24];
  const float* ga1   = (const float*)d_in[25];
  const float* attg  = (const float*)d_in[26];
  const float* beta  = (const float*)d_in[27];
  const float* gamma = (const float*)d_in[28];
  const float* fc1w  = (const float*)d_in[29];
  const float* fc1b  = (const float*)d_in[30];
  const float* fc2w  = (const float*)d_in[31];
  const float* fc2b  = (const float*)d_in[32];
  const float* fscaw = (const float*)d_in[33];
  const float* fscab = (const float*)d_in[34];

  const size_t S = (size_t)Bn * Cc * HWp;   // 3,276,800 elements per slot
  bf16* A  = (bf16*)d_ws;                   // 4 bf16 slots = 26.2 MB total
  bf16* Bs = A + S;
  bf16* Cs = A + 2 * S;
  bf16* Ds = A + 3 * S;
  float* smalls = (float*)(A + 4 * S);      // fp32 smalls
  float* scaV = smalls + 128;
  float* sra  = smalls + 512;               // sra[128]|sia[128]
  short* wS   = (short*)(smalls + 1024);    // bf16 frag tables
  short* wAf1 = wS;                         // 32768
  short* wAf2 = wAf1 + 32768;               // 16384
  short* cosF = wAf2 + 16384;               // 25600
  short* sinF = cosF + 25600;               // 25600
  short* wA_c11a = sinF + 25600;            // 4096
  short* wA_c1   = wA_c11a + 4096;          // 4096
  short* wA_c3   = wA_c1 + 4096;            // 4096
  short* wA_att  = wA_c3 + 4096;            // 3072
  short* kbwF    = wA_att + 3072;           // 131072-slot (81920 used)
  float* lnpart  = (float*)(kbwF + 131072); // 800*64 = 51200 floats (205 KB)
  float* fcpart  = lnpart + 51200;          // 800*128 = 102400 floats (410 KB)
  bf16* attb = Bs + S / 2;    // [B,32,HW] (second half of Bs)
  float* yb  = (float*)d_out; // y lives in d_out (fp32)

  dim3 cgrid(10, 2, Bn * Cc);
  dim3 pgrid(400, 1, Bn);

  k_prep_all<<<dim3(672), dim3(256), 0, stream>>>(kbw, kbb, kbwF, fc1w, fc2w, wAf1, wAf2,
                                                  cosF, sinF, c11aw, c1w, c3w, c2cw, c211w,
                                                  attg, wA_c11a, wA_c1, wA_c3, wA_att);
  k_ln<<<dim3(800), dim3(256), 0, stream>>>(inp, n1w, n1b, A, lnpart);  // A = x, lnpart
  k_small_mv_r<<<dim3(1), dim3(256), 0, stream>>>(lnpart, scaw, scab, scaV);
  k_conv1x1_dual<<<pgrid, dim3(256), 0, stream>>>(A, wA_c11a, c11ab, wA_c1, c1b, Bs, Ds); // B=t1 D=t2
  k_c11b_direct<<<dim3(3, 10, Bn * 16), dim3(256), 0, stream>>>(Bs, c11bw, c11bb, Cs); // C = x1
  k_att_fused<<<pgrid, dim3(256), 0, stream>>>(A, c2aw, c2ab, wA_att, c2cb, c211b, attg, attb);
  k_c21dw4<<<dim3(25, 64, Bn), dim3(256), 0, stream>>>(Ds, c21w, c21b, A);         // A = uf
  k_kba_mfma<<<dim3(3, 160, Bn * 8), dim3(256), 0, stream>>>(A, attb, Cs, scaV, kbwF, ga1, Ds);
  k_c3y_ln2<<<pgrid, dim3(256), 0, stream>>>(Ds, wA_c3, c3b, beta, inp, yb, n2w, n2b, A); // y, A=X
  // forward FFT2 (MFMA)
  k_cpass_mfma<<<cgrid, dim3(64), 0, stream>>>(A, (const bf16*)nullptr, cosF, sinF, Bs, Cs, -1.f, SCL, nullptr, nullptr);
  k_cpass_mfma<<<cgrid, dim3(64), 0, stream>>>(Bs, Cs, cosF, sinF, Ds, A, -1.f, SCL, nullptr, nullptr);
  // fused fc1+gate+fc2 (+ plane-mean partials); in-place on Ds/A
  k_fc12_mfma<<<pgrid, dim3(256), 0, stream>>>(Ds, A, wAf1, fc1b, wAf2, fc2b, Ds, A, fcpart);
  k_small_mv2_r<<<dim3(1), dim3(256), 0, stream>>>(fcpart, fscaw, fscab, sra);     // sra|sia
  // inverse FFT2 (MFMA) with per-plane (1+ra)/(1+ia) scaling fused into first pass
  k_cpass_mfma<<<cgrid, dim3(64), 0, stream>>>(Ds, A, cosF, sinF, Bs, Cs, 1.f, SCL, sra, sra + 128);
  k_cpass_final_mfma<<<cgrid, dim3(64), 0, stream>>>(Bs, Cs, cosF, sinF, 1.f, SCL, gamma, yb);
}